// Round 1
// 3295.991 us; speedup vs baseline: 1.0003x; 1.0003x over previous
//
#include <hip/hip_runtime.h>
#include <hip/hip_bf16.h>

typedef __hip_bfloat16 bf16;

#define BK 32
#define LDA 132  // padded LDS leading dim (legacy VALU path)

typedef __bf16 bfv8 __attribute__((ext_vector_type(8)));
typedef float f32x4 __attribute__((ext_vector_type(4)));

__device__ __forceinline__ float lrelu(float x) { return x > 0.f ? x : 0.01f * x; }

__device__ __forceinline__ float ldv(float v) { return v; }
__device__ __forceinline__ float ldv(bf16 v) { return __bfloat162float(v); }
__device__ __forceinline__ void stv(float* p, float v) { *p = v; }
__device__ __forceinline__ void stv(bf16* p, float v) { *p = __float2bfloat16(v); }

__device__ __forceinline__ float in_rd(const void* p, size_t i, int isbf) {
  return isbf ? __bfloat162float(((const bf16*)p)[i]) : ((const float*)p)[i];
}
__device__ __forceinline__ int ix_rd(const void* p, size_t i, int is64) {
  return is64 ? (int)((const long long*)p)[i] : ((const int*)p)[i];
}

// ---------------- fused per-array format probe: one launch, 23 blocks ----------------
struct ProbeArgs {
  const void* p[23];
  int s[23];
  int mode[23];
};

__global__ void detect_all(ProbeArgs a, int* __restrict__ flags) {
  __shared__ int sh[256];
  int b = blockIdx.x;
  const unsigned int* w = (const unsigned int*)a.p[b];
  int s = a.s[b], mode = a.mode[b];
  int t = threadIdx.x;
  int c = 0;
  if (t < s) {
    if (mode == 0) {
      unsigned int v = w[t];
      int e = (v >> 7) & 0xFF;
      c = (e >= 100 && e <= 140) ? 1 : 0;
    } else {
      c = (w[2 * t + 1] == 0u) ? 1 : 0;
    }
  }
  sh[t] = c;
  __syncthreads();
  for (int d = 128; d; d >>= 1) {
    if (t < d) sh[t] += sh[t + d];
    __syncthreads();
  }
  if (t == 0) flags[b] = (mode == 0) ? (sh[0] * 10 >= 7 * s) : (sh[0] * 10 >= 9 * s);
}

// ---------------- weight prep ----------------
// fp32 region (floats): [0,16384) W_inT [k,n]; [16384,32768) W_o1T [k,n]; [32768,49152) root;
// [49152,81920) rw; [81920] b_in; [82048] rgcn_bias; [82176] b_o1; [82304] W_o2; [82560] b_o2
// bf16 region (starting at float index BF_BASE, 16B aligned), each [128][128] bf16 in
// [n][k] (out,in) layout for MFMA B-fragments:
//   m=0 WinB; m=1 Wo1B; m=2 rootB; m=3 rwB0; m=4 rwB1   (rootB,rwB0,rwB1 contiguous)
#define PW_F32 82562
#define BF_BASE 82564
#define PW_TOTAL (BF_BASE + 5 * 8192)
__global__ void prep_weights(const void* Win, const void* bin, const void* rw,
                             const void* root, const void* rb, const void* Wo1,
                             const void* bo1, const void* Wo2, const void* bo2,
                             const int* __restrict__ fl, float* __restrict__ pw) {
  int i = blockIdx.x * 256 + threadIdx.x;
  if (i >= PW_TOTAL) return;
  if (i < 16384) {
    int k = i >> 7, o = i & 127;
    pw[i] = in_rd(Win, (size_t)o * 128 + k, fl[14]);
  } else if (i < 32768) {
    int j = i - 16384;
    int k = j >> 7, o = j & 127;
    pw[i] = in_rd(Wo1, (size_t)o * 128 + k, fl[19]);
  } else if (i < 49152) {
    pw[i] = in_rd(root, i - 32768, fl[17]);
  } else if (i < 81920) {
    pw[i] = in_rd(rw, i - 49152, fl[16]);
  } else if (i < 82048) {
    pw[i] = in_rd(bin, i - 81920, fl[15]);
  } else if (i < 82176) {
    pw[i] = in_rd(rb, i - 82048, fl[18]);
  } else if (i < 82304) {
    pw[i] = in_rd(bo1, i - 82176, fl[20]);
  } else if (i < 82560) {
    pw[i] = in_rd(Wo2, i - 82304, fl[21]);
  } else if (i < PW_F32) {
    pw[i] = in_rd(bo2, i - 82560, fl[22]);
  } else if (i >= BF_BASE) {
    int j = i - BF_BASE;
    bf16* bw = (bf16*)(pw + BF_BASE);
#pragma unroll
    for (int q = 0; q < 2; q++) {
      int u = 2 * j + q;
      int m = u >> 14, r = u & 16383;
      int n = r >> 7, k = r & 127;
      float v;
      if (m == 0) v = in_rd(Win, (size_t)n * 128 + k, fl[14]);
      else if (m == 1) v = in_rd(Wo1, (size_t)n * 128 + k, fl[19]);
      else if (m == 2) v = in_rd(root, (size_t)k * 128 + n, fl[17]);
      else v = in_rd(rw, (size_t)(m - 3) * 16384 + (size_t)k * 128 + n, fl[16]);
      bw[u] = __float2bfloat16(v);
    }
  }
}

// ---------------- utilities ----------------
__global__ void sig_fill(float* __restrict__ p, int n, float v) {
  int i = blockIdx.x * 256 + threadIdx.x;
  if (i < n) p[i] = v;
}
__global__ void zero_ints(int* __restrict__ p, int n) {
  int i = blockIdx.x * 256 + threadIdx.x;
  if (i < n) p[i] = 0;
}

// ---------------- CSR build ----------------
__global__ void count_edges(const void* __restrict__ ei, const void* __restrict__ et,
                            const int* __restrict__ fl, int* __restrict__ cnt, int NEr,
                            int NNr) {
  int e = blockIdx.x * 256 + threadIdx.x;
  if (e >= NEr) return;
  int d = ix_rd(ei, (size_t)NEr + e, fl[4]);
  int r = ix_rd(et, e, fl[5]) & 1;
  if ((unsigned)d >= (unsigned)NNr) return;
  atomicAdd(&cnt[r * NNr + d], 1);
}

__global__ void scan_blocks(const int* __restrict__ in, int* __restrict__ out,
                            int* __restrict__ bsum, int n) {
  __shared__ int sh[256];
  int t = threadIdx.x;
  int base = blockIdx.x * 1024 + t * 4;
  int a[4];
  int s = 0;
#pragma unroll
  for (int i = 0; i < 4; i++) {
    a[i] = (base + i < n) ? in[base + i] : 0;
    s += a[i];
  }
  sh[t] = s;
  __syncthreads();
  for (int d = 1; d < 256; d <<= 1) {
    int v = (t >= d) ? sh[t - d] : 0;
    __syncthreads();
    sh[t] += v;
    __syncthreads();
  }
  int ex = sh[t] - s;
#pragma unroll
  for (int i = 0; i < 4; i++) {
    if (base + i < n) out[base + i] = ex;
    ex += a[i];
  }
  if (t == 255 && bsum) bsum[blockIdx.x] = sh[255];
}

__global__ void scan_add_inv(int* __restrict__ off, const int* __restrict__ bsumsc,
                             const int* __restrict__ cnt, float* __restrict__ inv, int n) {
  int i = blockIdx.x * 256 + threadIdx.x;
  if (i >= n) return;
  off[i] += bsumsc[i >> 10];
  inv[i] = 1.f / fmaxf((float)cnt[i], 1.f);
}

__global__ void fill_elist(const void* __restrict__ ei, const void* __restrict__ et,
                           const int* __restrict__ fl, const int* __restrict__ off,
                           int* __restrict__ fill, int* __restrict__ elist, int NEr, int NNr) {
  int e = blockIdx.x * 256 + threadIdx.x;
  if (e >= NEr) return;
  int s = ix_rd(ei, e, fl[4]);
  int d = ix_rd(ei, (size_t)NEr + e, fl[4]);
  int r = ix_rd(et, e, fl[5]) & 1;
  if ((unsigned)d >= (unsigned)NNr || (unsigned)s >= (unsigned)NNr) return;
  int idx = r * NNr + d;
  int slot = off[idx] + atomicAdd(&fill[idx], 1);
  elist[slot] = s;
}

// ---------------- encoder GEMM ----------------
template <typename T>
__global__ __launch_bounds__(256) void enc_gemm(const void* __restrict__ A,
                                                const void* __restrict__ W,
                                                const void* __restrict__ B,
                                                const int* __restrict__ fl, int fa, int fw,
                                                int fb, T* __restrict__ x, int M, int K, int N,
                                                int row0, int col0) {
  __shared__ float Wb[128 * 102];
  __shared__ float bb[128];
  int t = threadIdx.x;
  int stride = (K & 1) ? K : K + 1;
  int fA = fl[fa];
  {
    int fW = fl[fw], fB = fl[fb];
    for (int idx = t; idx < N * K; idx += 256) {
      int j = idx / K, k = idx - j * K;
      Wb[j * stride + k] = in_rd(W, (size_t)j * K + k, fW);
    }
    if (t < N) bb[t] = in_rd(B, t, fB);
  }
  __syncthreads();
  int j = t % N;
  int r = t / N;
  int R = 256 / N;
  int iEnd = blockIdx.x * 64 + 64;
  if (iEnd > M) iEnd = M;
  const float* wrow = &Wb[j * stride];
  if (!fA) {
    const float* Af = (const float*)A;
    for (int i = blockIdx.x * 64 + r; i < iEnd; i += R) {
      const float* a = Af + (size_t)i * K;
      float acc = bb[j];
      for (int k = 0; k < K; k++) acc += a[k] * wrow[k];
      stv(&x[(size_t)(row0 + i) * 128 + col0 + j], lrelu(acc));
    }
  } else {
    const bf16* Ab = (const bf16*)A;
    for (int i = blockIdx.x * 64 + r; i < iEnd; i += R) {
      const bf16* a = Ab + (size_t)i * K;
      float acc = bb[j];
      for (int k = 0; k < K; k++) acc += __bfloat162float(a[k]) * wrow[k];
      stv(&x[(size_t)(row0 + i) * 128 + col0 + j], lrelu(acc));
    }
  }
}

// ---------------- gather means: 1 block = 1 node, 2 rels x 128 cols ----------------
template <typename T>
__global__ __launch_bounds__(256) void gather_means(const T* __restrict__ X,
                                                    const int* __restrict__ off,
                                                    const int* __restrict__ cnt,
                                                    const int* __restrict__ elist,
                                                    const float* __restrict__ inv,
                                                    bf16* __restrict__ mean, int NNr) {
  int node = blockIdx.x;
  int rel = threadIdx.x >> 7;
  int col = threadIdx.x & 127;
  int idx = rel * NNr + node;
  int st = off[idx];
  int n = cnt[idx];
  float s = 0.f;
  for (int e = 0; e < n; e++) {
    int src = elist[st + e];
    s += ldv(X[(size_t)src * 128 + col]);  // coalesced across 128 lanes
  }
  mean[(size_t)rel * NNr * 128 + (size_t)node * 128 + col] = __float2bfloat16(s * inv[idx]);
}

// ================= MFMA GEMMs (fp32 main path) =================
// Fragment layouts for v_mfma_f32_16x16x32_bf16 (m89/m91-verified C/D mapping):
//   A: lane l holds A[m = l&15][k = (l>>4)*8 + i], i=0..7   (8 contiguous K elems)
//   B: lane l holds B[k = (l>>4)*8 + i][n = l&15]  == Bt[n = l&15][k ...] with Bt=[out][in]
//   D: lane l reg j -> row = (l>>4)*4 + j, col = l&15
// Block = 128 rows x 128 cols, 4 waves in 2x2, each wave 64x64 (4x4 fragments).
// No LDS. A rows clamped (not zeroed) at M: junk rows are never stored.

__device__ __forceinline__ bfv8 ldcvt8(const float* p) {
  float4 f0 = *(const float4*)p;
  float4 f1 = *(const float4*)(p + 4);
  bfv8 v;
  v[0] = (__bf16)f0.x; v[1] = (__bf16)f0.y; v[2] = (__bf16)f0.z; v[3] = (__bf16)f0.w;
  v[4] = (__bf16)f1.x; v[5] = (__bf16)f1.y; v[6] = (__bf16)f1.z; v[7] = (__bf16)f1.w;
  return v;
}

// Out = lrelu(A @ Wb^T + bias); A fp32 [M][128], Wb bf16 [128][128] in [out][in] layout
__global__ __launch_bounds__(256) void mfma_lin(const float* __restrict__ A,
                                                const bf16* __restrict__ Wb,
                                                const float* __restrict__ bias,
                                                float* __restrict__ Out, int M) {
  int t = threadIdx.x;
  int wv = t >> 6, l = t & 63;
  int lr = l & 15, lg = l >> 4;
  int rbase = blockIdx.x * 128 + (wv >> 1) * 64;
  int cbase = (wv & 1) * 64;
  int ko = lg * 8;

  bfv8 bfr[4][4];
#pragma unroll
  for (int cg = 0; cg < 4; cg++)
#pragma unroll
    for (int ks = 0; ks < 4; ks++)
      bfr[cg][ks] = *(const bfv8*)&Wb[(size_t)(cbase + cg * 16 + lr) * 128 + ks * 32 + ko];

  const float* arow[4];
#pragma unroll
  for (int rg = 0; rg < 4; rg++) {
    int r = rbase + rg * 16 + lr;
    if (r > M - 1) r = M - 1;
    arow[rg] = A + (size_t)r * 128 + ko;
  }

  f32x4 acc[4][4] = {};
#pragma unroll
  for (int ks = 0; ks < 4; ks++) {
    bfv8 af[4];
#pragma unroll
    for (int rg = 0; rg < 4; rg++) af[rg] = ldcvt8(arow[rg] + ks * 32);
#pragma unroll
    for (int rg = 0; rg < 4; rg++)
#pragma unroll
      for (int cg = 0; cg < 4; cg++)
        acc[rg][cg] =
            __builtin_amdgcn_mfma_f32_16x16x32_bf16(af[rg], bfr[cg][ks], acc[rg][cg], 0, 0, 0);
  }

#pragma unroll
  for (int cg = 0; cg < 4; cg++) {
    int col = cbase + cg * 16 + lr;
    float bv = bias[col];
#pragma unroll
    for (int rg = 0; rg < 4; rg++) {
      int row0 = rbase + rg * 16 + lg * 4;
#pragma unroll
      for (int j = 0; j < 4; j++) {
        int row = row0 + j;
        if (row < M) Out[(size_t)row * 128 + col] = lrelu(acc[rg][cg][j] + bv);
      }
    }
  }
}

// Out = X @ root + mean0 @ rw0 + mean1 @ rw1 + bias  (no activation)
// WB = 3 contiguous bf16 [128][128] matrices in [out][in] layout: rootB, rwB0, rwB1
__global__ __launch_bounds__(256) void mfma_conv(const float* __restrict__ X,
                                                 const bf16* __restrict__ mean,
                                                 const bf16* __restrict__ WB,
                                                 const float* __restrict__ bias,
                                                 float* __restrict__ Out, int M) {
  int t = threadIdx.x;
  int wv = t >> 6, l = t & 63;
  int lr = l & 15, lg = l >> 4;
  int rbase = blockIdx.x * 128 + (wv >> 1) * 64;
  int cbase = (wv & 1) * 64;
  int ko = lg * 8;

  size_t rowoff[4];
#pragma unroll
  for (int rg = 0; rg < 4; rg++) {
    int r = rbase + rg * 16 + lr;
    if (r > M - 1) r = M - 1;
    rowoff[rg] = (size_t)r * 128 + ko;
  }

  f32x4 acc[4][4] = {};
  for (int seg = 0; seg < 3; seg++) {
    const bf16* Wb = WB + (size_t)seg * 16384;
    bfv8 bfr[4][4];
#pragma unroll
    for (int cg = 0; cg < 4; cg++)
#pragma unroll
      for (int ks = 0; ks < 4; ks++)
        bfr[cg][ks] = *(const bfv8*)&Wb[(size_t)(cbase + cg * 16 + lr) * 128 + ks * 32 + ko];

    if (seg == 0) {
#pragma unroll
      for (int ks = 0; ks < 4; ks++) {
        bfv8 af[4];
#pragma unroll
        for (int rg = 0; rg < 4; rg++) af[rg] = ldcvt8(X + rowoff[rg] + ks * 32);
#pragma unroll
        for (int rg = 0; rg < 4; rg++)
#pragma unroll
          for (int cg = 0; cg < 4; cg++)
            acc[rg][cg] = __builtin_amdgcn_mfma_f32_16x16x32_bf16(af[rg], bfr[cg][ks],
                                                                  acc[rg][cg], 0, 0, 0);
      }
    } else {
      const bf16* Msrc = mean + (size_t)(seg - 1) * M * 128;
#pragma unroll
      for (int ks = 0; ks < 4; ks++) {
        bfv8 af[4];
#pragma unroll
        for (int rg = 0; rg < 4; rg++)
          af[rg] = *(const bfv8*)&Msrc[rowoff[rg] + ks * 32];
#pragma unroll
        for (int rg = 0; rg < 4; rg++)
#pragma unroll
          for (int cg = 0; cg < 4; cg++)
            acc[rg][cg] = __builtin_amdgcn_mfma_f32_16x16x32_bf16(af[rg], bfr[cg][ks],
                                                                  acc[rg][cg], 0, 0, 0);
      }
    }
  }

#pragma unroll
  for (int cg = 0; cg < 4; cg++) {
    int col = cbase + cg * 16 + lr;
    float bv = bias[col];
#pragma unroll
    for (int rg = 0; rg < 4; rg++) {
      int row0 = rbase + rg * 16 + lg * 4;
#pragma unroll
      for (int j = 0; j < 4; j++) {
        int row = row0 + j;
        if (row < M) Out[(size_t)row * 128 + col] = acc[rg][cg][j] + bv;
      }
    }
  }
}

// ---------------- legacy VALU K=128 GEMM (bf16 / non-pre fallback) ----------
template <typename T>
__global__ __launch_bounds__(256, 2) void gemm_k128(const T* __restrict__ A,
                                                    const float* __restrict__ Wt,
                                                    const float* __restrict__ bias,
                                                    T* __restrict__ Out, int M) {
  __shared__ __align__(16) float As[BK][LDA];
  __shared__ __align__(16) float Bs[BK][LDA];
  int t = threadIdx.x;
  int i0 = blockIdx.x * 128;
  int mrow4 = (t >> 4) * 4;
  int ncol4 = (t & 15) * 4;
  float acc[8][8] = {};
  for (int k0 = 0; k0 < 128; k0 += BK) {
#pragma unroll
    for (int c = 0; c < 16; c++) {
      int idx = c * 256 + t;
      int m = idx >> 5;
      int kk = idx & 31;
      int row = i0 + m;
      As[kk][m] = (row < M) ? ldv(A[(size_t)row * 128 + k0 + kk]) : 0.f;
    }
#pragma unroll
    for (int c = 0; c < 16; c++) {
      int idx = c * 256 + t;
      int o = idx & 127;
      int kk = idx >> 7;
      Bs[kk][o] = Wt[(size_t)(k0 + kk) * 128 + o];
    }
    __syncthreads();
#pragma unroll
    for (int k2 = 0; k2 < BK; k2++) {
      float4 a0 = *(const float4*)&As[k2][mrow4];
      float4 a1 = *(const float4*)&As[k2][mrow4 + 64];
      float4 b0 = *(const float4*)&Bs[k2][ncol4];
      float4 b1 = *(const float4*)&Bs[k2][ncol4 + 64];
      float av[8] = {a0.x, a0.y, a0.z, a0.w, a1.x, a1.y, a1.z, a1.w};
      float bv[8] = {b0.x, b0.y, b0.z, b0.w, b1.x, b1.y, b1.z, b1.w};
#pragma unroll
      for (int i = 0; i < 8; i++)
#pragma unroll
        for (int j = 0; j < 8; j++) acc[i][j] += av[i] * bv[j];
    }
    __syncthreads();
  }
  float bvv[8];
#pragma unroll
  for (int j = 0; j < 8; j++) bvv[j] = bias[ncol4 + (j < 4 ? j : 60 + j)];
#pragma unroll
  for (int i = 0; i < 8; i++) {
    int row = i0 + mrow4 + (i < 4 ? i : 60 + i);
    if (row < M) {
#pragma unroll
      for (int j = 0; j < 8; j++) {
        int col = ncol4 + (j < 4 ? j : 60 + j);
        stv(&Out[(size_t)row * 128 + col], lrelu(acc[i][j] + bvv[j]));
      }
    }
  }
}

// ---------------- legacy RGCN conv GEMM (fallback paths) ----------------
template <typename T, bool PRE>
__global__ __launch_bounds__(256, 2) void conv_gemm(
    const T* __restrict__ X, const bf16* __restrict__ mean, const int* __restrict__ off,
    const int* __restrict__ cnt, const int* __restrict__ elist, const float* __restrict__ inv,
    const float* __restrict__ root, const float* __restrict__ rw,
    const float* __restrict__ bias, T* __restrict__ Out, int M) {
  __shared__ __align__(16) float As[BK][LDA];
  __shared__ __align__(16) float Bs[BK][LDA];
  int t = threadIdx.x;
  int i0 = blockIdx.x * 128;
  int mrow4 = (t >> 4) * 4;
  int ncol4 = (t & 15) * 4;
  float acc[8][8] = {};
  for (int seg = 0; seg < 3; seg++) {
    const float* B = (seg == 0) ? root : rw + (size_t)(seg - 1) * 16384;
    for (int k0 = 0; k0 < 128; k0 += BK) {
      if (PRE) {
#pragma unroll
        for (int c = 0; c < 16; c++) {
          int idx = c * 256 + t;
          int m = idx >> 5;
          int kk = idx & 31;
          int row = i0 + m;
          float v = 0.f;
          if (row < M) {
            v = (seg == 0) ? ldv(X[(size_t)row * 128 + k0 + kk])
                           : __bfloat162float(
                                 mean[(size_t)(seg - 1) * M * 128 + (size_t)row * 128 + k0 + kk]);
          }
          As[kk][m] = v;
        }
      } else {
        int kk = t & 31;
        int m0 = t >> 5;
        for (int p = 0; p < 16; p++) {
          int m = p * 8 + m0;
          int row = i0 + m;
          float v = 0.f;
          if (row < M) {
            if (seg == 0) {
              v = ldv(X[(size_t)row * 128 + k0 + kk]);
            } else {
              int idx = (seg - 1) * M + row;
              int st = off[idx];
              int en = st + cnt[idx];
              float a = 0.f;
              for (int e = st; e < en; e++) a += ldv(X[(size_t)elist[e] * 128 + k0 + kk]);
              v = a * inv[idx];
            }
          }
          As[kk][m] = v;
        }
      }
#pragma unroll
      for (int c = 0; c < 16; c++) {
        int idx = c * 256 + t;
        int o = idx & 127;
        int k2 = idx >> 7;
        Bs[k2][o] = B[(size_t)(k0 + k2) * 128 + o];
      }
      __syncthreads();
#pragma unroll
      for (int k2 = 0; k2 < BK; k2++) {
        float4 a0 = *(const float4*)&As[k2][mrow4];
        float4 a1 = *(const float4*)&As[k2][mrow4 + 64];
        float4 b0 = *(const float4*)&Bs[k2][ncol4];
        float4 b1 = *(const float4*)&Bs[k2][ncol4 + 64];
        float av[8] = {a0.x, a0.y, a0.z, a0.w, a1.x, a1.y, a1.z, a1.w};
        float bv[8] = {b0.x, b0.y, b0.z, b0.w, b1.x, b1.y, b1.z, b1.w};
#pragma unroll
        for (int i = 0; i < 8; i++)
#pragma unroll
          for (int j = 0; j < 8; j++) acc[i][j] += av[i] * bv[j];
      }
      __syncthreads();
    }
  }
  float bvv[8];
#pragma unroll
  for (int j = 0; j < 8; j++) bvv[j] = bias[ncol4 + (j < 4 ? j : 60 + j)];
#pragma unroll
  for (int i = 0; i < 8; i++) {
    int row = i0 + mrow4 + (i < 4 ? i : 60 + i);
    if (row < M) {
#pragma unroll
      for (int j = 0; j < 8; j++) {
        int col = ncol4 + (j < 4 ? j : 60 + j);
        stv(&Out[(size_t)row * 128 + col], acc[i][j] + bvv[j]);
      }
    }
  }
}

// ---------------- final 128 -> 2 linear, FP32 out ----------------
template <typename T>
__global__ void out_linear(const T* __restrict__ x, const float* __restrict__ W,
                           const float* __restrict__ B, float* __restrict__ out, int NNr) {
  int wave = threadIdx.x >> 6;
  int lane = threadIdx.x & 63;
  int i = blockIdx.x * 4 + wave;
  if (i >= NNr) return;
  const T* xr = x + (size_t)i * 128;
  float x0 = ldv(xr[lane]);
  float x1 = ldv(xr[lane + 64]);
  float p0 = x0 * W[lane] + x1 * W[lane + 64];
  float p1 = x0 * W[128 + lane] + x1 * W[128 + lane + 64];
#pragma unroll
  for (int offs = 32; offs; offs >>= 1) {
    p0 += __shfl_down(p0, offs, 64);
    p1 += __shfl_down(p1, offs, 64);
  }
  if (lane == 0) {
    out[(size_t)i * 2] = p0 + B[0];
    out[(size_t)i * 2 + 1] = p1 + B[1];
  }
}

// ---------------- pipeline ----------------
template <typename T>
static void run_pipeline(void* const* d_in, const int* S, float* out, char* ws,
                         size_t ws_size, int NUr, int NTr, int NEr, int dDes, int dNum,
                         int dCat, int dTw, hipStream_t stream) {
  const int NNr = NUr + NTr;
  const size_t xbytes = (size_t)NNr * 128 * sizeof(T);
  const size_t mbytes = (size_t)2 * NNr * 128 * sizeof(bf16);
  const size_t smallBytes = (size_t)4 * ((size_t)2 * NNr * 4) + 2 * 2048 * 4 +
                            (size_t)NEr * 4 + (size_t)PW_TOTAL * 4 + 512;
  const bool pre = (sizeof(T) == 4) && (ws_size >= 2 * xbytes + mbytes + smallBytes);

  T* xa = (T*)ws;
  T* xb = (T*)(ws + xbytes);
  bf16* means = (bf16*)(ws + 2 * xbytes);
  char* p = ws + 2 * xbytes + (pre ? mbytes : 0);
  int* cnt = (int*)p;      p += (size_t)2 * NNr * 4;
  int* fill = (int*)p;     p += (size_t)2 * NNr * 4;  // contiguous with cnt
  int* off = (int*)p;      p += (size_t)2 * NNr * 4;
  int* bsum = (int*)p;     p += 2048 * 4;             // contiguous with bsumsc
  int* bsumsc = (int*)p;   p += 2048 * 4;
  float* inv = (float*)p;  p += (size_t)2 * NNr * 4;
  int* elist = (int*)p;    p += (size_t)NEr * 4;
  float* pw = (float*)p;   p += (size_t)PW_TOTAL * 4;
  int* flags = (int*)p;

  // ---- format probes: one launch ----
  ProbeArgs pa;
  for (int i = 0; i < 23; i++) {
    int src = (i == 22) ? 21 : i;  // b_o2 (2 elems) inherits W_o2's dtype
    pa.p[i] = d_in[src];
    if (i == 4) {
      pa.mode[i] = 1;
      pa.s[i] = NEr < 256 ? NEr : 256;
    } else if (i == 5) {
      pa.mode[i] = 1;
      int s2 = NEr / 2 < 256 ? NEr / 2 : 256;
      pa.s[i] = s2 < 1 ? 1 : s2;
    } else {
      pa.mode[i] = 0;
      int s = S[src] / 2;
      if (s > 256) s = 256;
      if (s < 1) s = 1;
      pa.s[i] = s;
    }
  }
  detect_all<<<23, 256, 0, stream>>>(pa, flags);
  prep_weights<<<(PW_TOTAL + 255) / 256, 256, 0, stream>>>(
      d_in[14], d_in[15], d_in[16], d_in[17], d_in[18], d_in[19], d_in[20], d_in[21],
      d_in[22], flags, pw);

  const float* WtIn = pw;
  const float* WtO1 = pw + 16384;
  const float* rootp = pw + 32768;
  const float* rwp = pw + 49152;
  const float* bIn = pw + 81920;
  const float* rbp = pw + 82048;
  const float* bO1 = pw + 82176;
  const float* Wo2p = pw + 82304;
  const float* bo2p = pw + 82560;
  const bf16* WinB = (const bf16*)(pw + BF_BASE);
  const bf16* Wo1B = (const bf16*)(pw + BF_BASE + 8192);
  const bf16* ConvB = (const bf16*)(pw + BF_BASE + 16384);  // rootB, rwB0, rwB1

  const void* ei = d_in[4];
  const void* et = d_in[5];
  const int nb1 = (2 * NNr + 1023) / 1024;

  // ---- CSR build ----
  zero_ints<<<(4 * NNr + 255) / 256, 256, 0, stream>>>(cnt, 4 * NNr);
  zero_ints<<<16, 256, 0, stream>>>(bsum, 4096);
  count_edges<<<(NEr + 255) / 256, 256, 0, stream>>>(ei, et, flags, cnt, NEr, NNr);
  scan_blocks<<<nb1, 256, 0, stream>>>(cnt, off, bsum, 2 * NNr);
  scan_blocks<<<1, 256, 0, stream>>>(bsum, bsumsc, nullptr, nb1);
  scan_add_inv<<<(2 * NNr + 255) / 256, 256, 0, stream>>>(off, bsumsc, cnt, inv, 2 * NNr);
  fill_elist<<<(NEr + 255) / 256, 256, 0, stream>>>(ei, et, flags, off, fill, elist, NEr, NNr);

  // ---- encoders -> xa ----
  enc_gemm<T><<<(NUr + 63) / 64, 256, 0, stream>>>(d_in[0], d_in[6], d_in[7], flags, 0, 6, 7,
                                                   xa, NUr, dDes, 64, 0, 0);
  enc_gemm<T><<<(NUr + 63) / 64, 256, 0, stream>>>(d_in[2], d_in[8], d_in[9], flags, 2, 8, 9,
                                                   xa, NUr, dNum, 32, 0, 64);
  enc_gemm<T><<<(NUr + 63) / 64, 256, 0, stream>>>(d_in[3], d_in[10], d_in[11], flags, 3, 10,
                                                   11, xa, NUr, dCat, 32, 0, 96);
  enc_gemm<T><<<(NTr + 63) / 64, 256, 0, stream>>>(d_in[1], d_in[12], d_in[13], flags, 1, 12,
                                                   13, xa, NTr, dTw, 128, NUr, 0);

  const int mt = (NNr + 127) / 128;
  bool did = false;
  if constexpr (sizeof(T) == 4) {
    if (pre) {
      did = true;
      mfma_lin<<<mt, 256, 0, stream>>>((const float*)xa, WinB, bIn, (float*)xb, NNr);
      gather_means<T><<<NNr, 256, 0, stream>>>(xb, off, cnt, elist, inv, means, NNr);
      mfma_conv<<<mt, 256, 0, stream>>>((const float*)xb, means, ConvB, rbp, (float*)xa, NNr);
      gather_means<T><<<NNr, 256, 0, stream>>>(xa, off, cnt, elist, inv, means, NNr);
      mfma_conv<<<mt, 256, 0, stream>>>((const float*)xa, means, ConvB, rbp, (float*)xb, NNr);
      mfma_lin<<<mt, 256, 0, stream>>>((const float*)xb, Wo1B, bO1, (float*)xa, NNr);
    }
  }
  if (!did) {
    gemm_k128<T><<<mt, 256, 0, stream>>>(xa, WtIn, bIn, xb, NNr);
    conv_gemm<T, false><<<mt, 256, 0, stream>>>(xb, nullptr, off, cnt, elist, inv, rootp, rwp,
                                                rbp, xa, NNr);
    conv_gemm<T, false><<<mt, 256, 0, stream>>>(xa, nullptr, off, cnt, elist, inv, rootp, rwp,
                                                rbp, xb, NNr);
    gemm_k128<T><<<mt, 256, 0, stream>>>(xb, WtO1, bO1, xa, NNr);
  }

  out_linear<T><<<(NNr + 3) / 4, 256, 0, stream>>>(xa, Wo2p, bo2p, out, NNr);
}

extern "C" void kernel_launch(void* const* d_in, const int* in_sizes, int n_in,
                              void* d_out, int out_size, void* d_ws, size_t ws_size,
                              hipStream_t stream) {
  float* out = (float*)d_out;
  char* ws = (char*)d_ws;

  auto signal = [&](int k) {
    sig_fill<<<(out_size + 255) / 256, 256, 0, stream>>>(out, out_size, (float)(200 + k));
  };

  if (n_in != 23) { signal(1); return; }
  const int* S = in_sizes;
  if (S[7] != 64 || S[9] != 32 || S[11] != 32 || S[13] != 128) { signal(2); return; }
  if (S[15] != 128) { signal(3); return; }
  if (S[6] % 64 || S[8] % 32 || S[10] % 32 || S[12] % 128) { signal(4); return; }
  int dDes = S[6] / 64, dNum = S[8] / 32, dCat = S[10] / 32, dTw = S[12] / 128;
  if (dDes <= 0 || dTw <= 0 || S[0] % dDes || S[1] % dTw) { signal(5); return; }
  if (dDes > 101 || dNum > 101 || dCat > 101 || dTw > 101) { signal(4); return; }
  int NUr = S[0] / dDes, NTr = S[1] / dTw, NNr = NUr + NTr, NEr = S[5];
  if (S[2] != NUr * dNum || S[3] != NUr * dCat) { signal(5); return; }
  if (S[4] != 2 * NEr || NEr < 1024) { signal(6); return; }
  if (S[14] != 16384 || S[16] != 32768 || S[17] != 16384 || S[18] != 128 ||
      S[19] != 16384 || S[20] != 128 || S[21] != 256 || S[22] != 2) { signal(7); return; }
  if (out_size != NNr * 2) { signal(8); return; }

  const size_t smallBytes = (size_t)4 * ((size_t)2 * NNr * 4) + 2 * 2048 * 4 +
                            (size_t)NEr * 4 + (size_t)PW_TOTAL * 4 + 512;
  const size_t needF32 = 2 * (size_t)NNr * 128 * 4 + smallBytes;
  const size_t needB16 = 2 * (size_t)NNr * 128 * 2 + smallBytes;

  if (ws_size >= needF32) {
    run_pipeline<float>(d_in, S, out, ws, ws_size, NUr, NTr, NEr, dDes, dNum, dCat, dTw,
                        stream);
  } else if (ws_size >= needB16) {
    run_pipeline<bf16>(d_in, S, out, ws, ws_size, NUr, NTr, NEr, dDes, dNum, dCat, dTw,
                       stream);
  } else {
    signal(9);
  }
}

// Round 2
// 1680.099 us; speedup vs baseline: 1.9624x; 1.9618x over previous
//
#include <hip/hip_runtime.h>
#include <hip/hip_bf16.h>

typedef __hip_bfloat16 bf16;

typedef __bf16 bfv8 __attribute__((ext_vector_type(8)));
typedef float f32x4 __attribute__((ext_vector_type(4)));

__device__ __forceinline__ float lrelu(float x) { return x > 0.f ? x : 0.01f * x; }

__device__ __forceinline__ float ldv(float v) { return v; }
__device__ __forceinline__ float ldv(bf16 v) { return __bfloat162float(v); }
__device__ __forceinline__ void stv(float* p, float v) { *p = v; }
__device__ __forceinline__ void stv(bf16* p, float v) { *p = __float2bfloat16(v); }

__device__ __forceinline__ float in_rd(const void* p, size_t i, int isbf) {
  return isbf ? __bfloat162float(((const bf16*)p)[i]) : ((const float*)p)[i];
}
__device__ __forceinline__ int ix_rd(const void* p, size_t i, int is64) {
  return is64 ? (int)((const long long*)p)[i] : ((const int*)p)[i];
}

// ---------------- fused per-array format probe: one launch, 23 blocks ----------------
struct ProbeArgs {
  const void* p[23];
  int s[23];
  int mode[23];
};

__global__ void detect_all(ProbeArgs a, int* __restrict__ flags) {
  __shared__ int sh[256];
  int b = blockIdx.x;
  const unsigned int* w = (const unsigned int*)a.p[b];
  int s = a.s[b], mode = a.mode[b];
  int t = threadIdx.x;
  int c = 0;
  if (t < s) {
    if (mode == 0) {
      unsigned int v = w[t];
      int e = (v >> 7) & 0xFF;
      c = (e >= 100 && e <= 140) ? 1 : 0;
    } else {
      c = (w[2 * t + 1] == 0u) ? 1 : 0;
    }
  }
  sh[t] = c;
  __syncthreads();
  for (int d = 128; d; d >>= 1) {
    if (t < d) sh[t] += sh[t + d];
    __syncthreads();
  }
  if (t == 0) flags[b] = (mode == 0) ? (sh[0] * 10 >= 7 * s) : (sh[0] * 10 >= 9 * s);
}

// ---------------- weight prep ----------------
// fp32 region (floats): [0,16384) W_inT [k,n]; [16384,32768) W_o1T [k,n]; [32768,49152) root;
// [49152,81920) rw; [81920] b_in; [82048] rgcn_bias; [82176] b_o1; [82304] W_o2; [82560] b_o2
// bf16 region (starting at float index BF_BASE, 16B aligned), each [128][128] bf16 in
// [n][k] (out,in) layout for MFMA B-fragments:
//   m=0 WinB; m=1 Wo1B; m=2 rootB; m=3 rwB0; m=4 rwB1   (rootB,rwB0,rwB1 contiguous)
#define PW_F32 82562
#define BF_BASE 82564
#define PW_TOTAL (BF_BASE + 5 * 8192)
__global__ void prep_weights(const void* Win, const void* bin, const void* rw,
                             const void* root, const void* rb, const void* Wo1,
                             const void* bo1, const void* Wo2, const void* bo2,
                             const int* __restrict__ fl, float* __restrict__ pw) {
  int i = blockIdx.x * 256 + threadIdx.x;
  if (i >= PW_TOTAL) return;
  if (i < 16384) {
    int k = i >> 7, o = i & 127;
    pw[i] = in_rd(Win, (size_t)o * 128 + k, fl[14]);
  } else if (i < 32768) {
    int j = i - 16384;
    int k = j >> 7, o = j & 127;
    pw[i] = in_rd(Wo1, (size_t)o * 128 + k, fl[19]);
  } else if (i < 49152) {
    pw[i] = in_rd(root, i - 32768, fl[17]);
  } else if (i < 81920) {
    pw[i] = in_rd(rw, i - 49152, fl[16]);
  } else if (i < 82048) {
    pw[i] = in_rd(bin, i - 81920, fl[15]);
  } else if (i < 82176) {
    pw[i] = in_rd(rb, i - 82048, fl[18]);
  } else if (i < 82304) {
    pw[i] = in_rd(bo1, i - 82176, fl[20]);
  } else if (i < 82560) {
    pw[i] = in_rd(Wo2, i - 82304, fl[21]);
  } else if (i < PW_F32) {
    pw[i] = in_rd(bo2, i - 82560, fl[22]);
  } else if (i >= BF_BASE) {
    int j = i - BF_BASE;
    bf16* bw = (bf16*)(pw + BF_BASE);
#pragma unroll
    for (int q = 0; q < 2; q++) {
      int u = 2 * j + q;
      int m = u >> 14, r = u & 16383;
      int n = r >> 7, k = r & 127;
      float v;
      if (m == 0) v = in_rd(Win, (size_t)n * 128 + k, fl[14]);
      else if (m == 1) v = in_rd(Wo1, (size_t)n * 128 + k, fl[19]);
      else if (m == 2) v = in_rd(root, (size_t)k * 128 + n, fl[17]);
      else v = in_rd(rw, (size_t)(m - 3) * 16384 + (size_t)k * 128 + n, fl[16]);
      bw[u] = __float2bfloat16(v);
    }
  }
}

// ---------------- utilities ----------------
__global__ void sig_fill(float* __restrict__ p, int n, float v) {
  int i = blockIdx.x * 256 + threadIdx.x;
  if (i < n) p[i] = v;
}
__global__ void zero_ints(int* __restrict__ p, int n) {
  int i = blockIdx.x * 256 + threadIdx.x;
  if (i < n) p[i] = 0;
}

// ---------------- CSR build ----------------
__global__ void count_edges(const void* __restrict__ ei, const void* __restrict__ et,
                            const int* __restrict__ fl, int* __restrict__ cnt, int NEr,
                            int NNr) {
  int e = blockIdx.x * 256 + threadIdx.x;
  if (e >= NEr) return;
  int d = ix_rd(ei, (size_t)NEr + e, fl[4]);
  int r = ix_rd(et, e, fl[5]) & 1;
  if ((unsigned)d >= (unsigned)NNr) return;
  atomicAdd(&cnt[r * NNr + d], 1);
}

__global__ void scan_blocks(const int* __restrict__ in, int* __restrict__ out,
                            int* __restrict__ bsum, int n) {
  __shared__ int sh[256];
  int t = threadIdx.x;
  int base = blockIdx.x * 1024 + t * 4;
  int a[4];
  int s = 0;
#pragma unroll
  for (int i = 0; i < 4; i++) {
    a[i] = (base + i < n) ? in[base + i] : 0;
    s += a[i];
  }
  sh[t] = s;
  __syncthreads();
  for (int d = 1; d < 256; d <<= 1) {
    int v = (t >= d) ? sh[t - d] : 0;
    __syncthreads();
    sh[t] += v;
    __syncthreads();
  }
  int ex = sh[t] - s;
#pragma unroll
  for (int i = 0; i < 4; i++) {
    if (base + i < n) out[base + i] = ex;
    ex += a[i];
  }
  if (t == 255 && bsum) bsum[blockIdx.x] = sh[255];
}

__global__ void scan_add_inv(int* __restrict__ off, const int* __restrict__ bsumsc,
                             const int* __restrict__ cnt, float* __restrict__ inv, int n) {
  int i = blockIdx.x * 256 + threadIdx.x;
  if (i >= n) return;
  off[i] += bsumsc[i >> 10];
  inv[i] = 1.f / fmaxf((float)cnt[i], 1.f);
}

// elist word packs: bits [0,24) = src node id, bits [24,31) = dst & 127 (row within tile)
__global__ void fill_elist(const void* __restrict__ ei, const void* __restrict__ et,
                           const int* __restrict__ fl, const int* __restrict__ off,
                           int* __restrict__ fill, int* __restrict__ elist, int NEr, int NNr) {
  int e = blockIdx.x * 256 + threadIdx.x;
  if (e >= NEr) return;
  int s = ix_rd(ei, e, fl[4]);
  int d = ix_rd(ei, (size_t)NEr + e, fl[4]);
  int r = ix_rd(et, e, fl[5]) & 1;
  if ((unsigned)d >= (unsigned)NNr || (unsigned)s >= (unsigned)NNr) return;
  int idx = r * NNr + d;
  int slot = off[idx] + atomicAdd(&fill[idx], 1);
  elist[slot] = s | ((d & 127) << 24);
}

// ---------------- encoder GEMM ----------------
__global__ __launch_bounds__(256) void enc_gemm(const void* __restrict__ A,
                                                const void* __restrict__ W,
                                                const void* __restrict__ B,
                                                const int* __restrict__ fl, int fa, int fw,
                                                int fb, bf16* __restrict__ x, int M, int K,
                                                int N, int row0, int col0) {
  __shared__ float Wb[128 * 102];
  __shared__ float bb[128];
  int t = threadIdx.x;
  int stride = (K & 1) ? K : K + 1;
  int fA = fl[fa];
  {
    int fW = fl[fw], fB = fl[fb];
    for (int idx = t; idx < N * K; idx += 256) {
      int j = idx / K, k = idx - j * K;
      Wb[j * stride + k] = in_rd(W, (size_t)j * K + k, fW);
    }
    if (t < N) bb[t] = in_rd(B, t, fB);
  }
  __syncthreads();
  int j = t % N;
  int r = t / N;
  int R = 256 / N;
  int iEnd = blockIdx.x * 64 + 64;
  if (iEnd > M) iEnd = M;
  const float* wrow = &Wb[j * stride];
  if (!fA) {
    const float* Af = (const float*)A;
    for (int i = blockIdx.x * 64 + r; i < iEnd; i += R) {
      const float* a = Af + (size_t)i * K;
      float acc = bb[j];
      for (int k = 0; k < K; k++) acc += a[k] * wrow[k];
      stv(&x[(size_t)(row0 + i) * 128 + col0 + j], lrelu(acc));
    }
  } else {
    const bf16* Ab = (const bf16*)A;
    for (int i = blockIdx.x * 64 + r; i < iEnd; i += R) {
      const bf16* a = Ab + (size_t)i * K;
      float acc = bb[j];
      for (int k = 0; k < K; k++) acc += __bfloat162float(a[k]) * wrow[k];
      stv(&x[(size_t)(row0 + i) * 128 + col0 + j], lrelu(acc));
    }
  }
}

// ================= MFMA GEMMs (bf16 storage, fp32 accumulate) =================
// v_mfma_f32_16x16x32_bf16 fragments (m89/m91-verified C/D mapping):
//   A: lane l holds A[m = l&15][k = (l>>4)*8 + i]
//   B: lane l holds B[k = (l>>4)*8 + i][n = l&15]  (= Wt[n][k] with Wt in [out][in] layout)
//   D: lane l reg j -> row = (l>>4)*4 + j, col = l&15
// Block = 128 rows x 128 cols; 4 waves in 2x2; each wave 64x64 (4x4 fragments).

// Out = lrelu(A @ Wb^T + bias); A,Out bf16 [M][128]; Wb bf16 [out][in]
__global__ __launch_bounds__(256) void mfma_lin(const bf16* __restrict__ A,
                                                const bf16* __restrict__ Wb,
                                                const float* __restrict__ bias,
                                                bf16* __restrict__ Out, int M) {
  int t = threadIdx.x;
  int wv = t >> 6, l = t & 63;
  int lr = l & 15, lg = l >> 4;
  int i0 = blockIdx.x * 128;
  int rbase = (wv >> 1) * 64;
  int cbase = (wv & 1) * 64;
  int ko = lg * 8;

  size_t rowoff[4];
#pragma unroll
  for (int rg = 0; rg < 4; rg++) {
    int row = i0 + rbase + rg * 16 + lr;
    if (row > M - 1) row = M - 1;  // clamp: junk rows never stored
    rowoff[rg] = (size_t)row * 128;
  }

  bfv8 bfr[4][4];
#pragma unroll
  for (int cg = 0; cg < 4; cg++)
#pragma unroll
    for (int ks = 0; ks < 4; ks++)
      bfr[cg][ks] = *(const bfv8*)&Wb[(size_t)(cbase + cg * 16 + lr) * 128 + ks * 32 + ko];

  f32x4 acc[4][4] = {};
#pragma unroll
  for (int ks = 0; ks < 4; ks++) {
    bfv8 af[4];
#pragma unroll
    for (int rg = 0; rg < 4; rg++) af[rg] = *(const bfv8*)&A[rowoff[rg] + ks * 32 + ko];
#pragma unroll
    for (int rg = 0; rg < 4; rg++)
#pragma unroll
      for (int cg = 0; cg < 4; cg++)
        acc[rg][cg] =
            __builtin_amdgcn_mfma_f32_16x16x32_bf16(af[rg], bfr[cg][ks], acc[rg][cg], 0, 0, 0);
  }

#pragma unroll
  for (int cg = 0; cg < 4; cg++) {
    int col = cbase + cg * 16 + lr;
    float bv = bias[col];
#pragma unroll
    for (int rg = 0; rg < 4; rg++) {
      int row0 = i0 + rbase + rg * 16 + lg * 4;
#pragma unroll
      for (int j = 0; j < 4; j++) {
        int row = row0 + j;
        if (row < M) Out[(size_t)row * 128 + col] = __float2bfloat16(lrelu(acc[rg][cg][j] + bv));
      }
    }
  }
}

// Fused RGCN conv: Out = X@root + mean_r0(X)@rw0 + mean_r1(X)@rw1 + bias.
// Per 128-row block: edge-parallel gather of neighbor sums into a 64KB fp32 LDS tile
// (atomics; CSR is dst-contiguous per rel so the block's edges are one elist slice),
// then MFMA with inv-scaled bf16 fragments. LDS tile XOR-swizzled: byte ^= (m&7)<<4
// (row-major [128][128] f32 @512B stride is a 16-way bank conflict otherwise; swizzle -> 2-way).
__global__ __launch_bounds__(256, 2) void mfma_conv_f(
    const bf16* __restrict__ X, const int* __restrict__ off, const int* __restrict__ cnt,
    const int* __restrict__ elist, const float* __restrict__ inv,
    const bf16* __restrict__ WB, const float* __restrict__ bias, bf16* __restrict__ Out,
    int M, int NNr) {
  __shared__ __align__(16) float At[128 * 128];
  int t = threadIdx.x;
  int wv = t >> 6, l = t & 63;
  int lr = l & 15, lg = l >> 4;
  int i0 = blockIdx.x * 128;
  int rbase = (wv >> 1) * 64;
  int cbase = (wv & 1) * 64;
  int ko = lg * 8;

  // zero LDS tile
  {
    float4 z = {0.f, 0.f, 0.f, 0.f};
#pragma unroll
    for (int i = 0; i < 16; i++) *(float4*)&At[i * 1024 + t * 4] = z;
  }

  size_t rowoff[4];
  f32x4 inv0, inv1;
#pragma unroll
  for (int rg = 0; rg < 4; rg++) {
    int row = i0 + rbase + rg * 16 + lr;
    int rc = row < M ? row : M - 1;
    rowoff[rg] = (size_t)rc * 128;
    inv0[rg] = row < M ? inv[row] : 0.f;
    inv1[rg] = row < M ? inv[NNr + row] : 0.f;
  }
  int iend = (i0 + 128 < M) ? i0 + 128 : M;
  __syncthreads();

  f32x4 acc[4][4] = {};

  // ---- issue rel-0 gather atomics (completion deferred to the barrier) ----
  {
    int e0 = off[i0];
    int e1 = off[iend - 1] + cnt[iend - 1];
    int nw = (e1 - e0) * 16;
    for (int w = t; w < nw; w += 256) {
      int e = e0 + (w >> 4);
      unsigned wd = (unsigned)elist[e];
      int src = wd & 0xFFFFFF;
      int m = (int)(wd >> 24);
      int c0 = (w & 15) * 8;
      bfv8 v = *(const bfv8*)&X[(size_t)src * 128 + c0];
      int sw = (m & 7) << 4;
      int base = m * 512 + c0 * 4;
#pragma unroll
      for (int j = 0; j < 8; j++)
        atomicAdd((float*)((char*)At + ((base + j * 4) ^ sw)), __bfloat162float(v[j]));
    }
  }

  // ---- seg 0: X @ root from global (overlaps atomic latency) ----
#pragma unroll
  for (int ks = 0; ks < 4; ks++) {
    bfv8 bk[4];
#pragma unroll
    for (int cg = 0; cg < 4; cg++)
      bk[cg] = *(const bfv8*)&WB[(size_t)(cbase + cg * 16 + lr) * 128 + ks * 32 + ko];
    bfv8 af[4];
#pragma unroll
    for (int rg = 0; rg < 4; rg++) af[rg] = *(const bfv8*)&X[rowoff[rg] + ks * 32 + ko];
#pragma unroll
    for (int rg = 0; rg < 4; rg++)
#pragma unroll
      for (int cg = 0; cg < 4; cg++)
        acc[rg][cg] =
            __builtin_amdgcn_mfma_f32_16x16x32_bf16(af[rg], bk[cg], acc[rg][cg], 0, 0, 0);
  }
  __syncthreads();

  // ---- rel-0 MFMA from LDS (inv-scaled, cvt to bf16) ----
#pragma unroll
  for (int ks = 0; ks < 4; ks++) {
    bfv8 bk[4];
#pragma unroll
    for (int cg = 0; cg < 4; cg++)
      bk[cg] = *(const bfv8*)&WB[16384 + (size_t)(cbase + cg * 16 + lr) * 128 + ks * 32 + ko];
    bfv8 af[4];
#pragma unroll
    for (int rg = 0; rg < 4; rg++) {
      int m = rbase + rg * 16 + lr;
      int lb = m * 512 + ks * 128 + ko * 4;
      int sw = (m & 7) << 4;
      float4 f0 = *(const float4*)((const char*)At + (lb ^ sw));
      float4 f1 = *(const float4*)((const char*)At + ((lb + 16) ^ sw));
      float iv = inv0[rg];
      bfv8 a;
      a[0] = (__bf16)(f0.x * iv); a[1] = (__bf16)(f0.y * iv);
      a[2] = (__bf16)(f0.z * iv); a[3] = (__bf16)(f0.w * iv);
      a[4] = (__bf16)(f1.x * iv); a[5] = (__bf16)(f1.y * iv);
      a[6] = (__bf16)(f1.z * iv); a[7] = (__bf16)(f1.w * iv);
      af[rg] = a;
    }
#pragma unroll
    for (int rg = 0; rg < 4; rg++)
#pragma unroll
      for (int cg = 0; cg < 4; cg++)
        acc[rg][cg] =
            __builtin_amdgcn_mfma_f32_16x16x32_bf16(af[rg], bk[cg], acc[rg][cg], 0, 0, 0);
  }
  __syncthreads();

  // zero tile again for rel 1
  {
    float4 z = {0.f, 0.f, 0.f, 0.f};
#pragma unroll
    for (int i = 0; i < 16; i++) *(float4*)&At[i * 1024 + t * 4] = z;
  }
  __syncthreads();

  // ---- rel-1 gather ----
  {
    int e0 = off[NNr + i0];
    int e1 = off[NNr + iend - 1] + cnt[NNr + iend - 1];
    int nw = (e1 - e0) * 16;
    for (int w = t; w < nw; w += 256) {
      int e = e0 + (w >> 4);
      unsigned wd = (unsigned)elist[e];
      int src = wd & 0xFFFFFF;
      int m = (int)(wd >> 24);
      int c0 = (w & 15) * 8;
      bfv8 v = *(const bfv8*)&X[(size_t)src * 128 + c0];
      int sw = (m & 7) << 4;
      int base = m * 512 + c0 * 4;
#pragma unroll
      for (int j = 0; j < 8; j++)
        atomicAdd((float*)((char*)At + ((base + j * 4) ^ sw)), __bfloat162float(v[j]));
    }
  }
  __syncthreads();

  // ---- rel-1 MFMA from LDS ----
#pragma unroll
  for (int ks = 0; ks < 4; ks++) {
    bfv8 bk[4];
#pragma unroll
    for (int cg = 0; cg < 4; cg++)
      bk[cg] = *(const bfv8*)&WB[32768 + (size_t)(cbase + cg * 16 + lr) * 128 + ks * 32 + ko];
    bfv8 af[4];
#pragma unroll
    for (int rg = 0; rg < 4; rg++) {
      int m = rbase + rg * 16 + lr;
      int lb = m * 512 + ks * 128 + ko * 4;
      int sw = (m & 7) << 4;
      float4 f0 = *(const float4*)((const char*)At + (lb ^ sw));
      float4 f1 = *(const float4*)((const char*)At + ((lb + 16) ^ sw));
      float iv = inv1[rg];
      bfv8 a;
      a[0] = (__bf16)(f0.x * iv); a[1] = (__bf16)(f0.y * iv);
      a[2] = (__bf16)(f0.z * iv); a[3] = (__bf16)(f0.w * iv);
      a[4] = (__bf16)(f1.x * iv); a[5] = (__bf16)(f1.y * iv);
      a[6] = (__bf16)(f1.z * iv); a[7] = (__bf16)(f1.w * iv);
      af[rg] = a;
    }
#pragma unroll
    for (int rg = 0; rg < 4; rg++)
#pragma unroll
      for (int cg = 0; cg < 4; cg++)
        acc[rg][cg] =
            __builtin_amdgcn_mfma_f32_16x16x32_bf16(af[rg], bk[cg], acc[rg][cg], 0, 0, 0);
  }

  // ---- epilogue: + bias, no activation ----
#pragma unroll
  for (int cg = 0; cg < 4; cg++) {
    int col = cbase + cg * 16 + lr;
    float bv = bias[col];
#pragma unroll
    for (int rg = 0; rg < 4; rg++) {
      int row0 = i0 + rbase + rg * 16 + lg * 4;
#pragma unroll
      for (int j = 0; j < 4; j++) {
        int row = row0 + j;
        if (row < M) Out[(size_t)row * 128 + col] = __float2bfloat16(acc[rg][cg][j] + bv);
      }
    }
  }
}

// ---------------- final 128 -> 2 linear, FP32 out ----------------
__global__ void out_linear(const bf16* __restrict__ x, const float* __restrict__ W,
                           const float* __restrict__ B, float* __restrict__ out, int NNr) {
  int wave = threadIdx.x >> 6;
  int lane = threadIdx.x & 63;
  int i = blockIdx.x * 4 + wave;
  if (i >= NNr) return;
  const bf16* xr = x + (size_t)i * 128;
  float x0 = ldv(xr[lane]);
  float x1 = ldv(xr[lane + 64]);
  float p0 = x0 * W[lane] + x1 * W[lane + 64];
  float p1 = x0 * W[128 + lane] + x1 * W[128 + lane + 64];
#pragma unroll
  for (int offs = 32; offs; offs >>= 1) {
    p0 += __shfl_down(p0, offs, 64);
    p1 += __shfl_down(p1, offs, 64);
  }
  if (lane == 0) {
    out[(size_t)i * 2] = p0 + B[0];
    out[(size_t)i * 2 + 1] = p1 + B[1];
  }
}

// ---------------- pipeline (bf16 storage, MFMA everywhere) ----------------
static void run_pipeline(void* const* d_in, const int* S, float* out, char* ws,
                         int NUr, int NTr, int NEr, int dDes, int dNum, int dCat, int dTw,
                         hipStream_t stream) {
  const int NNr = NUr + NTr;
  const size_t xbytes = (size_t)NNr * 128 * 2;

  bf16* xa = (bf16*)ws;
  bf16* xb = (bf16*)(ws + xbytes);
  char* p = ws + 2 * xbytes;
  int* cnt = (int*)p;      p += (size_t)2 * NNr * 4;
  int* fill = (int*)p;     p += (size_t)2 * NNr * 4;  // contiguous with cnt
  int* off = (int*)p;      p += (size_t)2 * NNr * 4;
  int* bsum = (int*)p;     p += 2048 * 4;             // contiguous with bsumsc
  int* bsumsc = (int*)p;   p += 2048 * 4;
  float* inv = (float*)p;  p += (size_t)2 * NNr * 4;
  int* elist = (int*)p;    p += (size_t)NEr * 4;
  float* pw = (float*)p;   p += (size_t)PW_TOTAL * 4;
  int* flags = (int*)p;

  // ---- format probes: one launch ----
  ProbeArgs pa;
  for (int i = 0; i < 23; i++) {
    int src = (i == 22) ? 21 : i;  // b_o2 (2 elems) inherits W_o2's dtype
    pa.p[i] = d_in[src];
    if (i == 4) {
      pa.mode[i] = 1;
      pa.s[i] = NEr < 256 ? NEr : 256;
    } else if (i == 5) {
      pa.mode[i] = 1;
      int s2 = NEr / 2 < 256 ? NEr / 2 : 256;
      pa.s[i] = s2 < 1 ? 1 : s2;
    } else {
      pa.mode[i] = 0;
      int s = S[src] / 2;
      if (s > 256) s = 256;
      if (s < 1) s = 1;
      pa.s[i] = s;
    }
  }
  detect_all<<<23, 256, 0, stream>>>(pa, flags);
  prep_weights<<<(PW_TOTAL + 255) / 256, 256, 0, stream>>>(
      d_in[14], d_in[15], d_in[16], d_in[17], d_in[18], d_in[19], d_in[20], d_in[21],
      d_in[22], flags, pw);

  const float* bIn = pw + 81920;
  const float* rbp = pw + 82048;
  const float* bO1 = pw + 82176;
  const float* Wo2p = pw + 82304;
  const float* bo2p = pw + 82560;
  const bf16* WinB = (const bf16*)(pw + BF_BASE);
  const bf16* Wo1B = (const bf16*)(pw + BF_BASE + 8192);
  const bf16* ConvB = (const bf16*)(pw + BF_BASE + 16384);  // rootB, rwB0, rwB1

  const void* ei = d_in[4];
  const void* et = d_in[5];
  const int nb1 = (2 * NNr + 1023) / 1024;

  // ---- CSR build ----
  zero_ints<<<(4 * NNr + 255) / 256, 256, 0, stream>>>(cnt, 4 * NNr);
  zero_ints<<<16, 256, 0, stream>>>(bsum, 4096);
  count_edges<<<(NEr + 255) / 256, 256, 0, stream>>>(ei, et, flags, cnt, NEr, NNr);
  scan_blocks<<<nb1, 256, 0, stream>>>(cnt, off, bsum, 2 * NNr);
  scan_blocks<<<1, 256, 0, stream>>>(bsum, bsumsc, nullptr, nb1);
  scan_add_inv<<<(2 * NNr + 255) / 256, 256, 0, stream>>>(off, bsumsc, cnt, inv, 2 * NNr);
  fill_elist<<<(NEr + 255) / 256, 256, 0, stream>>>(ei, et, flags, off, fill, elist, NEr, NNr);

  // ---- encoders -> xa ----
  enc_gemm<<<(NUr + 63) / 64, 256, 0, stream>>>(d_in[0], d_in[6], d_in[7], flags, 0, 6, 7,
                                                xa, NUr, dDes, 64, 0, 0);
  enc_gemm<<<(NUr + 63) / 64, 256, 0, stream>>>(d_in[2], d_in[8], d_in[9], flags, 2, 8, 9,
                                                xa, NUr, dNum, 32, 0, 64);
  enc_gemm<<<(NUr + 63) / 64, 256, 0, stream>>>(d_in[3], d_in[10], d_in[11], flags, 3, 10,
                                                11, xa, NUr, dCat, 32, 0, 96);
  enc_gemm<<<(NTr + 63) / 64, 256, 0, stream>>>(d_in[1], d_in[12], d_in[13], flags, 1, 12,
                                                13, xa, NTr, dTw, 128, NUr, 0);

  const int mt = (NNr + 127) / 128;
  mfma_lin<<<mt, 256, 0, stream>>>(xa, WinB, bIn, xb, NNr);
  mfma_conv_f<<<mt, 256, 0, stream>>>(xb, off, cnt, elist, inv, ConvB, rbp, xa, NNr, NNr);
  mfma_conv_f<<<mt, 256, 0, stream>>>(xa, off, cnt, elist, inv, ConvB, rbp, xb, NNr, NNr);
  mfma_lin<<<mt, 256, 0, stream>>>(xb, Wo1B, bO1, xa, NNr);
  out_linear<<<(NNr + 3) / 4, 256, 0, stream>>>(xa, Wo2p, bo2p, out, NNr);
}

extern "C" void kernel_launch(void* const* d_in, const int* in_sizes, int n_in,
                              void* d_out, int out_size, void* d_ws, size_t ws_size,
                              hipStream_t stream) {
  float* out = (float*)d_out;
  char* ws = (char*)d_ws;

  auto signal = [&](int k) {
    sig_fill<<<(out_size + 255) / 256, 256, 0, stream>>>(out, out_size, (float)(200 + k));
  };

  if (n_in != 23) { signal(1); return; }
  const int* S = in_sizes;
  if (S[7] != 64 || S[9] != 32 || S[11] != 32 || S[13] != 128) { signal(2); return; }
  if (S[15] != 128) { signal(3); return; }
  if (S[6] % 64 || S[8] % 32 || S[10] % 32 || S[12] % 128) { signal(4); return; }
  int dDes = S[6] / 64, dNum = S[8] / 32, dCat = S[10] / 32, dTw = S[12] / 128;
  if (dDes <= 0 || dTw <= 0 || S[0] % dDes || S[1] % dTw) { signal(5); return; }
  if (dDes > 101 || dNum > 101 || dCat > 101 || dTw > 101) { signal(4); return; }
  int NUr = S[0] / dDes, NTr = S[1] / dTw, NNr = NUr + NTr, NEr = S[5];
  if (S[2] != NUr * dNum || S[3] != NUr * dCat) { signal(5); return; }
  if (S[4] != 2 * NEr || NEr < 1024) { signal(6); return; }
  if (NNr >= (1 << 24)) { signal(6); return; }  // elist src-packing limit
  if (S[14] != 16384 || S[16] != 32768 || S[17] != 16384 || S[18] != 128 ||
      S[19] != 16384 || S[20] != 128 || S[21] != 256 || S[22] != 2) { signal(7); return; }
  if (out_size != NNr * 2) { signal(8); return; }

  const size_t smallBytes = (size_t)4 * ((size_t)2 * NNr * 4) + 2 * 2048 * 4 +
                            (size_t)NEr * 4 + (size_t)PW_TOTAL * 4 + 512;
  const size_t need = 2 * (size_t)NNr * 128 * 2 + smallBytes;

  if (ws_size >= need) {
    run_pipeline(d_in, S, out, ws, NUr, NTr, NEr, dDes, dNum, dCat, dTw, stream);
  } else {
    signal(9);
  }
}

// Round 3
// 1555.304 us; speedup vs baseline: 2.1198x; 1.0802x over previous
//
#include <hip/hip_runtime.h>
#include <hip/hip_bf16.h>

typedef __hip_bfloat16 bf16;

typedef __bf16 bfv8 __attribute__((ext_vector_type(8)));
typedef float f32x4 __attribute__((ext_vector_type(4)));

__device__ __forceinline__ float lrelu(float x) { return x > 0.f ? x : 0.01f * x; }

__device__ __forceinline__ float ldv(float v) { return v; }
__device__ __forceinline__ float ldv(bf16 v) { return __bfloat162float(v); }
__device__ __forceinline__ void stv(float* p, float v) { *p = v; }
__device__ __forceinline__ void stv(bf16* p, float v) { *p = __float2bfloat16(v); }

__device__ __forceinline__ float in_rd(const void* p, size_t i, int isbf) {
  return isbf ? __bfloat162float(((const bf16*)p)[i]) : ((const float*)p)[i];
}
__device__ __forceinline__ int ix_rd(const void* p, size_t i, int is64) {
  return is64 ? (int)((const long long*)p)[i] : ((const int*)p)[i];
}

// ---------------- fused per-array format probe: one launch, 23 blocks ----------------
struct ProbeArgs {
  const void* p[23];
  int s[23];
  int mode[23];
};

__global__ void detect_all(ProbeArgs a, int* __restrict__ flags) {
  __shared__ int sh[256];
  int b = blockIdx.x;
  const unsigned int* w = (const unsigned int*)a.p[b];
  int s = a.s[b], mode = a.mode[b];
  int t = threadIdx.x;
  int c = 0;
  if (t < s) {
    if (mode == 0) {
      unsigned int v = w[t];
      int e = (v >> 7) & 0xFF;
      c = (e >= 100 && e <= 140) ? 1 : 0;
    } else {
      c = (w[2 * t + 1] == 0u) ? 1 : 0;
    }
  }
  sh[t] = c;
  __syncthreads();
  for (int d = 128; d; d >>= 1) {
    if (t < d) sh[t] += sh[t + d];
    __syncthreads();
  }
  if (t == 0) flags[b] = (mode == 0) ? (sh[0] * 10 >= 7 * s) : (sh[0] * 10 >= 9 * s);
}

// ---------------- weight prep ----------------
// fp32 region (floats): [0,16384) W_inT [k,n]; [16384,32768) W_o1T [k,n]; [32768,49152) root;
// [49152,81920) rw; [81920] b_in; [82048] rgcn_bias; [82176] b_o1; [82304] W_o2; [82560] b_o2
// bf16 region (starting at float index BF_BASE, 16B aligned), each [128][128] bf16 in
// [n][k] (out,in) layout for MFMA B-fragments:
//   m=0 WinB; m=1 Wo1B; m=2 rootB; m=3 rwB0; m=4 rwB1   (rootB,rwB0,rwB1 contiguous)
#define PW_F32 82562
#define BF_BASE 82564
#define PW_TOTAL (BF_BASE + 5 * 8192)
__global__ void prep_weights(const void* Win, const void* bin, const void* rw,
                             const void* root, const void* rb, const void* Wo1,
                             const void* bo1, const void* Wo2, const void* bo2,
                             const int* __restrict__ fl, float* __restrict__ pw) {
  int i = blockIdx.x * 256 + threadIdx.x;
  if (i >= PW_TOTAL) return;
  if (i < 16384) {
    int k = i >> 7, o = i & 127;
    pw[i] = in_rd(Win, (size_t)o * 128 + k, fl[14]);
  } else if (i < 32768) {
    int j = i - 16384;
    int k = j >> 7, o = j & 127;
    pw[i] = in_rd(Wo1, (size_t)o * 128 + k, fl[19]);
  } else if (i < 49152) {
    pw[i] = in_rd(root, i - 32768, fl[17]);
  } else if (i < 81920) {
    pw[i] = in_rd(rw, i - 49152, fl[16]);
  } else if (i < 82048) {
    pw[i] = in_rd(bin, i - 81920, fl[15]);
  } else if (i < 82176) {
    pw[i] = in_rd(rb, i - 82048, fl[18]);
  } else if (i < 82304) {
    pw[i] = in_rd(bo1, i - 82176, fl[20]);
  } else if (i < 82560) {
    pw[i] = in_rd(Wo2, i - 82304, fl[21]);
  } else if (i < PW_F32) {
    pw[i] = in_rd(bo2, i - 82560, fl[22]);
  } else if (i >= BF_BASE) {
    int j = i - BF_BASE;
    bf16* bw = (bf16*)(pw + BF_BASE);
#pragma unroll
    for (int q = 0; q < 2; q++) {
      int u = 2 * j + q;
      int m = u >> 14, r = u & 16383;
      int n = r >> 7, k = r & 127;
      float v;
      if (m == 0) v = in_rd(Win, (size_t)n * 128 + k, fl[14]);
      else if (m == 1) v = in_rd(Wo1, (size_t)n * 128 + k, fl[19]);
      else if (m == 2) v = in_rd(root, (size_t)k * 128 + n, fl[17]);
      else v = in_rd(rw, (size_t)(m - 3) * 16384 + (size_t)k * 128 + n, fl[16]);
      bw[u] = __float2bfloat16(v);
    }
  }
}

// ---------------- utilities ----------------
__global__ void sig_fill(float* __restrict__ p, int n, float v) {
  int i = blockIdx.x * 256 + threadIdx.x;
  if (i < n) p[i] = v;
}
__global__ void zero_ints(int* __restrict__ p, int n) {
  int i = blockIdx.x * 256 + threadIdx.x;
  if (i < n) p[i] = 0;
}

// ---------------- CSR build ----------------
__global__ void count_edges(const void* __restrict__ ei, const void* __restrict__ et,
                            const int* __restrict__ fl, int* __restrict__ cnt, int NEr,
                            int NNr) {
  int e = blockIdx.x * 256 + threadIdx.x;
  if (e >= NEr) return;
  int d = ix_rd(ei, (size_t)NEr + e, fl[4]);
  int r = ix_rd(et, e, fl[5]) & 1;
  if ((unsigned)d >= (unsigned)NNr) return;
  atomicAdd(&cnt[r * NNr + d], 1);
}

__global__ void scan_blocks(const int* __restrict__ in, int* __restrict__ out,
                            int* __restrict__ bsum, int n) {
  __shared__ int sh[256];
  int t = threadIdx.x;
  int base = blockIdx.x * 1024 + t * 4;
  int a[4];
  int s = 0;
#pragma unroll
  for (int i = 0; i < 4; i++) {
    a[i] = (base + i < n) ? in[base + i] : 0;
    s += a[i];
  }
  sh[t] = s;
  __syncthreads();
  for (int d = 1; d < 256; d <<= 1) {
    int v = (t >= d) ? sh[t - d] : 0;
    __syncthreads();
    sh[t] += v;
    __syncthreads();
  }
  int ex = sh[t] - s;
#pragma unroll
  for (int i = 0; i < 4; i++) {
    if (base + i < n) out[base + i] = ex;
    ex += a[i];
  }
  if (t == 255 && bsum) bsum[blockIdx.x] = sh[255];
}

__global__ void scan_add_inv(int* __restrict__ off, const int* __restrict__ bsumsc,
                             const int* __restrict__ cnt, float* __restrict__ inv, int n) {
  int i = blockIdx.x * 256 + threadIdx.x;
  if (i >= n) return;
  off[i] += bsumsc[i >> 10];
  inv[i] = 1.f / fmaxf((float)cnt[i], 1.f);
}

// elist word packs: bits [0,24) = src node id, bits [24,31) = dst & 127 (row within tile)
__global__ void fill_elist(const void* __restrict__ ei, const void* __restrict__ et,
                           const int* __restrict__ fl, const int* __restrict__ off,
                           int* __restrict__ fill, int* __restrict__ elist, int NEr, int NNr) {
  int e = blockIdx.x * 256 + threadIdx.x;
  if (e >= NEr) return;
  int s = ix_rd(ei, e, fl[4]);
  int d = ix_rd(ei, (size_t)NEr + e, fl[4]);
  int r = ix_rd(et, e, fl[5]) & 1;
  if ((unsigned)d >= (unsigned)NNr || (unsigned)s >= (unsigned)NNr) return;
  int idx = r * NNr + d;
  int slot = off[idx] + atomicAdd(&fill[idx], 1);
  elist[slot] = s | ((d & 127) << 24);
}

// ---------------- encoder GEMM ----------------
__global__ __launch_bounds__(256) void enc_gemm(const void* __restrict__ A,
                                                const void* __restrict__ W,
                                                const void* __restrict__ B,
                                                const int* __restrict__ fl, int fa, int fw,
                                                int fb, bf16* __restrict__ x, int M, int K,
                                                int N, int row0, int col0) {
  __shared__ float Wb[128 * 102];
  __shared__ float bb[128];
  int t = threadIdx.x;
  int stride = (K & 1) ? K : K + 1;
  int fA = fl[fa];
  {
    int fW = fl[fw], fB = fl[fb];
    for (int idx = t; idx < N * K; idx += 256) {
      int j = idx / K, k = idx - j * K;
      Wb[j * stride + k] = in_rd(W, (size_t)j * K + k, fW);
    }
    if (t < N) bb[t] = in_rd(B, t, fB);
  }
  __syncthreads();
  int j = t % N;
  int r = t / N;
  int R = 256 / N;
  int iEnd = blockIdx.x * 64 + 64;
  if (iEnd > M) iEnd = M;
  const float* wrow = &Wb[j * stride];
  if (!fA) {
    const float* Af = (const float*)A;
    for (int i = blockIdx.x * 64 + r; i < iEnd; i += R) {
      const float* a = Af + (size_t)i * K;
      float acc = bb[j];
      for (int k = 0; k < K; k++) acc += a[k] * wrow[k];
      stv(&x[(size_t)(row0 + i) * 128 + col0 + j], lrelu(acc));
    }
  } else {
    const bf16* Ab = (const bf16*)A;
    for (int i = blockIdx.x * 64 + r; i < iEnd; i += R) {
      const bf16* a = Ab + (size_t)i * K;
      float acc = bb[j];
      for (int k = 0; k < K; k++) acc += __bfloat162float(a[k]) * wrow[k];
      stv(&x[(size_t)(row0 + i) * 128 + col0 + j], lrelu(acc));
    }
  }
}

// ================= MFMA GEMMs (bf16 storage, fp32 accumulate) =================
// v_mfma_f32_16x16x32_bf16 fragments (m89/m91-verified C/D mapping):
//   A: lane l holds A[m = l&15][k = (l>>4)*8 + i]
//   B: lane l holds B[k = (l>>4)*8 + i][n = l&15]  (= Wt[n][k] with Wt in [out][in] layout)
//   D: lane l reg j -> row = (l>>4)*4 + j, col = l&15

// Out = lrelu(A @ Wb^T + bias); A,Out bf16 [M][128]; Wb bf16 [out][in]
// Block = 128 rows x 128 cols; 4 waves 2x2; wave = 64x64 (4x4 fragments).
__global__ __launch_bounds__(256) void mfma_lin(const bf16* __restrict__ A,
                                                const bf16* __restrict__ Wb,
                                                const float* __restrict__ bias,
                                                bf16* __restrict__ Out, int M) {
  int t = threadIdx.x;
  int wv = t >> 6, l = t & 63;
  int lr = l & 15, lg = l >> 4;
  int i0 = blockIdx.x * 128;
  int rbase = (wv >> 1) * 64;
  int cbase = (wv & 1) * 64;
  int ko = lg * 8;

  size_t rowoff[4];
#pragma unroll
  for (int rg = 0; rg < 4; rg++) {
    int row = i0 + rbase + rg * 16 + lr;
    if (row > M - 1) row = M - 1;  // clamp: junk rows never stored
    rowoff[rg] = (size_t)row * 128;
  }

  bfv8 bfr[4][4];
#pragma unroll
  for (int cg = 0; cg < 4; cg++)
#pragma unroll
    for (int ks = 0; ks < 4; ks++)
      bfr[cg][ks] = *(const bfv8*)&Wb[(size_t)(cbase + cg * 16 + lr) * 128 + ks * 32 + ko];

  f32x4 acc[4][4] = {};
#pragma unroll
  for (int ks = 0; ks < 4; ks++) {
    bfv8 af[4];
#pragma unroll
    for (int rg = 0; rg < 4; rg++) af[rg] = *(const bfv8*)&A[rowoff[rg] + ks * 32 + ko];
#pragma unroll
    for (int rg = 0; rg < 4; rg++)
#pragma unroll
      for (int cg = 0; cg < 4; cg++)
        acc[rg][cg] =
            __builtin_amdgcn_mfma_f32_16x16x32_bf16(af[rg], bfr[cg][ks], acc[rg][cg], 0, 0, 0);
  }

#pragma unroll
  for (int cg = 0; cg < 4; cg++) {
    int col = cbase + cg * 16 + lr;
    float bv = bias[col];
#pragma unroll
    for (int rg = 0; rg < 4; rg++) {
      int row0 = i0 + rbase + rg * 16 + lg * 4;
#pragma unroll
      for (int j = 0; j < 4; j++) {
        int row = row0 + j;
        if (row < M) Out[(size_t)row * 128 + col] = __float2bfloat16(lrelu(acc[rg][cg][j] + bv));
      }
    }
  }
}

// Fused RGCN conv: Out = X@root + mean_r0(X)@rw0 + mean_r1(X)@rw1 + bias.
// 32-row blocks, BOTH relations in one 32KB fp32 LDS tile (rows 0-31 rel0, 32-63 rel1)
// -> 4 blocks/CU (16 waves, 50% occ cap) and only 2 barriers per block.
// Gather is depth-2 software-pipelined: next iteration's elist+X loads issue before the
// current iteration's LDS atomics consume, keeping 2 loads/wave in flight.
// LDS XOR-swizzle byte ^= (row&7)<<4 (512B-stride rows otherwise 16-way conflict).
__global__ __launch_bounds__(256, 4) void mfma_conv_f(
    const bf16* __restrict__ X, const int* __restrict__ off, const int* __restrict__ cnt,
    const int* __restrict__ elist, const float* __restrict__ inv,
    const bf16* __restrict__ WB, const float* __restrict__ bias, bf16* __restrict__ Out,
    int M, int NNr) {
  __shared__ __align__(16) float At[64 * 128];
  int t = threadIdx.x;
  int wv = t >> 6, l = t & 63;
  int lr = l & 15, lg = l >> 4;
  int i0 = blockIdx.x * 32;
  int cbase = wv * 32;
  int ko = lg * 8;

  // zero tile (32KB / 256 threads = 8 float4 each)
  {
    float4 z = {0.f, 0.f, 0.f, 0.f};
#pragma unroll
    for (int i = 0; i < 8; i++) *(float4*)&At[i * 1024 + t * 4] = z;
  }

  int iend = (i0 + 32 < M) ? i0 + 32 : M;
  int e0a = off[i0];
  int n0 = off[iend - 1] + cnt[iend - 1] - e0a;
  int e0b = off[NNr + i0];
  int n1 = off[NNr + iend - 1] + cnt[NNr + iend - 1] - e0b;
  __syncthreads();

  // ---- combined-rel gather, depth-2 pipelined ----
  {
    int nw = (n0 + n1) * 16;
    auto ldw = [&](int w_) -> unsigned {
      int ei = w_ >> 4;
      return (unsigned)(ei < n0 ? elist[e0a + ei] : elist[e0b + ei - n0]);
    };
    int w = t;
    unsigned wd = 0;
    bfv8 v = {};
    if (w < nw) {
      wd = ldw(w);
      v = *(const bfv8*)&X[(size_t)(wd & 0xFFFFFF) * 128 + (w & 15) * 8];
    }
    while (w < nw) {
      int w2 = w + 256;
      unsigned wd2 = 0;
      bfv8 v2 = {};
      if (w2 < nw) {
        wd2 = ldw(w2);
        v2 = *(const bfv8*)&X[(size_t)(wd2 & 0xFFFFFF) * 128 + (w2 & 15) * 8];
      }
      {
        int m = (int)(wd >> 24) & 31;
        int mrow = ((w >> 4) < n0) ? m : 32 + m;
        int c0 = (w & 15) * 8;
        int sw = (mrow & 7) << 4;
        int base = mrow * 512 + c0 * 4;
#pragma unroll
        for (int j = 0; j < 8; j++)
          atomicAdd((float*)((char*)At + ((base + j * 4) ^ sw)), __bfloat162float(v[j]));
      }
      w = w2;
      wd = wd2;
      v = v2;
    }
  }

  // row clamps and inv scales
  size_t rowoff[2];
  float iv0[2], iv1[2];
#pragma unroll
  for (int rg = 0; rg < 2; rg++) {
    int row = i0 + rg * 16 + lr;
    int rc = row < M ? row : M - 1;
    rowoff[rg] = (size_t)rc * 128;
    iv0[rg] = row < M ? inv[row] : 0.f;
    iv1[rg] = row < M ? inv[NNr + row] : 0.f;
  }

  f32x4 acc[2][2] = {};

  // ---- seg 0: X @ root from global (overlaps outstanding gather atomics) ----
#pragma unroll
  for (int ks = 0; ks < 4; ks++) {
    bfv8 bk[2];
#pragma unroll
    for (int cg = 0; cg < 2; cg++)
      bk[cg] = *(const bfv8*)&WB[(size_t)(cbase + cg * 16 + lr) * 128 + ks * 32 + ko];
    bfv8 af[2];
#pragma unroll
    for (int rg = 0; rg < 2; rg++) af[rg] = *(const bfv8*)&X[rowoff[rg] + ks * 32 + ko];
#pragma unroll
    for (int rg = 0; rg < 2; rg++)
#pragma unroll
      for (int cg = 0; cg < 2; cg++)
        acc[rg][cg] =
            __builtin_amdgcn_mfma_f32_16x16x32_bf16(af[rg], bk[cg], acc[rg][cg], 0, 0, 0);
  }
  __syncthreads();

  // ---- rel-0 / rel-1 MFMA from LDS (inv-scaled, cvt to bf16) ----
#pragma unroll
  for (int r = 0; r < 2; r++) {
    const bf16* Wb = WB + 16384 * (1 + r);
#pragma unroll
    for (int ks = 0; ks < 4; ks++) {
      bfv8 bk[2];
#pragma unroll
      for (int cg = 0; cg < 2; cg++)
        bk[cg] = *(const bfv8*)&Wb[(size_t)(cbase + cg * 16 + lr) * 128 + ks * 32 + ko];
      bfv8 af[2];
#pragma unroll
      for (int rg = 0; rg < 2; rg++) {
        int mrow = r * 32 + rg * 16 + lr;
        int lb = mrow * 512 + ks * 128 + ko * 4;
        int sw = (mrow & 7) << 4;
        float4 f0 = *(const float4*)((const char*)At + (lb ^ sw));
        float4 f1 = *(const float4*)((const char*)At + ((lb + 16) ^ sw));
        float iv = r ? iv1[rg] : iv0[rg];
        bfv8 a;
        a[0] = (__bf16)(f0.x * iv); a[1] = (__bf16)(f0.y * iv);
        a[2] = (__bf16)(f0.z * iv); a[3] = (__bf16)(f0.w * iv);
        a[4] = (__bf16)(f1.x * iv); a[5] = (__bf16)(f1.y * iv);
        a[6] = (__bf16)(f1.z * iv); a[7] = (__bf16)(f1.w * iv);
        af[rg] = a;
      }
#pragma unroll
      for (int rg = 0; rg < 2; rg++)
#pragma unroll
        for (int cg = 0; cg < 2; cg++)
          acc[rg][cg] =
              __builtin_amdgcn_mfma_f32_16x16x32_bf16(af[rg], bk[cg], acc[rg][cg], 0, 0, 0);
    }
  }

  // ---- epilogue: + bias, no activation ----
#pragma unroll
  for (int cg = 0; cg < 2; cg++) {
    int col = cbase + cg * 16 + lr;
    float bv = bias[col];
#pragma unroll
    for (int rg = 0; rg < 2; rg++) {
      int row0 = i0 + rg * 16 + lg * 4;
#pragma unroll
      for (int j = 0; j < 4; j++) {
        int row = row0 + j;
        if (row < M) Out[(size_t)row * 128 + col] = __float2bfloat16(acc[rg][cg][j] + bv);
      }
    }
  }
}

// ---------------- final 128 -> 2 linear, FP32 out ----------------
__global__ void out_linear(const bf16* __restrict__ x, const float* __restrict__ W,
                           const float* __restrict__ B, float* __restrict__ out, int NNr) {
  int wave = threadIdx.x >> 6;
  int lane = threadIdx.x & 63;
  int i = blockIdx.x * 4 + wave;
  if (i >= NNr) return;
  const bf16* xr = x + (size_t)i * 128;
  float x0 = ldv(xr[lane]);
  float x1 = ldv(xr[lane + 64]);
  float p0 = x0 * W[lane] + x1 * W[lane + 64];
  float p1 = x0 * W[128 + lane] + x1 * W[128 + lane + 64];
#pragma unroll
  for (int offs = 32; offs; offs >>= 1) {
    p0 += __shfl_down(p0, offs, 64);
    p1 += __shfl_down(p1, offs, 64);
  }
  if (lane == 0) {
    out[(size_t)i * 2] = p0 + B[0];
    out[(size_t)i * 2 + 1] = p1 + B[1];
  }
}

// ---------------- pipeline (bf16 storage, MFMA everywhere) ----------------
static void run_pipeline(void* const* d_in, const int* S, float* out, char* ws,
                         int NUr, int NTr, int NEr, int dDes, int dNum, int dCat, int dTw,
                         hipStream_t stream) {
  const int NNr = NUr + NTr;
  const size_t xbytes = (size_t)NNr * 128 * 2;

  bf16* xa = (bf16*)ws;
  bf16* xb = (bf16*)(ws + xbytes);
  char* p = ws + 2 * xbytes;
  int* cnt = (int*)p;      p += (size_t)2 * NNr * 4;
  int* fill = (int*)p;     p += (size_t)2 * NNr * 4;  // contiguous with cnt
  int* off = (int*)p;      p += (size_t)2 * NNr * 4;
  int* bsum = (int*)p;     p += 2048 * 4;             // contiguous with bsumsc
  int* bsumsc = (int*)p;   p += 2048 * 4;
  float* inv = (float*)p;  p += (size_t)2 * NNr * 4;
  int* elist = (int*)p;    p += (size_t)NEr * 4;
  float* pw = (float*)p;   p += (size_t)PW_TOTAL * 4;
  int* flags = (int*)p;

  // ---- format probes: one launch ----
  ProbeArgs pa;
  for (int i = 0; i < 23; i++) {
    int src = (i == 22) ? 21 : i;  // b_o2 (2 elems) inherits W_o2's dtype
    pa.p[i] = d_in[src];
    if (i == 4) {
      pa.mode[i] = 1;
      pa.s[i] = NEr < 256 ? NEr : 256;
    } else if (i == 5) {
      pa.mode[i] = 1;
      int s2 = NEr / 2 < 256 ? NEr / 2 : 256;
      pa.s[i] = s2 < 1 ? 1 : s2;
    } else {
      pa.mode[i] = 0;
      int s = S[src] / 2;
      if (s > 256) s = 256;
      if (s < 1) s = 1;
      pa.s[i] = s;
    }
  }
  detect_all<<<23, 256, 0, stream>>>(pa, flags);
  prep_weights<<<(PW_TOTAL + 255) / 256, 256, 0, stream>>>(
      d_in[14], d_in[15], d_in[16], d_in[17], d_in[18], d_in[19], d_in[20], d_in[21],
      d_in[22], flags, pw);

  const float* bIn = pw + 81920;
  const float* rbp = pw + 82048;
  const float* bO1 = pw + 82176;
  const float* Wo2p = pw + 82304;
  const float* bo2p = pw + 82560;
  const bf16* WinB = (const bf16*)(pw + BF_BASE);
  const bf16* Wo1B = (const bf16*)(pw + BF_BASE + 8192);
  const bf16* ConvB = (const bf16*)(pw + BF_BASE + 16384);  // rootB, rwB0, rwB1

  const void* ei = d_in[4];
  const void* et = d_in[5];
  const int nb1 = (2 * NNr + 1023) / 1024;

  // ---- CSR build ----
  zero_ints<<<(4 * NNr + 255) / 256, 256, 0, stream>>>(cnt, 4 * NNr);
  zero_ints<<<16, 256, 0, stream>>>(bsum, 4096);
  count_edges<<<(NEr + 255) / 256, 256, 0, stream>>>(ei, et, flags, cnt, NEr, NNr);
  scan_blocks<<<nb1, 256, 0, stream>>>(cnt, off, bsum, 2 * NNr);
  scan_blocks<<<1, 256, 0, stream>>>(bsum, bsumsc, nullptr, nb1);
  scan_add_inv<<<(2 * NNr + 255) / 256, 256, 0, stream>>>(off, bsumsc, cnt, inv, 2 * NNr);
  fill_elist<<<(NEr + 255) / 256, 256, 0, stream>>>(ei, et, flags, off, fill, elist, NEr, NNr);

  // ---- encoders -> xa ----
  enc_gemm<<<(NUr + 63) / 64, 256, 0, stream>>>(d_in[0], d_in[6], d_in[7], flags, 0, 6, 7,
                                                xa, NUr, dDes, 64, 0, 0);
  enc_gemm<<<(NUr + 63) / 64, 256, 0, stream>>>(d_in[2], d_in[8], d_in[9], flags, 2, 8, 9,
                                                xa, NUr, dNum, 32, 0, 64);
  enc_gemm<<<(NUr + 63) / 64, 256, 0, stream>>>(d_in[3], d_in[10], d_in[11], flags, 3, 10,
                                                11, xa, NUr, dCat, 32, 0, 96);
  enc_gemm<<<(NTr + 63) / 64, 256, 0, stream>>>(d_in[1], d_in[12], d_in[13], flags, 1, 12,
                                                13, xa, NTr, dTw, 128, NUr, 0);

  const int mt = (NNr + 127) / 128;
  const int mt32 = (NNr + 31) / 32;
  mfma_lin<<<mt, 256, 0, stream>>>(xa, WinB, bIn, xb, NNr);
  mfma_conv_f<<<mt32, 256, 0, stream>>>(xb, off, cnt, elist, inv, ConvB, rbp, xa, NNr, NNr);
  mfma_conv_f<<<mt32, 256, 0, stream>>>(xa, off, cnt, elist, inv, ConvB, rbp, xb, NNr, NNr);
  mfma_lin<<<mt, 256, 0, stream>>>(xb, Wo1B, bO1, xa, NNr);
  out_linear<<<(NNr + 3) / 4, 256, 0, stream>>>(xa, Wo2p, bo2p, out, NNr);
}

extern "C" void kernel_launch(void* const* d_in, const int* in_sizes, int n_in,
                              void* d_out, int out_size, void* d_ws, size_t ws_size,
                              hipStream_t stream) {
  float* out = (float*)d_out;
  char* ws = (char*)d_ws;

  auto signal = [&](int k) {
    sig_fill<<<(out_size + 255) / 256, 256, 0, stream>>>(out, out_size, (float)(200 + k));
  };

  if (n_in != 23) { signal(1); return; }
  const int* S = in_sizes;
  if (S[7] != 64 || S[9] != 32 || S[11] != 32 || S[13] != 128) { signal(2); return; }
  if (S[15] != 128) { signal(3); return; }
  if (S[6] % 64 || S[8] % 32 || S[10] % 32 || S[12] % 128) { signal(4); return; }
  int dDes = S[6] / 64, dNum = S[8] / 32, dCat = S[10] / 32, dTw = S[12] / 128;
  if (dDes <= 0 || dTw <= 0 || S[0] % dDes || S[1] % dTw) { signal(5); return; }
  if (dDes > 101 || dNum > 101 || dCat > 101 || dTw > 101) { signal(4); return; }
  int NUr = S[0] / dDes, NTr = S[1] / dTw, NNr = NUr + NTr, NEr = S[5];
  if (S[2] != NUr * dNum || S[3] != NUr * dCat) { signal(5); return; }
  if (S[4] != 2 * NEr || NEr < 1024) { signal(6); return; }
  if (NNr >= (1 << 24)) { signal(6); return; }  // elist src-packing limit
  if (S[14] != 16384 || S[16] != 32768 || S[17] != 16384 || S[18] != 128 ||
      S[19] != 16384 || S[20] != 128 || S[21] != 256 || S[22] != 2) { signal(7); return; }
  if (out_size != NNr * 2) { signal(8); return; }

  const size_t smallBytes = (size_t)4 * ((size_t)2 * NNr * 4) + 2 * 2048 * 4 +
                            (size_t)NEr * 4 + (size_t)PW_TOTAL * 4 + 512;
  const size_t need = 2 * (size_t)NNr * 128 * 2 + smallBytes;

  if (ws_size >= need) {
    run_pipeline(d_in, S, out, ws, NUr, NTr, NEr, dDes, dNum, dCat, dTw, stream);
  } else {
    signal(9);
  }
}

// Round 4
// 1027.593 us; speedup vs baseline: 3.2084x; 1.5135x over previous
//
#include <hip/hip_runtime.h>
#include <hip/hip_bf16.h>

typedef __hip_bfloat16 bf16;

typedef __bf16 bfv8 __attribute__((ext_vector_type(8)));
typedef float f32x4 __attribute__((ext_vector_type(4)));

__device__ __forceinline__ float lrelu(float x) { return x > 0.f ? x : 0.01f * x; }

__device__ __forceinline__ float ldv(float v) { return v; }
__device__ __forceinline__ float ldv(bf16 v) { return __bfloat162float(v); }
__device__ __forceinline__ void stv(float* p, float v) { *p = v; }
__device__ __forceinline__ void stv(bf16* p, float v) { *p = __float2bfloat16(v); }

__device__ __forceinline__ float in_rd(const void* p, size_t i, int isbf) {
  return isbf ? __bfloat162float(((const bf16*)p)[i]) : ((const float*)p)[i];
}
__device__ __forceinline__ int ix_rd(const void* p, size_t i, int is64) {
  return is64 ? (int)((const long long*)p)[i] : ((const int*)p)[i];
}

// ---------------- fused per-array format probe: one launch, 23 blocks ----------------
struct ProbeArgs {
  const void* p[23];
  int s[23];
  int mode[23];
};

__global__ void detect_all(ProbeArgs a, int* __restrict__ flags) {
  __shared__ int sh[256];
  int b = blockIdx.x;
  const unsigned int* w = (const unsigned int*)a.p[b];
  int s = a.s[b], mode = a.mode[b];
  int t = threadIdx.x;
  int c = 0;
  if (t < s) {
    if (mode == 0) {
      unsigned int v = w[t];
      int e = (v >> 7) & 0xFF;
      c = (e >= 100 && e <= 140) ? 1 : 0;
    } else {
      c = (w[2 * t + 1] == 0u) ? 1 : 0;
    }
  }
  sh[t] = c;
  __syncthreads();
  for (int d = 128; d; d >>= 1) {
    if (t < d) sh[t] += sh[t + d];
    __syncthreads();
  }
  if (t == 0) flags[b] = (mode == 0) ? (sh[0] * 10 >= 7 * s) : (sh[0] * 10 >= 9 * s);
}

// ---------------- weight prep ----------------
// fp32 region (floats): [0,16384) W_inT [k,n]; [16384,32768) W_o1T [k,n]; [32768,49152) root;
// [49152,81920) rw; [81920] b_in; [82048] rgcn_bias; [82176] b_o1; [82304] W_o2; [82560] b_o2
// bf16 region (starting at float index BF_BASE, 16B aligned), each [128][128] bf16 in
// [n][k] (out,in) layout for MFMA B-fragments:
//   m=0 WinB; m=1 Wo1B; m=2 rootB; m=3 rwB0; m=4 rwB1   (rootB,rwB0,rwB1 contiguous)
#define PW_F32 82562
#define BF_BASE 82564
#define PW_TOTAL (BF_BASE + 5 * 8192)
__global__ void prep_weights(const void* Win, const void* bin, const void* rw,
                             const void* root, const void* rb, const void* Wo1,
                             const void* bo1, const void* Wo2, const void* bo2,
                             const int* __restrict__ fl, float* __restrict__ pw) {
  int i = blockIdx.x * 256 + threadIdx.x;
  if (i >= PW_TOTAL) return;
  if (i < 16384) {
    int k = i >> 7, o = i & 127;
    pw[i] = in_rd(Win, (size_t)o * 128 + k, fl[14]);
  } else if (i < 32768) {
    int j = i - 16384;
    int k = j >> 7, o = j & 127;
    pw[i] = in_rd(Wo1, (size_t)o * 128 + k, fl[19]);
  } else if (i < 49152) {
    pw[i] = in_rd(root, i - 32768, fl[17]);
  } else if (i < 81920) {
    pw[i] = in_rd(rw, i - 49152, fl[16]);
  } else if (i < 82048) {
    pw[i] = in_rd(bin, i - 81920, fl[15]);
  } else if (i < 82176) {
    pw[i] = in_rd(rb, i - 82048, fl[18]);
  } else if (i < 82304) {
    pw[i] = in_rd(bo1, i - 82176, fl[20]);
  } else if (i < 82560) {
    pw[i] = in_rd(Wo2, i - 82304, fl[21]);
  } else if (i < PW_F32) {
    pw[i] = in_rd(bo2, i - 82560, fl[22]);
  } else if (i >= BF_BASE) {
    int j = i - BF_BASE;
    bf16* bw = (bf16*)(pw + BF_BASE);
#pragma unroll
    for (int q = 0; q < 2; q++) {
      int u = 2 * j + q;
      int m = u >> 14, r = u & 16383;
      int n = r >> 7, k = r & 127;
      float v;
      if (m == 0) v = in_rd(Win, (size_t)n * 128 + k, fl[14]);
      else if (m == 1) v = in_rd(Wo1, (size_t)n * 128 + k, fl[19]);
      else if (m == 2) v = in_rd(root, (size_t)k * 128 + n, fl[17]);
      else v = in_rd(rw, (size_t)(m - 3) * 16384 + (size_t)k * 128 + n, fl[16]);
      bw[u] = __float2bfloat16(v);
    }
  }
}

// ---------------- utilities ----------------
__global__ void sig_fill(float* __restrict__ p, int n, float v) {
  int i = blockIdx.x * 256 + threadIdx.x;
  if (i < n) p[i] = v;
}
__global__ void zero_ints(int* __restrict__ p, int n) {
  int i = blockIdx.x * 256 + threadIdx.x;
  if (i < n) p[i] = 0;
}

// ---------------- CSR build ----------------
__global__ void count_edges(const void* __restrict__ ei, const void* __restrict__ et,
                            const int* __restrict__ fl, int* __restrict__ cnt, int NEr,
                            int NNr) {
  int e = blockIdx.x * 256 + threadIdx.x;
  if (e >= NEr) return;
  int d = ix_rd(ei, (size_t)NEr + e, fl[4]);
  int r = ix_rd(et, e, fl[5]) & 1;
  if ((unsigned)d >= (unsigned)NNr) return;
  atomicAdd(&cnt[r * NNr + d], 1);
}

__global__ void scan_blocks(const int* __restrict__ in, int* __restrict__ out,
                            int* __restrict__ bsum, int n) {
  __shared__ int sh[256];
  int t = threadIdx.x;
  int base = blockIdx.x * 1024 + t * 4;
  int a[4];
  int s = 0;
#pragma unroll
  for (int i = 0; i < 4; i++) {
    a[i] = (base + i < n) ? in[base + i] : 0;
    s += a[i];
  }
  sh[t] = s;
  __syncthreads();
  for (int d = 1; d < 256; d <<= 1) {
    int v = (t >= d) ? sh[t - d] : 0;
    __syncthreads();
    sh[t] += v;
    __syncthreads();
  }
  int ex = sh[t] - s;
#pragma unroll
  for (int i = 0; i < 4; i++) {
    if (base + i < n) out[base + i] = ex;
    ex += a[i];
  }
  if (t == 255 && bsum) bsum[blockIdx.x] = sh[255];
}

__global__ void scan_add_inv(int* __restrict__ off, const int* __restrict__ bsumsc,
                             const int* __restrict__ cnt, float* __restrict__ inv, int n) {
  int i = blockIdx.x * 256 + threadIdx.x;
  if (i >= n) return;
  off[i] += bsumsc[i >> 10];
  inv[i] = 1.f / fmaxf((float)cnt[i], 1.f);
}

// elist word packs: bits [0,24) = src node id (top bits unused by the conv kernel now)
__global__ void fill_elist(const void* __restrict__ ei, const void* __restrict__ et,
                           const int* __restrict__ fl, const int* __restrict__ off,
                           int* __restrict__ fill, int* __restrict__ elist, int NEr, int NNr) {
  int e = blockIdx.x * 256 + threadIdx.x;
  if (e >= NEr) return;
  int s = ix_rd(ei, e, fl[4]);
  int d = ix_rd(ei, (size_t)NEr + e, fl[4]);
  int r = ix_rd(et, e, fl[5]) & 1;
  if ((unsigned)d >= (unsigned)NNr || (unsigned)s >= (unsigned)NNr) return;
  int idx = r * NNr + d;
  int slot = off[idx] + atomicAdd(&fill[idx], 1);
  elist[slot] = s | ((d & 127) << 24);
}

// ---------------- encoder GEMM ----------------
__global__ __launch_bounds__(256) void enc_gemm(const void* __restrict__ A,
                                                const void* __restrict__ W,
                                                const void* __restrict__ B,
                                                const int* __restrict__ fl, int fa, int fw,
                                                int fb, bf16* __restrict__ x, int M, int K,
                                                int N, int row0, int col0) {
  __shared__ float Wb[128 * 102];
  __shared__ float bb[128];
  int t = threadIdx.x;
  int stride = (K & 1) ? K : K + 1;
  int fA = fl[fa];
  {
    int fW = fl[fw], fB = fl[fb];
    for (int idx = t; idx < N * K; idx += 256) {
      int j = idx / K, k = idx - j * K;
      Wb[j * stride + k] = in_rd(W, (size_t)j * K + k, fW);
    }
    if (t < N) bb[t] = in_rd(B, t, fB);
  }
  __syncthreads();
  int j = t % N;
  int r = t / N;
  int R = 256 / N;
  int iEnd = blockIdx.x * 64 + 64;
  if (iEnd > M) iEnd = M;
  const float* wrow = &Wb[j * stride];
  if (!fA) {
    const float* Af = (const float*)A;
    for (int i = blockIdx.x * 64 + r; i < iEnd; i += R) {
      const float* a = Af + (size_t)i * K;
      float acc = bb[j];
      for (int k = 0; k < K; k++) acc += a[k] * wrow[k];
      stv(&x[(size_t)(row0 + i) * 128 + col0 + j], lrelu(acc));
    }
  } else {
    const bf16* Ab = (const bf16*)A;
    for (int i = blockIdx.x * 64 + r; i < iEnd; i += R) {
      const bf16* a = Ab + (size_t)i * K;
      float acc = bb[j];
      for (int k = 0; k < K; k++) acc += __bfloat162float(a[k]) * wrow[k];
      stv(&x[(size_t)(row0 + i) * 128 + col0 + j], lrelu(acc));
    }
  }
}

// ================= MFMA GEMMs (bf16 storage, fp32 accumulate) =================
// v_mfma_f32_16x16x32_bf16 fragments (m89/m91-verified C/D mapping):
//   A: lane l holds A[m = l&15][k = (l>>4)*8 + i]
//   B: lane l holds B[k = (l>>4)*8 + i][n = l&15]  (= Wt[n][k] with Wt in [out][in] layout)
//   D: lane l reg j -> row = (l>>4)*4 + j, col = l&15

// Out = lrelu(A @ Wb^T + bias); A,Out bf16 [M][128]; Wb bf16 [out][in]
// Block = 128 rows x 128 cols; 4 waves 2x2; wave = 64x64 (4x4 fragments).
__global__ __launch_bounds__(256) void mfma_lin(const bf16* __restrict__ A,
                                                const bf16* __restrict__ Wb,
                                                const float* __restrict__ bias,
                                                bf16* __restrict__ Out, int M) {
  int t = threadIdx.x;
  int wv = t >> 6, l = t & 63;
  int lr = l & 15, lg = l >> 4;
  int i0 = blockIdx.x * 128;
  int rbase = (wv >> 1) * 64;
  int cbase = (wv & 1) * 64;
  int ko = lg * 8;

  size_t rowoff[4];
#pragma unroll
  for (int rg = 0; rg < 4; rg++) {
    int row = i0 + rbase + rg * 16 + lr;
    if (row > M - 1) row = M - 1;  // clamp: junk rows never stored
    rowoff[rg] = (size_t)row * 128;
  }

  bfv8 bfr[4][4];
#pragma unroll
  for (int cg = 0; cg < 4; cg++)
#pragma unroll
    for (int ks = 0; ks < 4; ks++)
      bfr[cg][ks] = *(const bfv8*)&Wb[(size_t)(cbase + cg * 16 + lr) * 128 + ks * 32 + ko];

  f32x4 acc[4][4] = {};
#pragma unroll
  for (int ks = 0; ks < 4; ks++) {
    bfv8 af[4];
#pragma unroll
    for (int rg = 0; rg < 4; rg++) af[rg] = *(const bfv8*)&A[rowoff[rg] + ks * 32 + ko];
#pragma unroll
    for (int rg = 0; rg < 4; rg++)
#pragma unroll
      for (int cg = 0; cg < 4; cg++)
        acc[rg][cg] =
            __builtin_amdgcn_mfma_f32_16x16x32_bf16(af[rg], bfr[cg][ks], acc[rg][cg], 0, 0, 0);
  }

#pragma unroll
  for (int cg = 0; cg < 4; cg++) {
    int col = cbase + cg * 16 + lr;
    float bv = bias[col];
#pragma unroll
    for (int rg = 0; rg < 4; rg++) {
      int row0 = i0 + rbase + rg * 16 + lg * 4;
#pragma unroll
      for (int j = 0; j < 4; j++) {
        int row = row0 + j;
        if (row < M) Out[(size_t)row * 128 + col] = __float2bfloat16(lrelu(acc[rg][cg][j] + bv));
      }
    }
  }
}

// Fused RGCN conv: Out = X@root + mean_r0(X)@rw0 + mean_r1(X)@rw1 + bias.
// 32-row blocks; both relations in one 32KB fp32 LDS tile (vrows 0-31 rel0, 32-63 rel1).
// OWNERSHIP gather (no LDS atomics): item = (vrow, 8-col chunk) owned by one thread;
// owner walks the node's CSR slice (depth-2 prefetch), accumulates 8 fp32 in registers,
// then 2 plain float4 LDS stores. 16 lanes of a node read one contiguous 256B X row.
// Every slot written (zeros if deg=0 / out of range) -> no zero pass, ONE barrier total.
// LDS XOR-swizzle byte ^= (vrow&7)<<4 (512B-stride rows otherwise 16-way conflict on read).
__global__ __launch_bounds__(256, 4) void mfma_conv_f(
    const bf16* __restrict__ X, const int* __restrict__ off, const int* __restrict__ cnt,
    const int* __restrict__ elist, const float* __restrict__ inv,
    const bf16* __restrict__ WB, const float* __restrict__ bias, bf16* __restrict__ Out,
    int M, int NNr) {
  __shared__ __align__(16) float At[64 * 128];
  int t = threadIdx.x;
  int wv = t >> 6, l = t & 63;
  int lr = l & 15, lg = l >> 4;
  int i0 = blockIdx.x * 32;
  int cbase = wv * 32;
  int ko = lg * 8;

  // ---- ownership gather: 1024 items, 4 per thread ----
  {
    int c8 = (t & 15) * 8;  // col chunk base (elements)
#pragma unroll
    for (int pn = 0; pn < 4; pn++) {
      int vr = (t >> 4) + pn * 16;  // 0..63
      int rel = vr >> 5, m = vr & 31;
      int node = i0 + m;
      float s[8] = {0.f, 0.f, 0.f, 0.f, 0.f, 0.f, 0.f, 0.f};
      if (node < M) {
        int idx = rel * NNr + node;
        int st = off[idx];
        int deg = cnt[idx];
        if (deg > 0) {
          int src = elist[st] & 0xFFFFFF;
          bfv8 v = *(const bfv8*)&X[(size_t)src * 128 + c8];
          for (int e = 1; e < deg; e++) {
            int src2 = elist[st + e] & 0xFFFFFF;
            bfv8 v2 = *(const bfv8*)&X[(size_t)src2 * 128 + c8];
#pragma unroll
            for (int j = 0; j < 8; j++) s[j] += __bfloat162float(v[j]);
            v = v2;
          }
#pragma unroll
          for (int j = 0; j < 8; j++) s[j] += __bfloat162float(v[j]);
        }
      }
      int sw = (vr & 7) << 4;
      int lb = vr * 512 + c8 * 4;
      *(float4*)((char*)At + (lb ^ sw)) = make_float4(s[0], s[1], s[2], s[3]);
      *(float4*)((char*)At + ((lb + 16) ^ sw)) = make_float4(s[4], s[5], s[6], s[7]);
    }
  }

  // row clamps and inv scales
  size_t rowoff[2];
  float iv0[2], iv1[2];
#pragma unroll
  for (int rg = 0; rg < 2; rg++) {
    int row = i0 + rg * 16 + lr;
    int rc = row < M ? row : M - 1;
    rowoff[rg] = (size_t)rc * 128;
    iv0[rg] = row < M ? inv[row] : 0.f;
    iv1[rg] = row < M ? inv[NNr + row] : 0.f;
  }

  f32x4 acc[2][2] = {};

  // ---- seg 0: X @ root from global (independent of LDS; overlaps store latency) ----
#pragma unroll
  for (int ks = 0; ks < 4; ks++) {
    bfv8 bk[2];
#pragma unroll
    for (int cg = 0; cg < 2; cg++)
      bk[cg] = *(const bfv8*)&WB[(size_t)(cbase + cg * 16 + lr) * 128 + ks * 32 + ko];
    bfv8 af[2];
#pragma unroll
    for (int rg = 0; rg < 2; rg++) af[rg] = *(const bfv8*)&X[rowoff[rg] + ks * 32 + ko];
#pragma unroll
    for (int rg = 0; rg < 2; rg++)
#pragma unroll
      for (int cg = 0; cg < 2; cg++)
        acc[rg][cg] =
            __builtin_amdgcn_mfma_f32_16x16x32_bf16(af[rg], bk[cg], acc[rg][cg], 0, 0, 0);
  }
  __syncthreads();

  // ---- rel-0 / rel-1 MFMA from LDS (inv-scaled, cvt to bf16) ----
#pragma unroll
  for (int r = 0; r < 2; r++) {
    const bf16* Wb = WB + 16384 * (1 + r);
#pragma unroll
    for (int ks = 0; ks < 4; ks++) {
      bfv8 bk[2];
#pragma unroll
      for (int cg = 0; cg < 2; cg++)
        bk[cg] = *(const bfv8*)&Wb[(size_t)(cbase + cg * 16 + lr) * 128 + ks * 32 + ko];
      bfv8 af[2];
#pragma unroll
      for (int rg = 0; rg < 2; rg++) {
        int mrow = r * 32 + rg * 16 + lr;
        int lb = mrow * 512 + ks * 128 + ko * 4;
        int sw = (mrow & 7) << 4;
        float4 f0 = *(const float4*)((const char*)At + (lb ^ sw));
        float4 f1 = *(const float4*)((const char*)At + ((lb + 16) ^ sw));
        float iv = r ? iv1[rg] : iv0[rg];
        bfv8 a;
        a[0] = (__bf16)(f0.x * iv); a[1] = (__bf16)(f0.y * iv);
        a[2] = (__bf16)(f0.z * iv); a[3] = (__bf16)(f0.w * iv);
        a[4] = (__bf16)(f1.x * iv); a[5] = (__bf16)(f1.y * iv);
        a[6] = (__bf16)(f1.z * iv); a[7] = (__bf16)(f1.w * iv);
        af[rg] = a;
      }
#pragma unroll
      for (int rg = 0; rg < 2; rg++)
#pragma unroll
        for (int cg = 0; cg < 2; cg++)
          acc[rg][cg] =
              __builtin_amdgcn_mfma_f32_16x16x32_bf16(af[rg], bk[cg], acc[rg][cg], 0, 0, 0);
    }
  }

  // ---- epilogue: + bias, no activation ----
#pragma unroll
  for (int cg = 0; cg < 2; cg++) {
    int col = cbase + cg * 16 + lr;
    float bv = bias[col];
#pragma unroll
    for (int rg = 0; rg < 2; rg++) {
      int row0 = i0 + rg * 16 + lg * 4;
#pragma unroll
      for (int j = 0; j < 4; j++) {
        int row = row0 + j;
        if (row < M) Out[(size_t)row * 128 + col] = __float2bfloat16(acc[rg][cg][j] + bv);
      }
    }
  }
}

// ---------------- final 128 -> 2 linear, FP32 out ----------------
__global__ void out_linear(const bf16* __restrict__ x, const float* __restrict__ W,
                           const float* __restrict__ B, float* __restrict__ out, int NNr) {
  int wave = threadIdx.x >> 6;
  int lane = threadIdx.x & 63;
  int i = blockIdx.x * 4 + wave;
  if (i >= NNr) return;
  const bf16* xr = x + (size_t)i * 128;
  float x0 = ldv(xr[lane]);
  float x1 = ldv(xr[lane + 64]);
  float p0 = x0 * W[lane] + x1 * W[lane + 64];
  float p1 = x0 * W[128 + lane] + x1 * W[128 + lane + 64];
#pragma unroll
  for (int offs = 32; offs; offs >>= 1) {
    p0 += __shfl_down(p0, offs, 64);
    p1 += __shfl_down(p1, offs, 64);
  }
  if (lane == 0) {
    out[(size_t)i * 2] = p0 + B[0];
    out[(size_t)i * 2 + 1] = p1 + B[1];
  }
}

// ---------------- pipeline (bf16 storage, MFMA everywhere) ----------------
static void run_pipeline(void* const* d_in, const int* S, float* out, char* ws,
                         int NUr, int NTr, int NEr, int dDes, int dNum, int dCat, int dTw,
                         hipStream_t stream) {
  const int NNr = NUr + NTr;
  const size_t xbytes = (size_t)NNr * 128 * 2;

  bf16* xa = (bf16*)ws;
  bf16* xb = (bf16*)(ws + xbytes);
  char* p = ws + 2 * xbytes;
  int* cnt = (int*)p;      p += (size_t)2 * NNr * 4;
  int* fill = (int*)p;     p += (size_t)2 * NNr * 4;  // contiguous with cnt
  int* off = (int*)p;      p += (size_t)2 * NNr * 4;
  int* bsum = (int*)p;     p += 2048 * 4;             // contiguous with bsumsc
  int* bsumsc = (int*)p;   p += 2048 * 4;
  float* inv = (float*)p;  p += (size_t)2 * NNr * 4;
  int* elist = (int*)p;    p += (size_t)NEr * 4;
  float* pw = (float*)p;   p += (size_t)PW_TOTAL * 4;
  int* flags = (int*)p;

  // ---- format probes: one launch ----
  ProbeArgs pa;
  for (int i = 0; i < 23; i++) {
    int src = (i == 22) ? 21 : i;  // b_o2 (2 elems) inherits W_o2's dtype
    pa.p[i] = d_in[src];
    if (i == 4) {
      pa.mode[i] = 1;
      pa.s[i] = NEr < 256 ? NEr : 256;
    } else if (i == 5) {
      pa.mode[i] = 1;
      int s2 = NEr / 2 < 256 ? NEr / 2 : 256;
      pa.s[i] = s2 < 1 ? 1 : s2;
    } else {
      pa.mode[i] = 0;
      int s = S[src] / 2;
      if (s > 256) s = 256;
      if (s < 1) s = 1;
      pa.s[i] = s;
    }
  }
  detect_all<<<23, 256, 0, stream>>>(pa, flags);
  prep_weights<<<(PW_TOTAL + 255) / 256, 256, 0, stream>>>(
      d_in[14], d_in[15], d_in[16], d_in[17], d_in[18], d_in[19], d_in[20], d_in[21],
      d_in[22], flags, pw);

  const float* bIn = pw + 81920;
  const float* rbp = pw + 82048;
  const float* bO1 = pw + 82176;
  const float* Wo2p = pw + 82304;
  const float* bo2p = pw + 82560;
  const bf16* WinB = (const bf16*)(pw + BF_BASE);
  const bf16* Wo1B = (const bf16*)(pw + BF_BASE + 8192);
  const bf16* ConvB = (const bf16*)(pw + BF_BASE + 16384);  // rootB, rwB0, rwB1

  const void* ei = d_in[4];
  const void* et = d_in[5];
  const int nb1 = (2 * NNr + 1023) / 1024;

  // ---- CSR build ----
  zero_ints<<<(4 * NNr + 255) / 256, 256, 0, stream>>>(cnt, 4 * NNr);
  zero_ints<<<16, 256, 0, stream>>>(bsum, 4096);
  count_edges<<<(NEr + 255) / 256, 256, 0, stream>>>(ei, et, flags, cnt, NEr, NNr);
  scan_blocks<<<nb1, 256, 0, stream>>>(cnt, off, bsum, 2 * NNr);
  scan_blocks<<<1, 256, 0, stream>>>(bsum, bsumsc, nullptr, nb1);
  scan_add_inv<<<(2 * NNr + 255) / 256, 256, 0, stream>>>(off, bsumsc, cnt, inv, 2 * NNr);
  fill_elist<<<(NEr + 255) / 256, 256, 0, stream>>>(ei, et, flags, off, fill, elist, NEr, NNr);

  // ---- encoders -> xa ----
  enc_gemm<<<(NUr + 63) / 64, 256, 0, stream>>>(d_in[0], d_in[6], d_in[7], flags, 0, 6, 7,
                                                xa, NUr, dDes, 64, 0, 0);
  enc_gemm<<<(NUr + 63) / 64, 256, 0, stream>>>(d_in[2], d_in[8], d_in[9], flags, 2, 8, 9,
                                                xa, NUr, dNum, 32, 0, 64);
  enc_gemm<<<(NUr + 63) / 64, 256, 0, stream>>>(d_in[3], d_in[10], d_in[11], flags, 3, 10,
                                                11, xa, NUr, dCat, 32, 0, 96);
  enc_gemm<<<(NTr + 63) / 64, 256, 0, stream>>>(d_in[1], d_in[12], d_in[13], flags, 1, 12,
                                                13, xa, NTr, dTw, 128, NUr, 0);

  const int mt = (NNr + 127) / 128;
  const int mt32 = (NNr + 31) / 32;
  mfma_lin<<<mt, 256, 0, stream>>>(xa, WinB, bIn, xb, NNr);
  mfma_conv_f<<<mt32, 256, 0, stream>>>(xb, off, cnt, elist, inv, ConvB, rbp, xa, NNr, NNr);
  mfma_conv_f<<<mt32, 256, 0, stream>>>(xa, off, cnt, elist, inv, ConvB, rbp, xb, NNr, NNr);
  mfma_lin<<<mt, 256, 0, stream>>>(xb, Wo1B, bO1, xa, NNr);
  out_linear<<<(NNr + 3) / 4, 256, 0, stream>>>(xa, Wo2p, bo2p, out, NNr);
}

extern "C" void kernel_launch(void* const* d_in, const int* in_sizes, int n_in,
                              void* d_out, int out_size, void* d_ws, size_t ws_size,
                              hipStream_t stream) {
  float* out = (float*)d_out;
  char* ws = (char*)d_ws;

  auto signal = [&](int k) {
    sig_fill<<<(out_size + 255) / 256, 256, 0, stream>>>(out, out_size, (float)(200 + k));
  };

  if (n_in != 23) { signal(1); return; }
  const int* S = in_sizes;
  if (S[7] != 64 || S[9] != 32 || S[11] != 32 || S[13] != 128) { signal(2); return; }
  if (S[15] != 128) { signal(3); return; }
  if (S[6] % 64 || S[8] % 32 || S[10] % 32 || S[12] % 128) { signal(4); return; }
  int dDes = S[6] / 64, dNum = S[8] / 32, dCat = S[10] / 32, dTw = S[12] / 128;
  if (dDes <= 0 || dTw <= 0 || S[0] % dDes || S[1] % dTw) { signal(5); return; }
  if (dDes > 101 || dNum > 101 || dCat > 101 || dTw > 101) { signal(4); return; }
  int NUr = S[0] / dDes, NTr = S[1] / dTw, NNr = NUr + NTr, NEr = S[5];
  if (S[2] != NUr * dNum || S[3] != NUr * dCat) { signal(5); return; }
  if (S[4] != 2 * NEr || NEr < 1024) { signal(6); return; }
  if (NNr >= (1 << 24)) { signal(6); return; }  // elist src-packing limit
  if (S[14] != 16384 || S[16] != 32768 || S[17] != 16384 || S[18] != 128 ||
      S[19] != 16384 || S[20] != 128 || S[21] != 256 || S[22] != 2) { signal(7); return; }
  if (out_size != NNr * 2) { signal(8); return; }

  const size_t smallBytes = (size_t)4 * ((size_t)2 * NNr * 4) + 2 * 2048 * 4 +
                            (size_t)NEr * 4 + (size_t)PW_TOTAL * 4 + 512;
  const size_t need = 2 * (size_t)NNr * 128 * 2 + smallBytes;

  if (ws_size >= need) {
    run_pipeline(d_in, S, out, ws, NUr, NTr, NEr, dDes, dNum, dCat, dTw, stream);
  } else {
    signal(9);
  }
}

// Round 5
// 647.767 us; speedup vs baseline: 5.0897x; 1.5864x over previous
//
#include <hip/hip_runtime.h>
#include <hip/hip_bf16.h>

typedef __hip_bfloat16 bf16;

typedef __bf16 bfv8 __attribute__((ext_vector_type(8)));
typedef float f32x4 __attribute__((ext_vector_type(4)));

__device__ __forceinline__ float lrelu(float x) { return x > 0.f ? x : 0.01f * x; }

__device__ __forceinline__ float ldv(float v) { return v; }
__device__ __forceinline__ float ldv(bf16 v) { return __bfloat162float(v); }
__device__ __forceinline__ void stv(float* p, float v) { *p = v; }
__device__ __forceinline__ void stv(bf16* p, float v) { *p = __float2bfloat16(v); }

__device__ __forceinline__ float in_rd(const void* p, size_t i, int isbf) {
  return isbf ? __bfloat162float(((const bf16*)p)[i]) : ((const float*)p)[i];
}
__device__ __forceinline__ int ix_rd(const void* p, size_t i, int is64) {
  return is64 ? (int)((const long long*)p)[i] : ((const int*)p)[i];
}

// ---------------- fused per-array format probe: one launch, 23 blocks ----------------
struct ProbeArgs {
  const void* p[23];
  int s[23];
  int mode[23];
};

__global__ void detect_all(ProbeArgs a, int* __restrict__ flags) {
  __shared__ int sh[256];
  int b = blockIdx.x;
  const unsigned int* w = (const unsigned int*)a.p[b];
  int s = a.s[b], mode = a.mode[b];
  int t = threadIdx.x;
  int c = 0;
  if (t < s) {
    if (mode == 0) {
      unsigned int v = w[t];
      int e = (v >> 7) & 0xFF;
      c = (e >= 100 && e <= 140) ? 1 : 0;
    } else {
      c = (w[2 * t + 1] == 0u) ? 1 : 0;
    }
  }
  sh[t] = c;
  __syncthreads();
  for (int d = 128; d; d >>= 1) {
    if (t < d) sh[t] += sh[t + d];
    __syncthreads();
  }
  if (t == 0) flags[b] = (mode == 0) ? (sh[0] * 10 >= 7 * s) : (sh[0] * 10 >= 9 * s);
}

// ---------------- weight prep ----------------
// fp32 region (floats): [0,16384) W_inT [k,n]; [16384,32768) W_o1T [k,n]; [32768,49152) root;
// [49152,81920) rw; [81920] b_in; [82048] rgcn_bias; [82176] b_o1; [82304] W_o2; [82560] b_o2
// bf16 region (starting at float index BF_BASE, 16B aligned), each [128][128] bf16 in
// [n][k] (out,in) layout for MFMA B-fragments:
//   m=0 WinB; m=1 Wo1B; m=2 rootB; m=3 rwB0; m=4 rwB1   (rootB,rwB0,rwB1 contiguous)
// ENC region (float index ENC_BASE): EncU bf16[128][128] fused user-encoder weight
// ([des|num|cat] block-diagonal, zero-padded); EncT bf16[128][128] tweet weight; biasU[128];
// biasT[128].
#define PW_F32 82562
#define BF_BASE 82564
#define PW_W_TOTAL (BF_BASE + 5 * 8192)
#define ENC_BASE PW_W_TOTAL
#define PW_TOTAL (ENC_BASE + 16384 + 256)
__global__ void prep_weights(const void* Win, const void* bin, const void* rw,
                             const void* root, const void* rb, const void* Wo1,
                             const void* bo1, const void* Wo2, const void* bo2,
                             const int* __restrict__ fl, float* __restrict__ pw) {
  int i = blockIdx.x * 256 + threadIdx.x;
  if (i >= PW_W_TOTAL) return;
  if (i < 16384) {
    int k = i >> 7, o = i & 127;
    pw[i] = in_rd(Win, (size_t)o * 128 + k, fl[14]);
  } else if (i < 32768) {
    int j = i - 16384;
    int k = j >> 7, o = j & 127;
    pw[i] = in_rd(Wo1, (size_t)o * 128 + k, fl[19]);
  } else if (i < 49152) {
    pw[i] = in_rd(root, i - 32768, fl[17]);
  } else if (i < 81920) {
    pw[i] = in_rd(rw, i - 49152, fl[16]);
  } else if (i < 82048) {
    pw[i] = in_rd(bin, i - 81920, fl[15]);
  } else if (i < 82176) {
    pw[i] = in_rd(rb, i - 82048, fl[18]);
  } else if (i < 82304) {
    pw[i] = in_rd(bo1, i - 82176, fl[20]);
  } else if (i < 82560) {
    pw[i] = in_rd(Wo2, i - 82304, fl[21]);
  } else if (i < PW_F32) {
    pw[i] = in_rd(bo2, i - 82560, fl[22]);
  } else if (i >= BF_BASE) {
    int j = i - BF_BASE;
    bf16* bw = (bf16*)(pw + BF_BASE);
#pragma unroll
    for (int q = 0; q < 2; q++) {
      int u = 2 * j + q;
      int m = u >> 14, r = u & 16383;
      int n = r >> 7, k = r & 127;
      float v;
      if (m == 0) v = in_rd(Win, (size_t)n * 128 + k, fl[14]);
      else if (m == 1) v = in_rd(Wo1, (size_t)n * 128 + k, fl[19]);
      else if (m == 2) v = in_rd(root, (size_t)k * 128 + n, fl[17]);
      else v = in_rd(rw, (size_t)(m - 3) * 16384 + (size_t)k * 128 + n, fl[16]);
      bw[u] = __float2bfloat16(v);
    }
  }
}

// Builds fused encoder weights/biases. EncU out 0-63 = W_des (k in [0,dDes)),
// out 64-95 = W_num (k in [dDes,dDes+dNum)), out 96-127 = W_cat; zero elsewhere.
__global__ void prep_enc(const void* Wd, const void* bd, const void* Wn, const void* bn,
                         const void* Wc, const void* bc, const void* Wt, const void* bt,
                         const int* __restrict__ fl, int dDes, int dNum, int dCat, int dTw,
                         float* __restrict__ pw) {
  int i = blockIdx.x * 256 + threadIdx.x;
  bf16* e = (bf16*)(pw + ENC_BASE);
  float* bU = pw + ENC_BASE + 16384;
  float* bT = bU + 128;
  if (i < 16384) {
    int n = i >> 7, k = i & 127;
    float v = 0.f;
    if (n < 64) {
      if (k < dDes) v = in_rd(Wd, (size_t)n * dDes + k, fl[6]);
    } else if (n < 96) {
      int kk = k - dDes;
      if (kk >= 0 && kk < dNum) v = in_rd(Wn, (size_t)(n - 64) * dNum + kk, fl[8]);
    } else {
      int kk = k - dDes - dNum;
      if (kk >= 0 && kk < dCat) v = in_rd(Wc, (size_t)(n - 96) * dCat + kk, fl[10]);
    }
    e[i] = __float2bfloat16(v);
  } else if (i < 32768) {
    int j = i - 16384;
    int n = j >> 7, k = j & 127;
    float v = (k < dTw) ? in_rd(Wt, (size_t)n * dTw + k, fl[12]) : 0.f;
    e[i] = __float2bfloat16(v);
  } else if (i < 32896) {
    int j = i - 32768;
    bU[j] = (j < 64) ? in_rd(bd, j, fl[7])
                     : (j < 96) ? in_rd(bn, j - 64, fl[9]) : in_rd(bc, j - 96, fl[11]);
  } else if (i < 33024) {
    bT[i - 32896] = in_rd(bt, i - 32896, fl[13]);
  }
}

// ---------------- utilities ----------------
__global__ void sig_fill(float* __restrict__ p, int n, float v) {
  int i = blockIdx.x * 256 + threadIdx.x;
  if (i < n) p[i] = v;
}
__global__ void zero_ints(int* __restrict__ p, int n) {
  int i = blockIdx.x * 256 + threadIdx.x;
  if (i < n) p[i] = 0;
}

// ---------------- CSR build ----------------
__global__ void count_edges(const void* __restrict__ ei, const void* __restrict__ et,
                            const int* __restrict__ fl, int* __restrict__ cnt, int NEr,
                            int NNr) {
  int e = blockIdx.x * 256 + threadIdx.x;
  if (e >= NEr) return;
  int d = ix_rd(ei, (size_t)NEr + e, fl[4]);
  int r = ix_rd(et, e, fl[5]) & 1;
  if ((unsigned)d >= (unsigned)NNr) return;
  atomicAdd(&cnt[r * NNr + d], 1);
}

__global__ void scan_blocks(const int* __restrict__ in, int* __restrict__ out,
                            int* __restrict__ bsum, int n) {
  __shared__ int sh[256];
  int t = threadIdx.x;
  int base = blockIdx.x * 1024 + t * 4;
  int a[4];
  int s = 0;
#pragma unroll
  for (int i = 0; i < 4; i++) {
    a[i] = (base + i < n) ? in[base + i] : 0;
    s += a[i];
  }
  sh[t] = s;
  __syncthreads();
  for (int d = 1; d < 256; d <<= 1) {
    int v = (t >= d) ? sh[t - d] : 0;
    __syncthreads();
    sh[t] += v;
    __syncthreads();
  }
  int ex = sh[t] - s;
#pragma unroll
  for (int i = 0; i < 4; i++) {
    if (base + i < n) out[base + i] = ex;
    ex += a[i];
  }
  if (t == 255 && bsum) bsum[blockIdx.x] = sh[255];
}

__global__ void scan_add_inv(int* __restrict__ off, const int* __restrict__ bsumsc,
                             const int* __restrict__ cnt, float* __restrict__ inv, int n) {
  int i = blockIdx.x * 256 + threadIdx.x;
  if (i >= n) return;
  off[i] += bsumsc[i >> 10];
  inv[i] = 1.f / fmaxf((float)cnt[i], 1.f);
}

// elist word packs: bits [0,24) = src node id (top bits unused by the conv kernel now)
__global__ void fill_elist(const void* __restrict__ ei, const void* __restrict__ et,
                           const int* __restrict__ fl, const int* __restrict__ off,
                           int* __restrict__ fill, int* __restrict__ elist, int NEr, int NNr) {
  int e = blockIdx.x * 256 + threadIdx.x;
  if (e >= NEr) return;
  int s = ix_rd(ei, e, fl[4]);
  int d = ix_rd(ei, (size_t)NEr + e, fl[4]);
  int r = ix_rd(et, e, fl[5]) & 1;
  if ((unsigned)d >= (unsigned)NNr || (unsigned)s >= (unsigned)NNr) return;
  int idx = r * NNr + d;
  int slot = off[idx] + atomicAdd(&fill[idx], 1);
  elist[slot] = s | ((d & 127) << 24);
}

// ---------------- legacy encoder GEMM (fallback for oversized K) ----------------
__global__ __launch_bounds__(256) void enc_gemm(const void* __restrict__ A,
                                                const void* __restrict__ W,
                                                const void* __restrict__ B,
                                                const int* __restrict__ fl, int fa, int fw,
                                                int fb, bf16* __restrict__ x, int M, int K,
                                                int N, int row0, int col0) {
  __shared__ float Wb[128 * 102];
  __shared__ float bb[128];
  int t = threadIdx.x;
  int stride = (K & 1) ? K : K + 1;
  int fA = fl[fa];
  {
    int fW = fl[fw], fB = fl[fb];
    for (int idx = t; idx < N * K; idx += 256) {
      int j = idx / K, k = idx - j * K;
      Wb[j * stride + k] = in_rd(W, (size_t)j * K + k, fW);
    }
    if (t < N) bb[t] = in_rd(B, t, fB);
  }
  __syncthreads();
  int j = t % N;
  int r = t / N;
  int R = 256 / N;
  int iEnd = blockIdx.x * 64 + 64;
  if (iEnd > M) iEnd = M;
  const float* wrow = &Wb[j * stride];
  if (!fA) {
    const float* Af = (const float*)A;
    for (int i = blockIdx.x * 64 + r; i < iEnd; i += R) {
      const float* a = Af + (size_t)i * K;
      float acc = bb[j];
      for (int k = 0; k < K; k++) acc += a[k] * wrow[k];
      stv(&x[(size_t)(row0 + i) * 128 + col0 + j], lrelu(acc));
    }
  } else {
    const bf16* Ab = (const bf16*)A;
    for (int i = blockIdx.x * 64 + r; i < iEnd; i += R) {
      const bf16* a = Ab + (size_t)i * K;
      float acc = bb[j];
      for (int k = 0; k < K; k++) acc += __bfloat162float(a[k]) * wrow[k];
      stv(&x[(size_t)(row0 + i) * 128 + col0 + j], lrelu(acc));
    }
  }
}

// ================= MFMA GEMMs (bf16 storage, fp32 accumulate) =================
// v_mfma_f32_16x16x32_bf16 fragments (m89/m91-verified C/D mapping):
//   A: lane l holds A[m = l&15][k = (l>>4)*8 + i]
//   B: lane l holds B[k = (l>>4)*8 + i][n = l&15]  (= Wt[n][k] with Wt in [out][in] layout)
//   D: lane l reg j -> row = (l>>4)*4 + j, col = l&15

// MFMA encoder: stages up to 3 input segments (fused-K, zero-padded to 128) into a
// bf16 LDS tile, then 128x128 K=128 MFMA with fused [out][in] weight + bias + lrelu.
// LDS rows XOR-swizzled (byte ^= (row&7)<<4): 256B-stride rows otherwise 16-way conflict.
__global__ __launch_bounds__(256) void enc_mfma(
    const void* __restrict__ A0, const void* __restrict__ A1, const void* __restrict__ A2,
    const int* __restrict__ fl, int fi0, int fi1, int fi2, int K0, int K1, int K2,
    const bf16* __restrict__ WbE, const float* __restrict__ biasE, bf16* __restrict__ x,
    int M, int row0) {
  __shared__ __align__(16) bf16 Xs[16384];
  int t = threadIdx.x;
  int i0 = blockIdx.x * 128;

  // zero tile (covers K-pad and rows >= M)
  {
    uint4 z = {0u, 0u, 0u, 0u};
#pragma unroll
    for (int i = 0; i < 8; i++) *(uint4*)((char*)Xs + i * 4096 + t * 16) = z;
  }
  __syncthreads();

  // stage segments, flat-coalesced over 128*Ks elements each
  const void* As[3] = {A0, A1, A2};
  int Ks_[3] = {K0, K1, K2};
  int fis[3] = {fi0, fi1, fi2};
  int cb = 0;
  for (int s = 0; s < 3; s++) {
    int Ks = Ks_[s];
    if (Ks <= 0) continue;
    int isbf = fl[fis[s]];
    const void* A = As[s];
    int total = 128 * Ks;
    for (int f = t; f < total; f += 256) {
      int row = f / Ks;
      int k = f - row * Ks;
      int gr = i0 + row;
      float v = (gr < M) ? in_rd(A, (size_t)gr * Ks + k, isbf) : 0.f;
      int byte = row * 256 + (cb + k) * 2;
      *(bf16*)((char*)Xs + (byte ^ ((row & 7) << 4))) = __float2bfloat16(v);
    }
    cb += Ks;
  }
  __syncthreads();

  // 128x128 K=128 MFMA; 4 waves 2x2; wave = 64x64 (4x4 fragments)
  int wv = t >> 6, l = t & 63;
  int lr = l & 15, lg = l >> 4;
  int rbase = (wv >> 1) * 64, cbase = (wv & 1) * 64;
  int ko = lg * 8;
  f32x4 acc[4][4] = {};
#pragma unroll
  for (int ks = 0; ks < 4; ks++) {
    bfv8 bk[4];
#pragma unroll
    for (int cg = 0; cg < 4; cg++)
      bk[cg] = *(const bfv8*)&WbE[(size_t)(cbase + cg * 16 + lr) * 128 + ks * 32 + ko];
    bfv8 af[4];
#pragma unroll
    for (int rg = 0; rg < 4; rg++) {
      int mrow = rbase + rg * 16 + lr;
      int byte = mrow * 256 + (ks * 32 + ko) * 2;
      af[rg] = *(const bfv8*)((const char*)Xs + (byte ^ ((mrow & 7) << 4)));
    }
#pragma unroll
    for (int rg = 0; rg < 4; rg++)
#pragma unroll
      for (int cg = 0; cg < 4; cg++)
        acc[rg][cg] =
            __builtin_amdgcn_mfma_f32_16x16x32_bf16(af[rg], bk[cg], acc[rg][cg], 0, 0, 0);
  }

#pragma unroll
  for (int cg = 0; cg < 4; cg++) {
    int col = cbase + cg * 16 + lr;
    float bv = biasE[col];
#pragma unroll
    for (int rg = 0; rg < 4; rg++) {
      int r0 = i0 + rbase + rg * 16 + lg * 4;
#pragma unroll
      for (int j = 0; j < 4; j++) {
        int row = r0 + j;
        if (row < M)
          x[(size_t)(row0 + row) * 128 + col] = __float2bfloat16(lrelu(acc[rg][cg][j] + bv));
      }
    }
  }
}

// Out = lrelu(A @ Wb^T + bias); A,Out bf16 [M][128]; Wb bf16 [out][in]
// Block = 128 rows x 128 cols; 4 waves 2x2; wave = 64x64 (4x4 fragments).
__global__ __launch_bounds__(256) void mfma_lin(const bf16* __restrict__ A,
                                                const bf16* __restrict__ Wb,
                                                const float* __restrict__ bias,
                                                bf16* __restrict__ Out, int M) {
  int t = threadIdx.x;
  int wv = t >> 6, l = t & 63;
  int lr = l & 15, lg = l >> 4;
  int i0 = blockIdx.x * 128;
  int rbase = (wv >> 1) * 64;
  int cbase = (wv & 1) * 64;
  int ko = lg * 8;

  size_t rowoff[4];
#pragma unroll
  for (int rg = 0; rg < 4; rg++) {
    int row = i0 + rbase + rg * 16 + lr;
    if (row > M - 1) row = M - 1;  // clamp: junk rows never stored
    rowoff[rg] = (size_t)row * 128;
  }

  bfv8 bfr[4][4];
#pragma unroll
  for (int cg = 0; cg < 4; cg++)
#pragma unroll
    for (int ks = 0; ks < 4; ks++)
      bfr[cg][ks] = *(const bfv8*)&Wb[(size_t)(cbase + cg * 16 + lr) * 128 + ks * 32 + ko];

  f32x4 acc[4][4] = {};
#pragma unroll
  for (int ks = 0; ks < 4; ks++) {
    bfv8 af[4];
#pragma unroll
    for (int rg = 0; rg < 4; rg++) af[rg] = *(const bfv8*)&A[rowoff[rg] + ks * 32 + ko];
#pragma unroll
    for (int rg = 0; rg < 4; rg++)
#pragma unroll
      for (int cg = 0; cg < 4; cg++)
        acc[rg][cg] =
            __builtin_amdgcn_mfma_f32_16x16x32_bf16(af[rg], bfr[cg][ks], acc[rg][cg], 0, 0, 0);
  }

#pragma unroll
  for (int cg = 0; cg < 4; cg++) {
    int col = cbase + cg * 16 + lr;
    float bv = bias[col];
#pragma unroll
    for (int rg = 0; rg < 4; rg++) {
      int row0 = i0 + rbase + rg * 16 + lg * 4;
#pragma unroll
      for (int j = 0; j < 4; j++) {
        int row = row0 + j;
        if (row < M) Out[(size_t)row * 128 + col] = __float2bfloat16(lrelu(acc[rg][cg][j] + bv));
      }
    }
  }
}

// Fused RGCN conv: Out = X@root + mean_r0(X)@rw0 + mean_r1(X)@rw1 + bias.
// 32-row blocks; both relations in one 32KB fp32 LDS tile (vrows 0-31 rel0, 32-63 rel1).
// OWNERSHIP gather (no LDS atomics): item = (vrow, 8-col chunk) owned by one thread;
// owner walks the node's CSR slice (depth-2 prefetch), accumulates 8 fp32 in registers,
// then 2 plain float4 LDS stores. 16 lanes of a node read one contiguous 256B X row.
// Every slot written (zeros if deg=0 / out of range) -> no zero pass, ONE barrier total.
// LDS XOR-swizzle byte ^= (vrow&7)<<4 (512B-stride rows otherwise 16-way conflict on read).
__global__ __launch_bounds__(256, 4) void mfma_conv_f(
    const bf16* __restrict__ X, const int* __restrict__ off, const int* __restrict__ cnt,
    const int* __restrict__ elist, const float* __restrict__ inv,
    const bf16* __restrict__ WB, const float* __restrict__ bias, bf16* __restrict__ Out,
    int M, int NNr) {
  __shared__ __align__(16) float At[64 * 128];
  int t = threadIdx.x;
  int wv = t >> 6, l = t & 63;
  int lr = l & 15, lg = l >> 4;
  int i0 = blockIdx.x * 32;
  int cbase = wv * 32;
  int ko = lg * 8;

  // ---- ownership gather: 1024 items, 4 per thread ----
  {
    int c8 = (t & 15) * 8;  // col chunk base (elements)
#pragma unroll
    for (int pn = 0; pn < 4; pn++) {
      int vr = (t >> 4) + pn * 16;  // 0..63
      int rel = vr >> 5, m = vr & 31;
      int node = i0 + m;
      float s[8] = {0.f, 0.f, 0.f, 0.f, 0.f, 0.f, 0.f, 0.f};
      if (node < M) {
        int idx = rel * NNr + node;
        int st = off[idx];
        int deg = cnt[idx];
        if (deg > 0) {
          int src = elist[st] & 0xFFFFFF;
          bfv8 v = *(const bfv8*)&X[(size_t)src * 128 + c8];
          for (int e = 1; e < deg; e++) {
            int src2 = elist[st + e] & 0xFFFFFF;
            bfv8 v2 = *(const bfv8*)&X[(size_t)src2 * 128 + c8];
#pragma unroll
            for (int j = 0; j < 8; j++) s[j] += __bfloat162float(v[j]);
            v = v2;
          }
#pragma unroll
          for (int j = 0; j < 8; j++) s[j] += __bfloat162float(v[j]);
        }
      }
      int sw = (vr & 7) << 4;
      int lb = vr * 512 + c8 * 4;
      *(float4*)((char*)At + (lb ^ sw)) = make_float4(s[0], s[1], s[2], s[3]);
      *(float4*)((char*)At + ((lb + 16) ^ sw)) = make_float4(s[4], s[5], s[6], s[7]);
    }
  }

  // row clamps and inv scales
  size_t rowoff[2];
  float iv0[2], iv1[2];
#pragma unroll
  for (int rg = 0; rg < 2; rg++) {
    int row = i0 + rg * 16 + lr;
    int rc = row < M ? row : M - 1;
    rowoff[rg] = (size_t)rc * 128;
    iv0[rg] = row < M ? inv[row] : 0.f;
    iv1[rg] = row < M ? inv[NNr + row] : 0.f;
  }

  f32x4 acc[2][2] = {};

  // ---- seg 0: X @ root from global (independent of LDS; overlaps store latency) ----
#pragma unroll
  for (int ks = 0; ks < 4; ks++) {
    bfv8 bk[2];
#pragma unroll
    for (int cg = 0; cg < 2; cg++)
      bk[cg] = *(const bfv8*)&WB[(size_t)(cbase + cg * 16 + lr) * 128 + ks * 32 + ko];
    bfv8 af[2];
#pragma unroll
    for (int rg = 0; rg < 2; rg++) af[rg] = *(const bfv8*)&X[rowoff[rg] + ks * 32 + ko];
#pragma unroll
    for (int rg = 0; rg < 2; rg++)
#pragma unroll
      for (int cg = 0; cg < 2; cg++)
        acc[rg][cg] =
            __builtin_amdgcn_mfma_f32_16x16x32_bf16(af[rg], bk[cg], acc[rg][cg], 0, 0, 0);
  }
  __syncthreads();

  // ---- rel-0 / rel-1 MFMA from LDS (inv-scaled, cvt to bf16) ----
#pragma unroll
  for (int r = 0; r < 2; r++) {
    const bf16* Wb = WB + 16384 * (1 + r);
#pragma unroll
    for (int ks = 0; ks < 4; ks++) {
      bfv8 bk[2];
#pragma unroll
      for (int cg = 0; cg < 2; cg++)
        bk[cg] = *(const bfv8*)&Wb[(size_t)(cbase + cg * 16 + lr) * 128 + ks * 32 + ko];
      bfv8 af[2];
#pragma unroll
      for (int rg = 0; rg < 2; rg++) {
        int mrow = r * 32 + rg * 16 + lr;
        int lb = mrow * 512 + ks * 128 + ko * 4;
        int sw = (mrow & 7) << 4;
        float4 f0 = *(const float4*)((const char*)At + (lb ^ sw));
        float4 f1 = *(const float4*)((const char*)At + ((lb + 16) ^ sw));
        float iv = r ? iv1[rg] : iv0[rg];
        bfv8 a;
        a[0] = (__bf16)(f0.x * iv); a[1] = (__bf16)(f0.y * iv);
        a[2] = (__bf16)(f0.z * iv); a[3] = (__bf16)(f0.w * iv);
        a[4] = (__bf16)(f1.x * iv); a[5] = (__bf16)(f1.y * iv);
        a[6] = (__bf16)(f1.z * iv); a[7] = (__bf16)(f1.w * iv);
        af[rg] = a;
      }
#pragma unroll
      for (int rg = 0; rg < 2; rg++)
#pragma unroll
        for (int cg = 0; cg < 2; cg++)
          acc[rg][cg] =
              __builtin_amdgcn_mfma_f32_16x16x32_bf16(af[rg], bk[cg], acc[rg][cg], 0, 0, 0);
    }
  }

  // ---- epilogue: + bias, no activation ----
#pragma unroll
  for (int cg = 0; cg < 2; cg++) {
    int col = cbase + cg * 16 + lr;
    float bv = bias[col];
#pragma unroll
    for (int rg = 0; rg < 2; rg++) {
      int row0 = i0 + rg * 16 + lg * 4;
#pragma unroll
      for (int j = 0; j < 4; j++) {
        int row = row0 + j;
        if (row < M) Out[(size_t)row * 128 + col] = __float2bfloat16(acc[rg][cg][j] + bv);
      }
    }
  }
}

// ---------------- final 128 -> 2 linear, FP32 out ----------------
__global__ void out_linear(const bf16* __restrict__ x, const float* __restrict__ W,
                           const float* __restrict__ B, float* __restrict__ out, int NNr) {
  int wave = threadIdx.x >> 6;
  int lane = threadIdx.x & 63;
  int i = blockIdx.x * 4 + wave;
  if (i >= NNr) return;
  const bf16* xr = x + (size_t)i * 128;
  float x0 = ldv(xr[lane]);
  float x1 = ldv(xr[lane + 64]);
  float p0 = x0 * W[lane] + x1 * W[lane + 64];
  float p1 = x0 * W[128 + lane] + x1 * W[128 + lane + 64];
#pragma unroll
  for (int offs = 32; offs; offs >>= 1) {
    p0 += __shfl_down(p0, offs, 64);
    p1 += __shfl_down(p1, offs, 64);
  }
  if (lane == 0) {
    out[(size_t)i * 2] = p0 + B[0];
    out[(size_t)i * 2 + 1] = p1 + B[1];
  }
}

// ---------------- pipeline (bf16 storage, MFMA everywhere) ----------------
static void run_pipeline(void* const* d_in, const int* S, float* out, char* ws,
                         int NUr, int NTr, int NEr, int dDes, int dNum, int dCat, int dTw,
                         hipStream_t stream) {
  const int NNr = NUr + NTr;
  const size_t xbytes = (size_t)NNr * 128 * 2;

  bf16* xa = (bf16*)ws;
  bf16* xb = (bf16*)(ws + xbytes);
  char* p = ws + 2 * xbytes;
  int* cnt = (int*)p;      p += (size_t)2 * NNr * 4;
  int* fill = (int*)p;     p += (size_t)2 * NNr * 4;  // contiguous with cnt
  int* off = (int*)p;      p += (size_t)2 * NNr * 4;
  int* bsum = (int*)p;     p += 2048 * 4;             // contiguous with bsumsc
  int* bsumsc = (int*)p;   p += 2048 * 4;
  float* inv = (float*)p;  p += (size_t)2 * NNr * 4;
  int* elist = (int*)p;    p += (size_t)NEr * 4;
  float* pw = (float*)p;   p += (size_t)PW_TOTAL * 4;
  int* flags = (int*)p;

  // ---- format probes: one launch ----
  ProbeArgs pa;
  for (int i = 0; i < 23; i++) {
    int src = (i == 22) ? 21 : i;  // b_o2 (2 elems) inherits W_o2's dtype
    pa.p[i] = d_in[src];
    if (i == 4) {
      pa.mode[i] = 1;
      pa.s[i] = NEr < 256 ? NEr : 256;
    } else if (i == 5) {
      pa.mode[i] = 1;
      int s2 = NEr / 2 < 256 ? NEr / 2 : 256;
      pa.s[i] = s2 < 1 ? 1 : s2;
    } else {
      pa.mode[i] = 0;
      int s = S[src] / 2;
      if (s > 256) s = 256;
      if (s < 1) s = 1;
      pa.s[i] = s;
    }
  }
  detect_all<<<23, 256, 0, stream>>>(pa, flags);
  prep_weights<<<(PW_W_TOTAL + 255) / 256, 256, 0, stream>>>(
      d_in[14], d_in[15], d_in[16], d_in[17], d_in[18], d_in[19], d_in[20], d_in[21],
      d_in[22], flags, pw);
  prep_enc<<<129, 256, 0, stream>>>(d_in[6], d_in[7], d_in[8], d_in[9], d_in[10], d_in[11],
                                    d_in[12], d_in[13], flags, dDes, dNum, dCat, dTw, pw);

  const float* bIn = pw + 81920;
  const float* rbp = pw + 82048;
  const float* bO1 = pw + 82176;
  const float* Wo2p = pw + 82304;
  const float* bo2p = pw + 82560;
  const bf16* WinB = (const bf16*)(pw + BF_BASE);
  const bf16* Wo1B = (const bf16*)(pw + BF_BASE + 8192);
  const bf16* ConvB = (const bf16*)(pw + BF_BASE + 16384);  // rootB, rwB0, rwB1
  const bf16* EncU = (const bf16*)(pw + ENC_BASE);
  const bf16* EncT = (const bf16*)(pw + ENC_BASE + 8192);
  const float* bU = pw + ENC_BASE + 16384;
  const float* bT = bU + 128;

  const void* ei = d_in[4];
  const void* et = d_in[5];
  const int nb1 = (2 * NNr + 1023) / 1024;

  // ---- CSR build ----
  zero_ints<<<(4 * NNr + 255) / 256, 256, 0, stream>>>(cnt, 4 * NNr);
  zero_ints<<<16, 256, 0, stream>>>(bsum, 4096);
  count_edges<<<(NEr + 255) / 256, 256, 0, stream>>>(ei, et, flags, cnt, NEr, NNr);
  scan_blocks<<<nb1, 256, 0, stream>>>(cnt, off, bsum, 2 * NNr);
  scan_blocks<<<1, 256, 0, stream>>>(bsum, bsumsc, nullptr, nb1);
  scan_add_inv<<<(2 * NNr + 255) / 256, 256, 0, stream>>>(off, bsumsc, cnt, inv, 2 * NNr);
  fill_elist<<<(NEr + 255) / 256, 256, 0, stream>>>(ei, et, flags, off, fill, elist, NEr, NNr);

  // ---- encoders -> xa ----
  if (dDes + dNum + dCat <= 128 && dTw <= 128) {
    enc_mfma<<<(NUr + 127) / 128, 256, 0, stream>>>(d_in[0], d_in[2], d_in[3], flags, 0, 2, 3,
                                                    dDes, dNum, dCat, EncU, bU, xa, NUr, 0);
    enc_mfma<<<(NTr + 127) / 128, 256, 0, stream>>>(d_in[1], nullptr, nullptr, flags, 1, 1, 1,
                                                    dTw, 0, 0, EncT, bT, xa, NTr, NUr);
  } else {
    enc_gemm<<<(NUr + 63) / 64, 256, 0, stream>>>(d_in[0], d_in[6], d_in[7], flags, 0, 6, 7,
                                                  xa, NUr, dDes, 64, 0, 0);
    enc_gemm<<<(NUr + 63) / 64, 256, 0, stream>>>(d_in[2], d_in[8], d_in[9], flags, 2, 8, 9,
                                                  xa, NUr, dNum, 32, 0, 64);
    enc_gemm<<<(NUr + 63) / 64, 256, 0, stream>>>(d_in[3], d_in[10], d_in[11], flags, 3, 10,
                                                  11, xa, NUr, dCat, 32, 0, 96);
    enc_gemm<<<(NTr + 63) / 64, 256, 0, stream>>>(d_in[1], d_in[12], d_in[13], flags, 1, 12,
                                                  13, xa, NTr, dTw, 128, NUr, 0);
  }

  const int mt = (NNr + 127) / 128;
  const int mt32 = (NNr + 31) / 32;
  mfma_lin<<<mt, 256, 0, stream>>>(xa, WinB, bIn, xb, NNr);
  mfma_conv_f<<<mt32, 256, 0, stream>>>(xb, off, cnt, elist, inv, ConvB, rbp, xa, NNr, NNr);
  mfma_conv_f<<<mt32, 256, 0, stream>>>(xa, off, cnt, elist, inv, ConvB, rbp, xb, NNr, NNr);
  mfma_lin<<<mt, 256, 0, stream>>>(xb, Wo1B, bO1, xa, NNr);
  out_linear<<<(NNr + 3) / 4, 256, 0, stream>>>(xa, Wo2p, bo2p, out, NNr);
}

extern "C" void kernel_launch(void* const* d_in, const int* in_sizes, int n_in,
                              void* d_out, int out_size, void* d_ws, size_t ws_size,
                              hipStream_t stream) {
  float* out = (float*)d_out;
  char* ws = (char*)d_ws;

  auto signal = [&](int k) {
    sig_fill<<<(out_size + 255) / 256, 256, 0, stream>>>(out, out_size, (float)(200 + k));
  };

  if (n_in != 23) { signal(1); return; }
  const int* S = in_sizes;
  if (S[7] != 64 || S[9] != 32 || S[11] != 32 || S[13] != 128) { signal(2); return; }
  if (S[15] != 128) { signal(3); return; }
  if (S[6] % 64 || S[8] % 32 || S[10] % 32 || S[12] % 128) { signal(4); return; }
  int dDes = S[6] / 64, dNum = S[8] / 32, dCat = S[10] / 32, dTw = S[12] / 128;
  if (dDes <= 0 || dTw <= 0 || S[0] % dDes || S[1] % dTw) { signal(5); return; }
  if (dDes > 101 || dNum > 101 || dCat > 101 || dTw > 101) { signal(4); return; }
  int NUr = S[0] / dDes, NTr = S[1] / dTw, NNr = NUr + NTr, NEr = S[5];
  if (S[2] != NUr * dNum || S[3] != NUr * dCat) { signal(5); return; }
  if (S[4] != 2 * NEr || NEr < 1024) { signal(6); return; }
  if (NNr >= (1 << 24)) { signal(6); return; }  // elist src-packing limit
  if (S[14] != 16384 || S[16] != 32768 || S[17] != 16384 || S[18] != 128 ||
      S[19] != 16384 || S[20] != 128 || S[21] != 256 || S[22] != 2) { signal(7); return; }
  if (out_size != NNr * 2) { signal(8); return; }

  const size_t smallBytes = (size_t)4 * ((size_t)2 * NNr * 4) + 2 * 2048 * 4 +
                            (size_t)NEr * 4 + (size_t)PW_TOTAL * 4 + 512;
  const size_t need = 2 * (size_t)NNr * 128 * 2 + smallBytes;

  if (ws_size >= need) {
    run_pipeline(d_in, S, out, ws, NUr, NTr, NEr, dDes, dNum, dCat, dTw, stream);
  } else {
    signal(9);
  }
}

// Round 6
// 635.950 us; speedup vs baseline: 5.1843x; 1.0186x over previous
//
#include <hip/hip_runtime.h>
#include <hip/hip_bf16.h>

typedef __hip_bfloat16 bf16;

typedef __bf16 bfv8 __attribute__((ext_vector_type(8)));
typedef float f32x4 __attribute__((ext_vector_type(4)));

__device__ __forceinline__ float lrelu(float x) { return x > 0.f ? x : 0.01f * x; }

__device__ __forceinline__ float ldv(float v) { return v; }
__device__ __forceinline__ float ldv(bf16 v) { return __bfloat162float(v); }
__device__ __forceinline__ void stv(float* p, float v) { *p = v; }
__device__ __forceinline__ void stv(bf16* p, float v) { *p = __float2bfloat16(v); }

__device__ __forceinline__ float in_rd(const void* p, size_t i, int isbf) {
  return isbf ? __bfloat162float(((const bf16*)p)[i]) : ((const float*)p)[i];
}
__device__ __forceinline__ int ix_rd(const void* p, size_t i, int is64) {
  return is64 ? (int)((const long long*)p)[i] : ((const int*)p)[i];
}

// ---------------- fused per-array format probe: one launch, 23 blocks ----------------
struct ProbeArgs {
  const void* p[23];
  int s[23];
  int mode[23];
};

__global__ void detect_all(ProbeArgs a, int* __restrict__ flags) {
  __shared__ int sh[256];
  int b = blockIdx.x;
  const unsigned int* w = (const unsigned int*)a.p[b];
  int s = a.s[b], mode = a.mode[b];
  int t = threadIdx.x;
  int c = 0;
  if (t < s) {
    if (mode == 0) {
      unsigned int v = w[t];
      int e = (v >> 7) & 0xFF;
      c = (e >= 100 && e <= 140) ? 1 : 0;
    } else {
      c = (w[2 * t + 1] == 0u) ? 1 : 0;
    }
  }
  sh[t] = c;
  __syncthreads();
  for (int d = 128; d; d >>= 1) {
    if (t < d) sh[t] += sh[t + d];
    __syncthreads();
  }
  if (t == 0) flags[b] = (mode == 0) ? (sh[0] * 10 >= 7 * s) : (sh[0] * 10 >= 9 * s);
}

// ---------------- weight prep ----------------
// fp32 region (floats): [0,16384) W_inT [k,n]; [16384,32768) W_o1T [k,n]; [32768,49152) root;
// [49152,81920) rw; [81920] b_in; [82048] rgcn_bias; [82176] b_o1; [82304] W_o2; [82560] b_o2
// bf16 region (starting at float index BF_BASE, 16B aligned), each [128][128] bf16 in
// [n][k] (out,in) layout for MFMA B-fragments:
//   m=0 WinB; m=1 Wo1B; m=2 rootB; m=3 rwB0; m=4 rwB1   (rootB,rwB0,rwB1 contiguous)
// ENC region (float index ENC_BASE): EncU bf16[128][128] fused user-encoder weight
// ([des|num|cat] block-diagonal, zero-padded); EncT bf16[128][128] tweet weight; biasU[128];
// biasT[128].
#define PW_F32 82562
#define BF_BASE 82564
#define PW_W_TOTAL (BF_BASE + 5 * 8192)
#define ENC_BASE PW_W_TOTAL
#define PW_TOTAL (ENC_BASE + 16384 + 256)
__global__ void prep_weights(const void* Win, const void* bin, const void* rw,
                             const void* root, const void* rb, const void* Wo1,
                             const void* bo1, const void* Wo2, const void* bo2,
                             const int* __restrict__ fl, float* __restrict__ pw) {
  int i = blockIdx.x * 256 + threadIdx.x;
  if (i >= PW_W_TOTAL) return;
  if (i < 16384) {
    int k = i >> 7, o = i & 127;
    pw[i] = in_rd(Win, (size_t)o * 128 + k, fl[14]);
  } else if (i < 32768) {
    int j = i - 16384;
    int k = j >> 7, o = j & 127;
    pw[i] = in_rd(Wo1, (size_t)o * 128 + k, fl[19]);
  } else if (i < 49152) {
    pw[i] = in_rd(root, i - 32768, fl[17]);
  } else if (i < 81920) {
    pw[i] = in_rd(rw, i - 49152, fl[16]);
  } else if (i < 82048) {
    pw[i] = in_rd(bin, i - 81920, fl[15]);
  } else if (i < 82176) {
    pw[i] = in_rd(rb, i - 82048, fl[18]);
  } else if (i < 82304) {
    pw[i] = in_rd(bo1, i - 82176, fl[20]);
  } else if (i < 82560) {
    pw[i] = in_rd(Wo2, i - 82304, fl[21]);
  } else if (i < PW_F32) {
    pw[i] = in_rd(bo2, i - 82560, fl[22]);
  } else if (i >= BF_BASE) {
    int j = i - BF_BASE;
    bf16* bw = (bf16*)(pw + BF_BASE);
#pragma unroll
    for (int q = 0; q < 2; q++) {
      int u = 2 * j + q;
      int m = u >> 14, r = u & 16383;
      int n = r >> 7, k = r & 127;
      float v;
      if (m == 0) v = in_rd(Win, (size_t)n * 128 + k, fl[14]);
      else if (m == 1) v = in_rd(Wo1, (size_t)n * 128 + k, fl[19]);
      else if (m == 2) v = in_rd(root, (size_t)k * 128 + n, fl[17]);
      else v = in_rd(rw, (size_t)(m - 3) * 16384 + (size_t)k * 128 + n, fl[16]);
      bw[u] = __float2bfloat16(v);
    }
  }
}

// Builds fused encoder weights/biases. EncU out 0-63 = W_des (k in [0,dDes)),
// out 64-95 = W_num (k in [dDes,dDes+dNum)), out 96-127 = W_cat; zero elsewhere.
__global__ void prep_enc(const void* Wd, const void* bd, const void* Wn, const void* bn,
                         const void* Wc, const void* bc, const void* Wt, const void* bt,
                         const int* __restrict__ fl, int dDes, int dNum, int dCat, int dTw,
                         float* __restrict__ pw) {
  int i = blockIdx.x * 256 + threadIdx.x;
  bf16* e = (bf16*)(pw + ENC_BASE);
  float* bU = pw + ENC_BASE + 16384;
  float* bT = bU + 128;
  if (i < 16384) {
    int n = i >> 7, k = i & 127;
    float v = 0.f;
    if (n < 64) {
      if (k < dDes) v = in_rd(Wd, (size_t)n * dDes + k, fl[6]);
    } else if (n < 96) {
      int kk = k - dDes;
      if (kk >= 0 && kk < dNum) v = in_rd(Wn, (size_t)(n - 64) * dNum + kk, fl[8]);
    } else {
      int kk = k - dDes - dNum;
      if (kk >= 0 && kk < dCat) v = in_rd(Wc, (size_t)(n - 96) * dCat + kk, fl[10]);
    }
    e[i] = __float2bfloat16(v);
  } else if (i < 32768) {
    int j = i - 16384;
    int n = j >> 7, k = j & 127;
    float v = (k < dTw) ? in_rd(Wt, (size_t)n * dTw + k, fl[12]) : 0.f;
    e[i] = __float2bfloat16(v);
  } else if (i < 32896) {
    int j = i - 32768;
    bU[j] = (j < 64) ? in_rd(bd, j, fl[7])
                     : (j < 96) ? in_rd(bn, j - 64, fl[9]) : in_rd(bc, j - 96, fl[11]);
  } else if (i < 33024) {
    bT[i - 32896] = in_rd(bt, i - 32896, fl[13]);
  }
}

// ---------------- utilities ----------------
__global__ void sig_fill(float* __restrict__ p, int n, float v) {
  int i = blockIdx.x * 256 + threadIdx.x;
  if (i < n) p[i] = v;
}
__global__ void zero_ints(int* __restrict__ p, int n) {
  int i = blockIdx.x * 256 + threadIdx.x;
  if (i < n) p[i] = 0;
}

// ---------------- CSR build ----------------
__global__ void count_edges(const void* __restrict__ ei, const void* __restrict__ et,
                            const int* __restrict__ fl, int* __restrict__ cnt, int NEr,
                            int NNr) {
  int e = blockIdx.x * 256 + threadIdx.x;
  if (e >= NEr) return;
  int d = ix_rd(ei, (size_t)NEr + e, fl[4]);
  int r = ix_rd(et, e, fl[5]) & 1;
  if ((unsigned)d >= (unsigned)NNr) return;
  atomicAdd(&cnt[r * NNr + d], 1);
}

__global__ void scan_blocks(const int* __restrict__ in, int* __restrict__ out,
                            int* __restrict__ bsum, int n) {
  __shared__ int sh[256];
  int t = threadIdx.x;
  int base = blockIdx.x * 1024 + t * 4;
  int a[4];
  int s = 0;
#pragma unroll
  for (int i = 0; i < 4; i++) {
    a[i] = (base + i < n) ? in[base + i] : 0;
    s += a[i];
  }
  sh[t] = s;
  __syncthreads();
  for (int d = 1; d < 256; d <<= 1) {
    int v = (t >= d) ? sh[t - d] : 0;
    __syncthreads();
    sh[t] += v;
    __syncthreads();
  }
  int ex = sh[t] - s;
#pragma unroll
  for (int i = 0; i < 4; i++) {
    if (base + i < n) out[base + i] = ex;
    ex += a[i];
  }
  if (t == 255 && bsum) bsum[blockIdx.x] = sh[255];
}

__global__ void scan_add_inv(int* __restrict__ off, const int* __restrict__ bsumsc,
                             const int* __restrict__ cnt, float* __restrict__ inv, int n) {
  int i = blockIdx.x * 256 + threadIdx.x;
  if (i >= n) return;
  off[i] += bsumsc[i >> 10];
  inv[i] = 1.f / fmaxf((float)cnt[i], 1.f);
}

// elist word packs: bits [0,24) = src node id (top bits unused by the conv kernel now)
__global__ void fill_elist(const void* __restrict__ ei, const void* __restrict__ et,
                           const int* __restrict__ fl, const int* __restrict__ off,
                           int* __restrict__ fill, int* __restrict__ elist, int NEr, int NNr) {
  int e = blockIdx.x * 256 + threadIdx.x;
  if (e >= NEr) return;
  int s = ix_rd(ei, e, fl[4]);
  int d = ix_rd(ei, (size_t)NEr + e, fl[4]);
  int r = ix_rd(et, e, fl[5]) & 1;
  if ((unsigned)d >= (unsigned)NNr || (unsigned)s >= (unsigned)NNr) return;
  int idx = r * NNr + d;
  int slot = off[idx] + atomicAdd(&fill[idx], 1);
  elist[slot] = s | ((d & 127) << 24);
}

// ---------------- legacy encoder GEMM (fallback for oversized K) ----------------
__global__ __launch_bounds__(256) void enc_gemm(const void* __restrict__ A,
                                                const void* __restrict__ W,
                                                const void* __restrict__ B,
                                                const int* __restrict__ fl, int fa, int fw,
                                                int fb, bf16* __restrict__ x, int M, int K,
                                                int N, int row0, int col0) {
  __shared__ float Wb[128 * 102];
  __shared__ float bb[128];
  int t = threadIdx.x;
  int stride = (K & 1) ? K : K + 1;
  int fA = fl[fa];
  {
    int fW = fl[fw], fB = fl[fb];
    for (int idx = t; idx < N * K; idx += 256) {
      int j = idx / K, k = idx - j * K;
      Wb[j * stride + k] = in_rd(W, (size_t)j * K + k, fW);
    }
    if (t < N) bb[t] = in_rd(B, t, fB);
  }
  __syncthreads();
  int j = t % N;
  int r = t / N;
  int R = 256 / N;
  int iEnd = blockIdx.x * 64 + 64;
  if (iEnd > M) iEnd = M;
  const float* wrow = &Wb[j * stride];
  if (!fA) {
    const float* Af = (const float*)A;
    for (int i = blockIdx.x * 64 + r; i < iEnd; i += R) {
      const float* a = Af + (size_t)i * K;
      float acc = bb[j];
      for (int k = 0; k < K; k++) acc += a[k] * wrow[k];
      stv(&x[(size_t)(row0 + i) * 128 + col0 + j], lrelu(acc));
    }
  } else {
    const bf16* Ab = (const bf16*)A;
    for (int i = blockIdx.x * 64 + r; i < iEnd; i += R) {
      const bf16* a = Ab + (size_t)i * K;
      float acc = bb[j];
      for (int k = 0; k < K; k++) acc += __bfloat162float(a[k]) * wrow[k];
      stv(&x[(size_t)(row0 + i) * 128 + col0 + j], lrelu(acc));
    }
  }
}

// ================= MFMA GEMMs (bf16 storage, fp32 accumulate) =================
// v_mfma_f32_16x16x32_bf16 fragments (m89/m91-verified C/D mapping):
//   A: lane l holds A[m = l&15][k = (l>>4)*8 + i]
//   B: lane l holds B[k = (l>>4)*8 + i][n = l&15]  (= Wt[n][k] with Wt in [out][in] layout)
//   D: lane l reg j -> row = (l>>4)*4 + j, col = l&15

// MFMA encoder: stages up to 3 input segments (fused-K, zero-padded to 128) into a
// bf16 LDS tile, then 128x128 K=128 MFMA with fused [out][in] weight + bias + lrelu.
// LDS rows XOR-swizzled (byte ^= (row&7)<<4): 256B-stride rows otherwise 16-way conflict.
__global__ __launch_bounds__(256) void enc_mfma(
    const void* __restrict__ A0, const void* __restrict__ A1, const void* __restrict__ A2,
    const int* __restrict__ fl, int fi0, int fi1, int fi2, int K0, int K1, int K2,
    const bf16* __restrict__ WbE, const float* __restrict__ biasE, bf16* __restrict__ x,
    int M, int row0) {
  __shared__ __align__(16) bf16 Xs[16384];
  int t = threadIdx.x;
  int i0 = blockIdx.x * 128;

  // zero tile (covers K-pad and rows >= M)
  {
    uint4 z = {0u, 0u, 0u, 0u};
#pragma unroll
    for (int i = 0; i < 8; i++) *(uint4*)((char*)Xs + i * 4096 + t * 16) = z;
  }
  __syncthreads();

  // stage segments, flat-coalesced over 128*Ks elements each
  const void* As[3] = {A0, A1, A2};
  int Ks_[3] = {K0, K1, K2};
  int fis[3] = {fi0, fi1, fi2};
  int cb = 0;
  for (int s = 0; s < 3; s++) {
    int Ks = Ks_[s];
    if (Ks <= 0) continue;
    int isbf = fl[fis[s]];
    const void* A = As[s];
    int total = 128 * Ks;
    for (int f = t; f < total; f += 256) {
      int row = f / Ks;
      int k = f - row * Ks;
      int gr = i0 + row;
      float v = (gr < M) ? in_rd(A, (size_t)gr * Ks + k, isbf) : 0.f;
      int byte = row * 256 + (cb + k) * 2;
      *(bf16*)((char*)Xs + (byte ^ ((row & 7) << 4))) = __float2bfloat16(v);
    }
    cb += Ks;
  }
  __syncthreads();

  // 128x128 K=128 MFMA; 4 waves 2x2; wave = 64x64 (4x4 fragments)
  int wv = t >> 6, l = t & 63;
  int lr = l & 15, lg = l >> 4;
  int rbase = (wv >> 1) * 64, cbase = (wv & 1) * 64;
  int ko = lg * 8;
  f32x4 acc[4][4] = {};
#pragma unroll
  for (int ks = 0; ks < 4; ks++) {
    bfv8 bk[4];
#pragma unroll
    for (int cg = 0; cg < 4; cg++)
      bk[cg] = *(const bfv8*)&WbE[(size_t)(cbase + cg * 16 + lr) * 128 + ks * 32 + ko];
    bfv8 af[4];
#pragma unroll
    for (int rg = 0; rg < 4; rg++) {
      int mrow = rbase + rg * 16 + lr;
      int byte = mrow * 256 + (ks * 32 + ko) * 2;
      af[rg] = *(const bfv8*)((const char*)Xs + (byte ^ ((mrow & 7) << 4)));
    }
#pragma unroll
    for (int rg = 0; rg < 4; rg++)
#pragma unroll
      for (int cg = 0; cg < 4; cg++)
        acc[rg][cg] =
            __builtin_amdgcn_mfma_f32_16x16x32_bf16(af[rg], bk[cg], acc[rg][cg], 0, 0, 0);
  }

#pragma unroll
  for (int cg = 0; cg < 4; cg++) {
    int col = cbase + cg * 16 + lr;
    float bv = biasE[col];
#pragma unroll
    for (int rg = 0; rg < 4; rg++) {
      int r0 = i0 + rbase + rg * 16 + lg * 4;
#pragma unroll
      for (int j = 0; j < 4; j++) {
        int row = r0 + j;
        if (row < M)
          x[(size_t)(row0 + row) * 128 + col] = __float2bfloat16(lrelu(acc[rg][cg][j] + bv));
      }
    }
  }
}

// Out = lrelu(A @ Wb^T + bias); A,Out bf16 [M][128]; Wb bf16 [out][in]
// Block = 128 rows x 128 cols; 4 waves 2x2; wave = 64x64 (4x4 fragments).
__global__ __launch_bounds__(256) void mfma_lin(const bf16* __restrict__ A,
                                                const bf16* __restrict__ Wb,
                                                const float* __restrict__ bias,
                                                bf16* __restrict__ Out, int M) {
  int t = threadIdx.x;
  int wv = t >> 6, l = t & 63;
  int lr = l & 15, lg = l >> 4;
  int i0 = blockIdx.x * 128;
  int rbase = (wv >> 1) * 64;
  int cbase = (wv & 1) * 64;
  int ko = lg * 8;

  size_t rowoff[4];
#pragma unroll
  for (int rg = 0; rg < 4; rg++) {
    int row = i0 + rbase + rg * 16 + lr;
    if (row > M - 1) row = M - 1;  // clamp: junk rows never stored
    rowoff[rg] = (size_t)row * 128;
  }

  bfv8 bfr[4][4];
#pragma unroll
  for (int cg = 0; cg < 4; cg++)
#pragma unroll
    for (int ks = 0; ks < 4; ks++)
      bfr[cg][ks] = *(const bfv8*)&Wb[(size_t)(cbase + cg * 16 + lr) * 128 + ks * 32 + ko];

  f32x4 acc[4][4] = {};
#pragma unroll
  for (int ks = 0; ks < 4; ks++) {
    bfv8 af[4];
#pragma unroll
    for (int rg = 0; rg < 4; rg++) af[rg] = *(const bfv8*)&A[rowoff[rg] + ks * 32 + ko];
#pragma unroll
    for (int rg = 0; rg < 4; rg++)
#pragma unroll
      for (int cg = 0; cg < 4; cg++)
        acc[rg][cg] =
            __builtin_amdgcn_mfma_f32_16x16x32_bf16(af[rg], bfr[cg][ks], acc[rg][cg], 0, 0, 0);
  }

#pragma unroll
  for (int cg = 0; cg < 4; cg++) {
    int col = cbase + cg * 16 + lr;
    float bv = bias[col];
#pragma unroll
    for (int rg = 0; rg < 4; rg++) {
      int row0 = i0 + rbase + rg * 16 + lg * 4;
#pragma unroll
      for (int j = 0; j < 4; j++) {
        int row = row0 + j;
        if (row < M) Out[(size_t)row * 128 + col] = __float2bfloat16(lrelu(acc[rg][cg][j] + bv));
      }
    }
  }
}

// Fused RGCN conv: Out = X@root + mean_r0(X)@rw0 + mean_r1(X)@rw1 + bias.
// 32-row blocks; both relations in one 32KB fp32 LDS tile (vrows 0-31 rel0, 32-63 rel1).
// OWNERSHIP gather: item = (vrow, 8-col chunk) owned by one thread. JOINT 4-cursor walk:
// all 4 owned items step together (merged loop to max(deg), per-item predication) with
// next-step elist+X loads issued before this step's accumulate -> ~4 random X-row loads
// in flight per wave (R5 was serial walks, ~2 in flight; latency-bound at 162us).
// Every slot written (zeros if deg=0 / out of range) -> no zero pass, ONE barrier total.
// LDS XOR-swizzle byte ^= (vrow&7)<<4 (512B-stride rows otherwise 16-way conflict on read).
__global__ __launch_bounds__(256, 4) void mfma_conv_f(
    const bf16* __restrict__ X, const int* __restrict__ off, const int* __restrict__ cnt,
    const int* __restrict__ elist, const float* __restrict__ inv,
    const bf16* __restrict__ WB, const float* __restrict__ bias, bf16* __restrict__ Out,
    int M, int NNr) {
  __shared__ __align__(16) float At[64 * 128];
  int t = threadIdx.x;
  int wv = t >> 6, l = t & 63;
  int lr = l & 15, lg = l >> 4;
  int i0 = blockIdx.x * 32;
  int cbase = wv * 32;
  int ko = lg * 8;

  // ---- joint 4-cursor ownership gather ----
  {
    int c8 = (t & 15) * 8;  // col chunk base (elements)
    int st_[4], dg[4];
    float s[4][8] = {};
#pragma unroll
    for (int pn = 0; pn < 4; pn++) {
      int vr = (t >> 4) + pn * 16;  // 0..63
      int rel = vr >> 5, m = vr & 31;
      int node = i0 + m;
      if (node < M) {
        int idx = rel * NNr + node;
        st_[pn] = off[idx];
        dg[pn] = cnt[idx];
      } else {
        st_[pn] = 0;
        dg[pn] = 0;
      }
    }
    int dmax = max(max(dg[0], dg[1]), max(dg[2], dg[3]));
    bfv8 v[4];
#pragma unroll
    for (int pn = 0; pn < 4; pn++) {
      if (dg[pn] > 0) {
        int src = elist[st_[pn]] & 0xFFFFFF;
        v[pn] = *(const bfv8*)&X[(size_t)src * 128 + c8];
      }
    }
    for (int e = 0; e < dmax; e++) {
      bfv8 nv[4];
#pragma unroll
      for (int pn = 0; pn < 4; pn++) {
        if (e + 1 < dg[pn]) {
          int src = elist[st_[pn] + e + 1] & 0xFFFFFF;
          nv[pn] = *(const bfv8*)&X[(size_t)src * 128 + c8];
        }
      }
#pragma unroll
      for (int pn = 0; pn < 4; pn++) {
        if (e < dg[pn]) {
#pragma unroll
          for (int j = 0; j < 8; j++) s[pn][j] += __bfloat162float(v[pn][j]);
        }
      }
#pragma unroll
      for (int pn = 0; pn < 4; pn++) v[pn] = nv[pn];
    }
#pragma unroll
    for (int pn = 0; pn < 4; pn++) {
      int vr = (t >> 4) + pn * 16;
      int sw = (vr & 7) << 4;
      int lb = vr * 512 + c8 * 4;
      *(float4*)((char*)At + (lb ^ sw)) = make_float4(s[pn][0], s[pn][1], s[pn][2], s[pn][3]);
      *(float4*)((char*)At + ((lb + 16) ^ sw)) =
          make_float4(s[pn][4], s[pn][5], s[pn][6], s[pn][7]);
    }
  }

  // row clamps and inv scales
  size_t rowoff[2];
  float iv0[2], iv1[2];
#pragma unroll
  for (int rg = 0; rg < 2; rg++) {
    int row = i0 + rg * 16 + lr;
    int rc = row < M ? row : M - 1;
    rowoff[rg] = (size_t)rc * 128;
    iv0[rg] = row < M ? inv[row] : 0.f;
    iv1[rg] = row < M ? inv[NNr + row] : 0.f;
  }

  f32x4 acc[2][2] = {};

  // ---- seg 0: X @ root from global (independent of LDS; overlaps store latency) ----
#pragma unroll
  for (int ks = 0; ks < 4; ks++) {
    bfv8 bk[2];
#pragma unroll
    for (int cg = 0; cg < 2; cg++)
      bk[cg] = *(const bfv8*)&WB[(size_t)(cbase + cg * 16 + lr) * 128 + ks * 32 + ko];
    bfv8 af[2];
#pragma unroll
    for (int rg = 0; rg < 2; rg++) af[rg] = *(const bfv8*)&X[rowoff[rg] + ks * 32 + ko];
#pragma unroll
    for (int rg = 0; rg < 2; rg++)
#pragma unroll
      for (int cg = 0; cg < 2; cg++)
        acc[rg][cg] =
            __builtin_amdgcn_mfma_f32_16x16x32_bf16(af[rg], bk[cg], acc[rg][cg], 0, 0, 0);
  }
  __syncthreads();

  // ---- rel-0 / rel-1 MFMA from LDS (inv-scaled, cvt to bf16) ----
#pragma unroll
  for (int r = 0; r < 2; r++) {
    const bf16* Wb = WB + 16384 * (1 + r);
#pragma unroll
    for (int ks = 0; ks < 4; ks++) {
      bfv8 bk[2];
#pragma unroll
      for (int cg = 0; cg < 2; cg++)
        bk[cg] = *(const bfv8*)&Wb[(size_t)(cbase + cg * 16 + lr) * 128 + ks * 32 + ko];
      bfv8 af[2];
#pragma unroll
      for (int rg = 0; rg < 2; rg++) {
        int mrow = r * 32 + rg * 16 + lr;
        int lb = mrow * 512 + ks * 128 + ko * 4;
        int sw = (mrow & 7) << 4;
        float4 f0 = *(const float4*)((const char*)At + (lb ^ sw));
        float4 f1 = *(const float4*)((const char*)At + ((lb + 16) ^ sw));
        float iv = r ? iv1[rg] : iv0[rg];
        bfv8 a;
        a[0] = (__bf16)(f0.x * iv); a[1] = (__bf16)(f0.y * iv);
        a[2] = (__bf16)(f0.z * iv); a[3] = (__bf16)(f0.w * iv);
        a[4] = (__bf16)(f1.x * iv); a[5] = (__bf16)(f1.y * iv);
        a[6] = (__bf16)(f1.z * iv); a[7] = (__bf16)(f1.w * iv);
        af[rg] = a;
      }
#pragma unroll
      for (int rg = 0; rg < 2; rg++)
#pragma unroll
        for (int cg = 0; cg < 2; cg++)
          acc[rg][cg] =
              __builtin_amdgcn_mfma_f32_16x16x32_bf16(af[rg], bk[cg], acc[rg][cg], 0, 0, 0);
    }
  }

  // ---- epilogue: + bias, no activation ----
#pragma unroll
  for (int cg = 0; cg < 2; cg++) {
    int col = cbase + cg * 16 + lr;
    float bv = bias[col];
#pragma unroll
    for (int rg = 0; rg < 2; rg++) {
      int row0 = i0 + rg * 16 + lg * 4;
#pragma unroll
      for (int j = 0; j < 4; j++) {
        int row = row0 + j;
        if (row < M) Out[(size_t)row * 128 + col] = __float2bfloat16(acc[rg][cg][j] + bv);
      }
    }
  }
}

// ---------------- final 128 -> 2 linear, FP32 out ----------------
__global__ void out_linear(const bf16* __restrict__ x, const float* __restrict__ W,
                           const float* __restrict__ B, float* __restrict__ out, int NNr) {
  int wave = threadIdx.x >> 6;
  int lane = threadIdx.x & 63;
  int i = blockIdx.x * 4 + wave;
  if (i >= NNr) return;
  const bf16* xr = x + (size_t)i * 128;
  float x0 = ldv(xr[lane]);
  float x1 = ldv(xr[lane + 64]);
  float p0 = x0 * W[lane] + x1 * W[lane + 64];
  float p1 = x0 * W[128 + lane] + x1 * W[128 + lane + 64];
#pragma unroll
  for (int offs = 32; offs; offs >>= 1) {
    p0 += __shfl_down(p0, offs, 64);
    p1 += __shfl_down(p1, offs, 64);
  }
  if (lane == 0) {
    out[(size_t)i * 2] = p0 + B[0];
    out[(size_t)i * 2 + 1] = p1 + B[1];
  }
}

// ---------------- pipeline (bf16 storage, MFMA everywhere) ----------------
static void run_pipeline(void* const* d_in, const int* S, float* out, char* ws,
                         int NUr, int NTr, int NEr, int dDes, int dNum, int dCat, int dTw,
                         hipStream_t stream) {
  const int NNr = NUr + NTr;
  const size_t xbytes = (size_t)NNr * 128 * 2;

  bf16* xa = (bf16*)ws;
  bf16* xb = (bf16*)(ws + xbytes);
  char* p = ws + 2 * xbytes;
  int* cnt = (int*)p;      p += (size_t)2 * NNr * 4;
  int* fill = (int*)p;     p += (size_t)2 * NNr * 4;  // contiguous with cnt
  int* off = (int*)p;      p += (size_t)2 * NNr * 4;
  int* bsum = (int*)p;     p += 2048 * 4;             // contiguous with bsumsc
  int* bsumsc = (int*)p;   p += 2048 * 4;
  float* inv = (float*)p;  p += (size_t)2 * NNr * 4;
  int* elist = (int*)p;    p += (size_t)NEr * 4;
  float* pw = (float*)p;   p += (size_t)PW_TOTAL * 4;
  int* flags = (int*)p;

  // ---- format probes: one launch ----
  ProbeArgs pa;
  for (int i = 0; i < 23; i++) {
    int src = (i == 22) ? 21 : i;  // b_o2 (2 elems) inherits W_o2's dtype
    pa.p[i] = d_in[src];
    if (i == 4) {
      pa.mode[i] = 1;
      pa.s[i] = NEr < 256 ? NEr : 256;
    } else if (i == 5) {
      pa.mode[i] = 1;
      int s2 = NEr / 2 < 256 ? NEr / 2 : 256;
      pa.s[i] = s2 < 1 ? 1 : s2;
    } else {
      pa.mode[i] = 0;
      int s = S[src] / 2;
      if (s > 256) s = 256;
      if (s < 1) s = 1;
      pa.s[i] = s;
    }
  }
  detect_all<<<23, 256, 0, stream>>>(pa, flags);
  prep_weights<<<(PW_W_TOTAL + 255) / 256, 256, 0, stream>>>(
      d_in[14], d_in[15], d_in[16], d_in[17], d_in[18], d_in[19], d_in[20], d_in[21],
      d_in[22], flags, pw);
  prep_enc<<<129, 256, 0, stream>>>(d_in[6], d_in[7], d_in[8], d_in[9], d_in[10], d_in[11],
                                    d_in[12], d_in[13], flags, dDes, dNum, dCat, dTw, pw);

  const float* bIn = pw + 81920;
  const float* rbp = pw + 82048;
  const float* bO1 = pw + 82176;
  const float* Wo2p = pw + 82304;
  const float* bo2p = pw + 82560;
  const bf16* WinB = (const bf16*)(pw + BF_BASE);
  const bf16* Wo1B = (const bf16*)(pw + BF_BASE + 8192);
  const bf16* ConvB = (const bf16*)(pw + BF_BASE + 16384);  // rootB, rwB0, rwB1
  const bf16* EncU = (const bf16*)(pw + ENC_BASE);
  const bf16* EncT = (const bf16*)(pw + ENC_BASE + 8192);
  const float* bU = pw + ENC_BASE + 16384;
  const float* bT = bU + 128;

  const void* ei = d_in[4];
  const void* et = d_in[5];
  const int nb1 = (2 * NNr + 1023) / 1024;

  // ---- CSR build ----
  zero_ints<<<(4 * NNr + 255) / 256, 256, 0, stream>>>(cnt, 4 * NNr);
  zero_ints<<<16, 256, 0, stream>>>(bsum, 4096);
  count_edges<<<(NEr + 255) / 256, 256, 0, stream>>>(ei, et, flags, cnt, NEr, NNr);
  scan_blocks<<<nb1, 256, 0, stream>>>(cnt, off, bsum, 2 * NNr);
  scan_blocks<<<1, 256, 0, stream>>>(bsum, bsumsc, nullptr, nb1);
  scan_add_inv<<<(2 * NNr + 255) / 256, 256, 0, stream>>>(off, bsumsc, cnt, inv, 2 * NNr);
  fill_elist<<<(NEr + 255) / 256, 256, 0, stream>>>(ei, et, flags, off, fill, elist, NEr, NNr);

  // ---- encoders -> xa ----
  if (dDes + dNum + dCat <= 128 && dTw <= 128) {
    enc_mfma<<<(NUr + 127) / 128, 256, 0, stream>>>(d_in[0], d_in[2], d_in[3], flags, 0, 2, 3,
                                                    dDes, dNum, dCat, EncU, bU, xa, NUr, 0);
    enc_mfma<<<(NTr + 127) / 128, 256, 0, stream>>>(d_in[1], nullptr, nullptr, flags, 1, 1, 1,
                                                    dTw, 0, 0, EncT, bT, xa, NTr, NUr);
  } else {
    enc_gemm<<<(NUr + 63) / 64, 256, 0, stream>>>(d_in[0], d_in[6], d_in[7], flags, 0, 6, 7,
                                                  xa, NUr, dDes, 64, 0, 0);
    enc_gemm<<<(NUr + 63) / 64, 256, 0, stream>>>(d_in[2], d_in[8], d_in[9], flags, 2, 8, 9,
                                                  xa, NUr, dNum, 32, 0, 64);
    enc_gemm<<<(NUr + 63) / 64, 256, 0, stream>>>(d_in[3], d_in[10], d_in[11], flags, 3, 10,
                                                  11, xa, NUr, dCat, 32, 0, 96);
    enc_gemm<<<(NTr + 63) / 64, 256, 0, stream>>>(d_in[1], d_in[12], d_in[13], flags, 1, 12,
                                                  13, xa, NTr, dTw, 128, NUr, 0);
  }

  const int mt = (NNr + 127) / 128;
  const int mt32 = (NNr + 31) / 32;
  mfma_lin<<<mt, 256, 0, stream>>>(xa, WinB, bIn, xb, NNr);
  mfma_conv_f<<<mt32, 256, 0, stream>>>(xb, off, cnt, elist, inv, ConvB, rbp, xa, NNr, NNr);
  mfma_conv_f<<<mt32, 256, 0, stream>>>(xa, off, cnt, elist, inv, ConvB, rbp, xb, NNr, NNr);
  mfma_lin<<<mt, 256, 0, stream>>>(xb, Wo1B, bO1, xa, NNr);
  out_linear<<<(NNr + 3) / 4, 256, 0, stream>>>(xa, Wo2p, bo2p, out, NNr);
}

extern "C" void kernel_launch(void* const* d_in, const int* in_sizes, int n_in,
                              void* d_out, int out_size, void* d_ws, size_t ws_size,
                              hipStream_t stream) {
  float* out = (float*)d_out;
  char* ws = (char*)d_ws;

  auto signal = [&](int k) {
    sig_fill<<<(out_size + 255) / 256, 256, 0, stream>>>(out, out_size, (float)(200 + k));
  };

  if (n_in != 23) { signal(1); return; }
  const int* S = in_sizes;
  if (S[7] != 64 || S[9] != 32 || S[11] != 32 || S[13] != 128) { signal(2); return; }
  if (S[15] != 128) { signal(3); return; }
  if (S[6] % 64 || S[8] % 32 || S[10] % 32 || S[12] % 128) { signal(4); return; }
  int dDes = S[6] / 64, dNum = S[8] / 32, dCat = S[10] / 32, dTw = S[12] / 128;
  if (dDes <= 0 || dTw <= 0 || S[0] % dDes || S[1] % dTw) { signal(5); return; }
  if (dDes > 101 || dNum > 101 || dCat > 101 || dTw > 101) { signal(4); return; }
  int NUr = S[0] / dDes, NTr = S[1] / dTw, NNr = NUr + NTr, NEr = S[5];
  if (S[2] != NUr * dNum || S[3] != NUr * dCat) { signal(5); return; }
  if (S[4] != 2 * NEr || NEr < 1024) { signal(6); return; }
  if (NNr >= (1 << 24)) { signal(6); return; }  // elist src-packing limit
  if (S[14] != 16384 || S[16] != 32768 || S[17] != 16384 || S[18] != 128 ||
      S[19] != 16384 || S[20] != 128 || S[21] != 256 || S[22] != 2) { signal(7); return; }
  if (out_size != NNr * 2) { signal(8); return; }

  const size_t smallBytes = (size_t)4 * ((size_t)2 * NNr * 4) + 2 * 2048 * 4 +
                            (size_t)NEr * 4 + (size_t)PW_TOTAL * 4 + 512;
  const size_t need = 2 * (size_t)NNr * 128 * 2 + smallBytes;

  if (ws_size >= need) {
    run_pipeline(d_in, S, out, ws, NUr, NTr, NEr, dDes, dNum, dCat, dTw, stream);
  } else {
    signal(9);
  }
}

// Round 7
// 520.649 us; speedup vs baseline: 6.3324x; 1.2215x over previous
//
#include <hip/hip_runtime.h>
#include <hip/hip_bf16.h>

typedef __hip_bfloat16 bf16;

typedef __bf16 bfv8 __attribute__((ext_vector_type(8)));
typedef float f32x4 __attribute__((ext_vector_type(4)));

__device__ __forceinline__ float lrelu(float x) { return x > 0.f ? x : 0.01f * x; }

__device__ __forceinline__ float ldv(float v) { return v; }
__device__ __forceinline__ float ldv(bf16 v) { return __bfloat162float(v); }
__device__ __forceinline__ void stv(float* p, float v) { *p = v; }
__device__ __forceinline__ void stv(bf16* p, float v) { *p = __float2bfloat16(v); }

__device__ __forceinline__ float in_rd(const void* p, size_t i, int isbf) {
  return isbf ? __bfloat162float(((const bf16*)p)[i]) : ((const float*)p)[i];
}
__device__ __forceinline__ int ix_rd(const void* p, size_t i, int is64) {
  return is64 ? (int)((const long long*)p)[i] : ((const int*)p)[i];
}

// ---------------- fused per-array format probe: one launch, 23 blocks ----------------
struct ProbeArgs {
  const void* p[23];
  int s[23];
  int mode[23];
};

__global__ void detect_all(ProbeArgs a, int* __restrict__ flags) {
  __shared__ int sh[256];
  int b = blockIdx.x;
  const unsigned int* w = (const unsigned int*)a.p[b];
  int s = a.s[b], mode = a.mode[b];
  int t = threadIdx.x;
  int c = 0;
  if (t < s) {
    if (mode == 0) {
      unsigned int v = w[t];
      int e = (v >> 7) & 0xFF;
      c = (e >= 100 && e <= 140) ? 1 : 0;
    } else {
      c = (w[2 * t + 1] == 0u) ? 1 : 0;
    }
  }
  sh[t] = c;
  __syncthreads();
  for (int d = 128; d; d >>= 1) {
    if (t < d) sh[t] += sh[t + d];
    __syncthreads();
  }
  if (t == 0) flags[b] = (mode == 0) ? (sh[0] * 10 >= 7 * s) : (sh[0] * 10 >= 9 * s);
}

// ---------------- weight prep ----------------
// fp32 region (floats): [0,16384) W_inT [k,n]; [16384,32768) W_o1T [k,n]; [32768,49152) root;
// [49152,81920) rw; [81920] b_in; [82048] rgcn_bias; [82176] b_o1; [82304] W_o2; [82560] b_o2
// bf16 region (starting at float index BF_BASE, 16B aligned), each [128][128] bf16 in
// [n][k] (out,in) layout for MFMA B-fragments:
//   m=0 WinB; m=1 Wo1B; m=2 rootB; m=3 rwB0; m=4 rwB1   (rootB,rwB0,rwB1 contiguous)
// ENC region (float index ENC_BASE): EncU bf16[128][128] fused user-encoder weight
// ([des|num|cat] block-diagonal, zero-padded); EncT bf16[128][128] tweet weight; biasU[128];
// biasT[128].
#define PW_F32 82562
#define BF_BASE 82564
#define PW_W_TOTAL (BF_BASE + 5 * 8192)
#define ENC_BASE PW_W_TOTAL
#define PW_TOTAL (ENC_BASE + 16384 + 256)
__global__ void prep_weights(const void* Win, const void* bin, const void* rw,
                             const void* root, const void* rb, const void* Wo1,
                             const void* bo1, const void* Wo2, const void* bo2,
                             const int* __restrict__ fl, float* __restrict__ pw) {
  int i = blockIdx.x * 256 + threadIdx.x;
  if (i >= PW_W_TOTAL) return;
  if (i < 16384) {
    int k = i >> 7, o = i & 127;
    pw[i] = in_rd(Win, (size_t)o * 128 + k, fl[14]);
  } else if (i < 32768) {
    int j = i - 16384;
    int k = j >> 7, o = j & 127;
    pw[i] = in_rd(Wo1, (size_t)o * 128 + k, fl[19]);
  } else if (i < 49152) {
    pw[i] = in_rd(root, i - 32768, fl[17]);
  } else if (i < 81920) {
    pw[i] = in_rd(rw, i - 49152, fl[16]);
  } else if (i < 82048) {
    pw[i] = in_rd(bin, i - 81920, fl[15]);
  } else if (i < 82176) {
    pw[i] = in_rd(rb, i - 82048, fl[18]);
  } else if (i < 82304) {
    pw[i] = in_rd(bo1, i - 82176, fl[20]);
  } else if (i < 82560) {
    pw[i] = in_rd(Wo2, i - 82304, fl[21]);
  } else if (i < PW_F32) {
    pw[i] = in_rd(bo2, i - 82560, fl[22]);
  } else if (i >= BF_BASE) {
    int j = i - BF_BASE;
    bf16* bw = (bf16*)(pw + BF_BASE);
#pragma unroll
    for (int q = 0; q < 2; q++) {
      int u = 2 * j + q;
      int m = u >> 14, r = u & 16383;
      int n = r >> 7, k = r & 127;
      float v;
      if (m == 0) v = in_rd(Win, (size_t)n * 128 + k, fl[14]);
      else if (m == 1) v = in_rd(Wo1, (size_t)n * 128 + k, fl[19]);
      else if (m == 2) v = in_rd(root, (size_t)k * 128 + n, fl[17]);
      else v = in_rd(rw, (size_t)(m - 3) * 16384 + (size_t)k * 128 + n, fl[16]);
      bw[u] = __float2bfloat16(v);
    }
  }
}

// Builds fused encoder weights/biases. EncU out 0-63 = W_des (k in [0,dDes)),
// out 64-95 = W_num (k in [dDes,dDes+dNum)), out 96-127 = W_cat; zero elsewhere.
__global__ void prep_enc(const void* Wd, const void* bd, const void* Wn, const void* bn,
                         const void* Wc, const void* bc, const void* Wt, const void* bt,
                         const int* __restrict__ fl, int dDes, int dNum, int dCat, int dTw,
                         float* __restrict__ pw) {
  int i = blockIdx.x * 256 + threadIdx.x;
  bf16* e = (bf16*)(pw + ENC_BASE);
  float* bU = pw + ENC_BASE + 16384;
  float* bT = bU + 128;
  if (i < 16384) {
    int n = i >> 7, k = i & 127;
    float v = 0.f;
    if (n < 64) {
      if (k < dDes) v = in_rd(Wd, (size_t)n * dDes + k, fl[6]);
    } else if (n < 96) {
      int kk = k - dDes;
      if (kk >= 0 && kk < dNum) v = in_rd(Wn, (size_t)(n - 64) * dNum + kk, fl[8]);
    } else {
      int kk = k - dDes - dNum;
      if (kk >= 0 && kk < dCat) v = in_rd(Wc, (size_t)(n - 96) * dCat + kk, fl[10]);
    }
    e[i] = __float2bfloat16(v);
  } else if (i < 32768) {
    int j = i - 16384;
    int n = j >> 7, k = j & 127;
    float v = (k < dTw) ? in_rd(Wt, (size_t)n * dTw + k, fl[12]) : 0.f;
    e[i] = __float2bfloat16(v);
  } else if (i < 32896) {
    int j = i - 32768;
    bU[j] = (j < 64) ? in_rd(bd, j, fl[7])
                     : (j < 96) ? in_rd(bn, j - 64, fl[9]) : in_rd(bc, j - 96, fl[11]);
  } else if (i < 33024) {
    bT[i - 32896] = in_rd(bt, i - 32896, fl[13]);
  }
}

// ---------------- utilities ----------------
__global__ void sig_fill(float* __restrict__ p, int n, float v) {
  int i = blockIdx.x * 256 + threadIdx.x;
  if (i < n) p[i] = v;
}
__global__ void zero_ints(int* __restrict__ p, int n) {
  int i = blockIdx.x * 256 + threadIdx.x;
  if (i < n) p[i] = 0;
}

// ---------------- CSR build ----------------
__global__ void count_edges(const void* __restrict__ ei, const void* __restrict__ et,
                            const int* __restrict__ fl, int* __restrict__ cnt, int NEr,
                            int NNr) {
  int e = blockIdx.x * 256 + threadIdx.x;
  if (e >= NEr) return;
  int d = ix_rd(ei, (size_t)NEr + e, fl[4]);
  int r = ix_rd(et, e, fl[5]) & 1;
  if ((unsigned)d >= (unsigned)NNr) return;
  atomicAdd(&cnt[r * NNr + d], 1);
}

__global__ void scan_blocks(const int* __restrict__ in, int* __restrict__ out,
                            int* __restrict__ bsum, int n) {
  __shared__ int sh[256];
  int t = threadIdx.x;
  int base = blockIdx.x * 1024 + t * 4;
  int a[4];
  int s = 0;
#pragma unroll
  for (int i = 0; i < 4; i++) {
    a[i] = (base + i < n) ? in[base + i] : 0;
    s += a[i];
  }
  sh[t] = s;
  __syncthreads();
  for (int d = 1; d < 256; d <<= 1) {
    int v = (t >= d) ? sh[t - d] : 0;
    __syncthreads();
    sh[t] += v;
    __syncthreads();
  }
  int ex = sh[t] - s;
#pragma unroll
  for (int i = 0; i < 4; i++) {
    if (base + i < n) out[base + i] = ex;
    ex += a[i];
  }
  if (t == 255 && bsum) bsum[blockIdx.x] = sh[255];
}

__global__ void scan_add_inv(int* __restrict__ off, const int* __restrict__ bsumsc,
                             const int* __restrict__ cnt, float* __restrict__ inv, int n) {
  int i = blockIdx.x * 256 + threadIdx.x;
  if (i >= n) return;
  off[i] += bsumsc[i >> 10];
  inv[i] = 1.f / fmaxf((float)cnt[i], 1.f);
}

// elist word packs: bits [0,24) = src node id
__global__ void fill_elist(const void* __restrict__ ei, const void* __restrict__ et,
                           const int* __restrict__ fl, const int* __restrict__ off,
                           int* __restrict__ fill, int* __restrict__ elist, int NEr, int NNr) {
  int e = blockIdx.x * 256 + threadIdx.x;
  if (e >= NEr) return;
  int s = ix_rd(ei, e, fl[4]);
  int d = ix_rd(ei, (size_t)NEr + e, fl[4]);
  int r = ix_rd(et, e, fl[5]) & 1;
  if ((unsigned)d >= (unsigned)NNr || (unsigned)s >= (unsigned)NNr) return;
  int idx = r * NNr + d;
  int slot = off[idx] + atomicAdd(&fill[idx], 1);
  elist[slot] = s | ((d & 127) << 24);
}

// ---------------- legacy encoder GEMM (fallback for oversized K) ----------------
__global__ __launch_bounds__(256) void enc_gemm(const void* __restrict__ A,
                                                const void* __restrict__ W,
                                                const void* __restrict__ B,
                                                const int* __restrict__ fl, int fa, int fw,
                                                int fb, bf16* __restrict__ x, int M, int K,
                                                int N, int row0, int col0) {
  __shared__ float Wb[128 * 102];
  __shared__ float bb[128];
  int t = threadIdx.x;
  int stride = (K & 1) ? K : K + 1;
  int fA = fl[fa];
  {
    int fW = fl[fw], fB = fl[fb];
    for (int idx = t; idx < N * K; idx += 256) {
      int j = idx / K, k = idx - j * K;
      Wb[j * stride + k] = in_rd(W, (size_t)j * K + k, fW);
    }
    if (t < N) bb[t] = in_rd(B, t, fB);
  }
  __syncthreads();
  int j = t % N;
  int r = t / N;
  int R = 256 / N;
  int iEnd = blockIdx.x * 64 + 64;
  if (iEnd > M) iEnd = M;
  const float* wrow = &Wb[j * stride];
  if (!fA) {
    const float* Af = (const float*)A;
    for (int i = blockIdx.x * 64 + r; i < iEnd; i += R) {
      const float* a = Af + (size_t)i * K;
      float acc = bb[j];
      for (int k = 0; k < K; k++) acc += a[k] * wrow[k];
      stv(&x[(size_t)(row0 + i) * 128 + col0 + j], lrelu(acc));
    }
  } else {
    const bf16* Ab = (const bf16*)A;
    for (int i = blockIdx.x * 64 + r; i < iEnd; i += R) {
      const bf16* a = Ab + (size_t)i * K;
      float acc = bb[j];
      for (int k = 0; k < K; k++) acc += __bfloat162float(a[k]) * wrow[k];
      stv(&x[(size_t)(row0 + i) * 128 + col0 + j], lrelu(acc));
    }
  }
}

// ================= MFMA GEMMs (bf16 storage, fp32 accumulate) =================
// v_mfma_f32_16x16x32_bf16 fragments (m89/m91-verified C/D mapping):
//   A: lane l holds A[m = l&15][k = (l>>4)*8 + i]
//   B: lane l holds B[k = (l>>4)*8 + i][n = l&15]  (= Wt[n][k] with Wt in [out][in] layout)
//   D: lane l reg j -> row = (l>>4)*4 + j, col = l&15

// Fused MFMA encoder: stages up to 3 input segments (fused-K, zero-padded to 128) into a
// bf16 LDS tile, stage-1 128x128 K=128 MFMA (enc weight) + lrelu -> LDS, then stage-2
// K=128 MFMA (W_in) + lrelu -> global. Saves the xa round trip + a kernel launch.
// LDS rows XOR-swizzled (byte ^= (row&7)<<4): 256B-stride rows otherwise 16-way conflict.
__global__ __launch_bounds__(256) void enc_mfma(
    const void* __restrict__ A0, const void* __restrict__ A1, const void* __restrict__ A2,
    const int* __restrict__ fl, int fi0, int fi1, int fi2, int K0, int K1, int K2,
    const bf16* __restrict__ WbE, const float* __restrict__ biasE,
    const bf16* __restrict__ WbL, const float* __restrict__ bL, bf16* __restrict__ x,
    int M, int row0) {
  __shared__ __align__(16) bf16 Xs[16384];
  int t = threadIdx.x;
  int i0 = blockIdx.x * 128;

  // zero tile (covers K-pad and rows >= M)
  {
    uint4 z = {0u, 0u, 0u, 0u};
#pragma unroll
    for (int i = 0; i < 8; i++) *(uint4*)((char*)Xs + i * 4096 + t * 16) = z;
  }
  __syncthreads();

  // stage segments, flat-coalesced over 128*Ks elements each
  const void* As[3] = {A0, A1, A2};
  int Ks_[3] = {K0, K1, K2};
  int fis[3] = {fi0, fi1, fi2};
  int cb = 0;
  for (int s = 0; s < 3; s++) {
    int Ks = Ks_[s];
    if (Ks <= 0) continue;
    int isbf = fl[fis[s]];
    const void* A = As[s];
    int total = 128 * Ks;
    for (int f = t; f < total; f += 256) {
      int row = f / Ks;
      int k = f - row * Ks;
      int gr = i0 + row;
      float v = (gr < M) ? in_rd(A, (size_t)gr * Ks + k, isbf) : 0.f;
      int byte = row * 256 + (cb + k) * 2;
      *(bf16*)((char*)Xs + (byte ^ ((row & 7) << 4))) = __float2bfloat16(v);
    }
    cb += Ks;
  }
  __syncthreads();

  // stage 1: input @ EncW^T; 4 waves 2x2; wave = 64x64 (4x4 fragments)
  int wv = t >> 6, l = t & 63;
  int lr = l & 15, lg = l >> 4;
  int rbase = (wv >> 1) * 64, cbase = (wv & 1) * 64;
  int ko = lg * 8;
  f32x4 acc[4][4] = {};
#pragma unroll
  for (int ks = 0; ks < 4; ks++) {
    bfv8 bk[4];
#pragma unroll
    for (int cg = 0; cg < 4; cg++)
      bk[cg] = *(const bfv8*)&WbE[(size_t)(cbase + cg * 16 + lr) * 128 + ks * 32 + ko];
    bfv8 af[4];
#pragma unroll
    for (int rg = 0; rg < 4; rg++) {
      int mrow = rbase + rg * 16 + lr;
      int byte = mrow * 256 + (ks * 32 + ko) * 2;
      af[rg] = *(const bfv8*)((const char*)Xs + (byte ^ ((mrow & 7) << 4)));
    }
#pragma unroll
    for (int rg = 0; rg < 4; rg++)
#pragma unroll
      for (int cg = 0; cg < 4; cg++)
        acc[rg][cg] =
            __builtin_amdgcn_mfma_f32_16x16x32_bf16(af[rg], bk[cg], acc[rg][cg], 0, 0, 0);
  }
  __syncthreads();  // all input-tile reads done before overwrite

  // y = lrelu(acc + biasE) -> Xs (bf16, swizzled)
#pragma unroll
  for (int cg = 0; cg < 4; cg++) {
    int col = cbase + cg * 16 + lr;
    float bv = biasE[col];
#pragma unroll
    for (int rg = 0; rg < 4; rg++) {
      int r0 = rbase + rg * 16 + lg * 4;
#pragma unroll
      for (int j = 0; j < 4; j++) {
        int row = r0 + j;
        int byte = row * 256 + col * 2;
        *(bf16*)((char*)Xs + (byte ^ ((row & 7) << 4))) =
            __float2bfloat16(lrelu(acc[rg][cg][j] + bv));
      }
    }
  }
  __syncthreads();

  // stage 2: y @ W_in^T + b_in, lrelu -> global
  f32x4 acc2[4][4] = {};
#pragma unroll
  for (int ks = 0; ks < 4; ks++) {
    bfv8 bk[4];
#pragma unroll
    for (int cg = 0; cg < 4; cg++)
      bk[cg] = *(const bfv8*)&WbL[(size_t)(cbase + cg * 16 + lr) * 128 + ks * 32 + ko];
    bfv8 af[4];
#pragma unroll
    for (int rg = 0; rg < 4; rg++) {
      int mrow = rbase + rg * 16 + lr;
      int byte = mrow * 256 + (ks * 32 + ko) * 2;
      af[rg] = *(const bfv8*)((const char*)Xs + (byte ^ ((mrow & 7) << 4)));
    }
#pragma unroll
    for (int rg = 0; rg < 4; rg++)
#pragma unroll
      for (int cg = 0; cg < 4; cg++)
        acc2[rg][cg] =
            __builtin_amdgcn_mfma_f32_16x16x32_bf16(af[rg], bk[cg], acc2[rg][cg], 0, 0, 0);
  }

#pragma unroll
  for (int cg = 0; cg < 4; cg++) {
    int col = cbase + cg * 16 + lr;
    float bv = bL[col];
#pragma unroll
    for (int rg = 0; rg < 4; rg++) {
      int r0 = i0 + rbase + rg * 16 + lg * 4;
#pragma unroll
      for (int j = 0; j < 4; j++) {
        int row = r0 + j;
        if (row < M)
          x[(size_t)(row0 + row) * 128 + col] = __float2bfloat16(lrelu(acc2[rg][cg][j] + bv));
      }
    }
  }
}

// Out = lrelu(A @ Wb^T + bias); fallback-path linear (used when fused encoder can't run)
__global__ __launch_bounds__(256) void mfma_lin(const bf16* __restrict__ A,
                                                const bf16* __restrict__ Wb,
                                                const float* __restrict__ bias,
                                                bf16* __restrict__ Out, int M) {
  int t = threadIdx.x;
  int wv = t >> 6, l = t & 63;
  int lr = l & 15, lg = l >> 4;
  int i0 = blockIdx.x * 128;
  int rbase = (wv >> 1) * 64;
  int cbase = (wv & 1) * 64;
  int ko = lg * 8;

  size_t rowoff[4];
#pragma unroll
  for (int rg = 0; rg < 4; rg++) {
    int row = i0 + rbase + rg * 16 + lr;
    if (row > M - 1) row = M - 1;
    rowoff[rg] = (size_t)row * 128;
  }

  bfv8 bfr[4][4];
#pragma unroll
  for (int cg = 0; cg < 4; cg++)
#pragma unroll
    for (int ks = 0; ks < 4; ks++)
      bfr[cg][ks] = *(const bfv8*)&Wb[(size_t)(cbase + cg * 16 + lr) * 128 + ks * 32 + ko];

  f32x4 acc[4][4] = {};
#pragma unroll
  for (int ks = 0; ks < 4; ks++) {
    bfv8 af[4];
#pragma unroll
    for (int rg = 0; rg < 4; rg++) af[rg] = *(const bfv8*)&A[rowoff[rg] + ks * 32 + ko];
#pragma unroll
    for (int rg = 0; rg < 4; rg++)
#pragma unroll
      for (int cg = 0; cg < 4; cg++)
        acc[rg][cg] =
            __builtin_amdgcn_mfma_f32_16x16x32_bf16(af[rg], bfr[cg][ks], acc[rg][cg], 0, 0, 0);
  }

#pragma unroll
  for (int cg = 0; cg < 4; cg++) {
    int col = cbase + cg * 16 + lr;
    float bv = bias[col];
#pragma unroll
    for (int rg = 0; rg < 4; rg++) {
      int row0 = i0 + rbase + rg * 16 + lg * 4;
#pragma unroll
      for (int j = 0; j < 4; j++) {
        int row = row0 + j;
        if (row < M) Out[(size_t)row * 128 + col] = __float2bfloat16(lrelu(acc[rg][cg][j] + bv));
      }
    }
  }
}

// Fused RGCN conv: Out = X@root + mean_r0(X)@rw0 + mean_r1(X)@rw1 + bias.
// 32-row blocks; both relations in one 32KB fp32 LDS tile (vrows 0-31 rel0, 32-63 rel1).
// Gather: ownership items (vrow, 8-col chunk), 4 cursors per thread walked jointly with
// BRANCH-FREE clamped depth-2 lookahead -> 8 unconditional X-row loads in flight per wave
// (R6's if-guarded loads collapsed to ~2 in flight; VGPR 48 was the tell).
// TAIL=true additionally fuses lrelu(conv_out @ W_o1^T + b_o1) @ W_o2^T + b_o2 -> out2.
// LDS XOR-swizzle byte ^= (row&7)<<4 on MFMA-read tiles.
template <bool TAIL>
__global__ __launch_bounds__(256, 4) void mfma_conv_f(
    const bf16* __restrict__ X, const int* __restrict__ off, const int* __restrict__ cnt,
    const int* __restrict__ elist, const float* __restrict__ inv,
    const bf16* __restrict__ WB, const float* __restrict__ bias, bf16* __restrict__ Out,
    const bf16* __restrict__ Wo1B, const float* __restrict__ bO1,
    const float* __restrict__ Wo2, const float* __restrict__ bo2,
    float* __restrict__ out2, int M, int NNr, int NEr) {
  __shared__ __align__(16) float At[64 * 128];
  int t = threadIdx.x;
  int wv = t >> 6, l = t & 63;
  int lr = l & 15, lg = l >> 4;
  int i0 = blockIdx.x * 32;
  int cbase = wv * 32;
  int ko = lg * 8;

  // ---- joint 4-cursor ownership gather, branch-free clamped depth-2 lookahead ----
  {
    int c8 = (t & 15) * 8;  // col chunk base (elements)
    int stc[4], dgc[4];
#pragma unroll
    for (int pn = 0; pn < 4; pn++) {
      int vr = (t >> 4) + pn * 16;  // 0..63
      int rel = vr >> 5, m = vr & 31;
      int node = i0 + m;
      int idx = rel * NNr + node;
      bool ok = node < M;
      stc[pn] = ok ? off[idx] : 0;
      dgc[pn] = ok ? cnt[idx] : 0;
    }
    int dmax = max(max(dgc[0], dgc[1]), max(dgc[2], dgc[3]));
    float s[4][8] = {};

    auto xoff = [&](int pn, int e) -> size_t {
      int ec = e < dgc[pn] - 1 ? e : dgc[pn] - 1;  // clamp within list
      ec = ec < 0 ? 0 : ec;
      int ei = stc[pn] + ec;
      ei = ei < NEr - 1 ? ei : NEr - 1;  // global clamp (deg-0 tail nodes)
      return (size_t)(elist[ei] & 0xFFFFFF) * 128 + c8;
    };

    bfv8 v0[4], v1[4];
#pragma unroll
    for (int pn = 0; pn < 4; pn++) v0[pn] = *(const bfv8*)&X[xoff(pn, 0)];
#pragma unroll
    for (int pn = 0; pn < 4; pn++) v1[pn] = *(const bfv8*)&X[xoff(pn, 1)];

    for (int e = 0; e < dmax; e++) {
      bfv8 v2[4];
#pragma unroll
      for (int pn = 0; pn < 4; pn++) v2[pn] = *(const bfv8*)&X[xoff(pn, e + 2)];
#pragma unroll
      for (int pn = 0; pn < 4; pn++) {
        float msk = e < dgc[pn] ? 1.f : 0.f;
#pragma unroll
        for (int j = 0; j < 8; j++) s[pn][j] += msk * __bfloat162float(v0[pn][j]);
      }
#pragma unroll
      for (int pn = 0; pn < 4; pn++) {
        v0[pn] = v1[pn];
        v1[pn] = v2[pn];
      }
    }
#pragma unroll
    for (int pn = 0; pn < 4; pn++) {
      int vr = (t >> 4) + pn * 16;
      int sw = (vr & 7) << 4;
      int lb = vr * 512 + c8 * 4;
      *(float4*)((char*)At + (lb ^ sw)) = make_float4(s[pn][0], s[pn][1], s[pn][2], s[pn][3]);
      *(float4*)((char*)At + ((lb + 16) ^ sw)) =
          make_float4(s[pn][4], s[pn][5], s[pn][6], s[pn][7]);
    }
  }

  // row clamps and inv scales
  size_t rowoff[2];
  float iv0[2], iv1[2];
#pragma unroll
  for (int rg = 0; rg < 2; rg++) {
    int row = i0 + rg * 16 + lr;
    int rc = row < M ? row : M - 1;
    rowoff[rg] = (size_t)rc * 128;
    iv0[rg] = row < M ? inv[row] : 0.f;
    iv1[rg] = row < M ? inv[NNr + row] : 0.f;
  }

  f32x4 acc[2][2] = {};

  // ---- seg 0: X @ root from global (independent of LDS; overlaps store latency) ----
#pragma unroll
  for (int ks = 0; ks < 4; ks++) {
    bfv8 bk[2];
#pragma unroll
    for (int cg = 0; cg < 2; cg++)
      bk[cg] = *(const bfv8*)&WB[(size_t)(cbase + cg * 16 + lr) * 128 + ks * 32 + ko];
    bfv8 af[2];
#pragma unroll
    for (int rg = 0; rg < 2; rg++) af[rg] = *(const bfv8*)&X[rowoff[rg] + ks * 32 + ko];
#pragma unroll
    for (int rg = 0; rg < 2; rg++)
#pragma unroll
      for (int cg = 0; cg < 2; cg++)
        acc[rg][cg] =
            __builtin_amdgcn_mfma_f32_16x16x32_bf16(af[rg], bk[cg], acc[rg][cg], 0, 0, 0);
  }
  __syncthreads();

  // ---- rel-0 / rel-1 MFMA from LDS (inv-scaled, cvt to bf16) ----
#pragma unroll
  for (int r = 0; r < 2; r++) {
    const bf16* Wb = WB + 16384 * (1 + r);
#pragma unroll
    for (int ks = 0; ks < 4; ks++) {
      bfv8 bk[2];
#pragma unroll
      for (int cg = 0; cg < 2; cg++)
        bk[cg] = *(const bfv8*)&Wb[(size_t)(cbase + cg * 16 + lr) * 128 + ks * 32 + ko];
      bfv8 af[2];
#pragma unroll
      for (int rg = 0; rg < 2; rg++) {
        int mrow = r * 32 + rg * 16 + lr;
        int lb = mrow * 512 + ks * 128 + ko * 4;
        int sw = (mrow & 7) << 4;
        float4 f0 = *(const float4*)((const char*)At + (lb ^ sw));
        float4 f1 = *(const float4*)((const char*)At + ((lb + 16) ^ sw));
        float iv = r ? iv1[rg] : iv0[rg];
        bfv8 a;
        a[0] = (__bf16)(f0.x * iv); a[1] = (__bf16)(f0.y * iv);
        a[2] = (__bf16)(f0.z * iv); a[3] = (__bf16)(f0.w * iv);
        a[4] = (__bf16)(f1.x * iv); a[5] = (__bf16)(f1.y * iv);
        a[6] = (__bf16)(f1.z * iv); a[7] = (__bf16)(f1.w * iv);
        af[rg] = a;
      }
#pragma unroll
      for (int rg = 0; rg < 2; rg++)
#pragma unroll
        for (int cg = 0; cg < 2; cg++)
          acc[rg][cg] =
              __builtin_amdgcn_mfma_f32_16x16x32_bf16(af[rg], bk[cg], acc[rg][cg], 0, 0, 0);
    }
  }

  if (!TAIL) {
    // ---- epilogue: + bias, no activation ----
#pragma unroll
    for (int cg = 0; cg < 2; cg++) {
      int col = cbase + cg * 16 + lr;
      float bv = bias[col];
#pragma unroll
      for (int rg = 0; rg < 2; rg++) {
        int row0 = i0 + rg * 16 + lg * 4;
#pragma unroll
        for (int j = 0; j < 4; j++) {
          int row = row0 + j;
          if (row < M) Out[(size_t)row * 128 + col] = __float2bfloat16(acc[rg][cg][j] + bv);
        }
      }
    }
  } else {
    // ---- fused tail: y = conv_out + bias (bf16, LDS, swizzled) ----
    __syncthreads();  // all At reads done before overwrite
#pragma unroll
    for (int cg = 0; cg < 2; cg++) {
      int col = cbase + cg * 16 + lr;
      float bv = bias[col];
#pragma unroll
      for (int rg = 0; rg < 2; rg++) {
#pragma unroll
        for (int j = 0; j < 4; j++) {
          int row32 = rg * 16 + lg * 4 + j;
          int byte = row32 * 256 + col * 2;
          *(bf16*)((char*)At + (byte ^ ((row32 & 7) << 4))) =
              __float2bfloat16(acc[rg][cg][j] + bv);
        }
      }
    }
    __syncthreads();

    // z = lrelu(y @ Wo1^T + bO1): 32 rows x 128 cols, wave owns 32-col slice
    f32x4 acc2[2][2] = {};
#pragma unroll
    for (int ks = 0; ks < 4; ks++) {
      bfv8 bk[2];
#pragma unroll
      for (int cg = 0; cg < 2; cg++)
        bk[cg] = *(const bfv8*)&Wo1B[(size_t)(cbase + cg * 16 + lr) * 128 + ks * 32 + ko];
      bfv8 af[2];
#pragma unroll
      for (int rg = 0; rg < 2; rg++) {
        int mrow = rg * 16 + lr;
        int byte = mrow * 256 + (ks * 32 + ko) * 2;
        af[rg] = *(const bfv8*)((const char*)At + (byte ^ ((mrow & 7) << 4)));
      }
#pragma unroll
      for (int rg = 0; rg < 2; rg++)
#pragma unroll
        for (int cg = 0; cg < 2; cg++)
          acc2[rg][cg] =
              __builtin_amdgcn_mfma_f32_16x16x32_bf16(af[rg], bk[cg], acc2[rg][cg], 0, 0, 0);
    }
    // store z (bf16, LDS bytes [8192,16384), no swizzle)
#pragma unroll
    for (int cg = 0; cg < 2; cg++) {
      int col = cbase + cg * 16 + lr;
      float bv = bO1[col];
#pragma unroll
      for (int rg = 0; rg < 2; rg++) {
#pragma unroll
        for (int j = 0; j < 4; j++) {
          int row32 = rg * 16 + lg * 4 + j;
          *(bf16*)((char*)At + 8192 + row32 * 256 + col * 2) =
              __float2bfloat16(lrelu(acc2[rg][cg][j] + bv));
        }
      }
    }
    __syncthreads();

    // final: out2[row] = z_row @ Wo2^T + bo2; 8 threads per row, shuffle-reduce
    int row = t >> 3, seg = t & 7;
    const bf16* zr = (const bf16*)((const char*)At + 8192 + row * 256 + seg * 32);
    float p0 = 0.f, p1 = 0.f;
#pragma unroll
    for (int q = 0; q < 16; q++) {
      float xv = __bfloat162float(zr[q]);
      int col = seg * 16 + q;
      p0 += xv * Wo2[col];
      p1 += xv * Wo2[128 + col];
    }
#pragma unroll
    for (int o = 4; o; o >>= 1) {
      p0 += __shfl_down(p0, o, 8);
      p1 += __shfl_down(p1, o, 8);
    }
    int grow = i0 + row;
    if (seg == 0 && grow < M) {
      out2[(size_t)grow * 2] = p0 + bo2[0];
      out2[(size_t)grow * 2 + 1] = p1 + bo2[1];
    }
  }
}

// ---------------- pipeline (bf16 storage, MFMA everywhere, fused ends) ----------------
static void run_pipeline(void* const* d_in, const int* S, float* out, char* ws,
                         int NUr, int NTr, int NEr, int dDes, int dNum, int dCat, int dTw,
                         hipStream_t stream) {
  const int NNr = NUr + NTr;
  const size_t xbytes = (size_t)NNr * 128 * 2;

  bf16* xa = (bf16*)ws;
  bf16* xb = (bf16*)(ws + xbytes);
  char* p = ws + 2 * xbytes;
  int* cnt = (int*)p;      p += (size_t)2 * NNr * 4;
  int* fill = (int*)p;     p += (size_t)2 * NNr * 4;  // contiguous with cnt
  int* off = (int*)p;      p += (size_t)2 * NNr * 4;
  int* bsum = (int*)p;     p += 2048 * 4;             // contiguous with bsumsc
  int* bsumsc = (int*)p;   p += 2048 * 4;
  float* inv = (float*)p;  p += (size_t)2 * NNr * 4;
  int* elist = (int*)p;    p += (size_t)NEr * 4;
  float* pw = (float*)p;   p += (size_t)PW_TOTAL * 4;
  int* flags = (int*)p;

  // ---- format probes: one launch ----
  ProbeArgs pa;
  for (int i = 0; i < 23; i++) {
    int src = (i == 22) ? 21 : i;  // b_o2 (2 elems) inherits W_o2's dtype
    pa.p[i] = d_in[src];
    if (i == 4) {
      pa.mode[i] = 1;
      pa.s[i] = NEr < 256 ? NEr : 256;
    } else if (i == 5) {
      pa.mode[i] = 1;
      int s2 = NEr / 2 < 256 ? NEr / 2 : 256;
      pa.s[i] = s2 < 1 ? 1 : s2;
    } else {
      pa.mode[i] = 0;
      int s = S[src] / 2;
      if (s > 256) s = 256;
      if (s < 1) s = 1;
      pa.s[i] = s;
    }
  }
  detect_all<<<23, 256, 0, stream>>>(pa, flags);
  prep_weights<<<(PW_W_TOTAL + 255) / 256, 256, 0, stream>>>(
      d_in[14], d_in[15], d_in[16], d_in[17], d_in[18], d_in[19], d_in[20], d_in[21],
      d_in[22], flags, pw);
  prep_enc<<<129, 256, 0, stream>>>(d_in[6], d_in[7], d_in[8], d_in[9], d_in[10], d_in[11],
                                    d_in[12], d_in[13], flags, dDes, dNum, dCat, dTw, pw);

  const float* bIn = pw + 81920;
  const float* rbp = pw + 82048;
  const float* bO1 = pw + 82176;
  const float* Wo2p = pw + 82304;
  const float* bo2p = pw + 82560;
  const bf16* WinB = (const bf16*)(pw + BF_BASE);
  const bf16* Wo1B = (const bf16*)(pw + BF_BASE + 8192);
  const bf16* ConvB = (const bf16*)(pw + BF_BASE + 16384);  // rootB, rwB0, rwB1
  const bf16* EncU = (const bf16*)(pw + ENC_BASE);
  const bf16* EncT = (const bf16*)(pw + ENC_BASE + 8192);
  const float* bU = pw + ENC_BASE + 16384;
  const float* bT = bU + 128;

  const void* ei = d_in[4];
  const void* et = d_in[5];
  const int nb1 = (2 * NNr + 1023) / 1024;

  // ---- CSR build ----
  zero_ints<<<(4 * NNr + 255) / 256, 256, 0, stream>>>(cnt, 4 * NNr);
  zero_ints<<<16, 256, 0, stream>>>(bsum, 4096);
  count_edges<<<(NEr + 255) / 256, 256, 0, stream>>>(ei, et, flags, cnt, NEr, NNr);
  scan_blocks<<<nb1, 256, 0, stream>>>(cnt, off, bsum, 2 * NNr);
  scan_blocks<<<1, 256, 0, stream>>>(bsum, bsumsc, nullptr, nb1);
  scan_add_inv<<<(2 * NNr + 255) / 256, 256, 0, stream>>>(off, bsumsc, cnt, inv, 2 * NNr);
  fill_elist<<<(NEr + 255) / 256, 256, 0, stream>>>(ei, et, flags, off, fill, elist, NEr, NNr);

  // ---- encoders (fused with W_in) -> xb ----
  if (dDes + dNum + dCat <= 128 && dTw <= 128) {
    enc_mfma<<<(NUr + 127) / 128, 256, 0, stream>>>(d_in[0], d_in[2], d_in[3], flags, 0, 2, 3,
                                                    dDes, dNum, dCat, EncU, bU, WinB, bIn, xb,
                                                    NUr, 0);
    enc_mfma<<<(NTr + 127) / 128, 256, 0, stream>>>(d_in[1], nullptr, nullptr, flags, 1, 1, 1,
                                                    dTw, 0, 0, EncT, bT, WinB, bIn, xb, NTr,
                                                    NUr);
  } else {
    enc_gemm<<<(NUr + 63) / 64, 256, 0, stream>>>(d_in[0], d_in[6], d_in[7], flags, 0, 6, 7,
                                                  xa, NUr, dDes, 64, 0, 0);
    enc_gemm<<<(NUr + 63) / 64, 256, 0, stream>>>(d_in[2], d_in[8], d_in[9], flags, 2, 8, 9,
                                                  xa, NUr, dNum, 32, 0, 64);
    enc_gemm<<<(NUr + 63) / 64, 256, 0, stream>>>(d_in[3], d_in[10], d_in[11], flags, 3, 10,
                                                  11, xa, NUr, dCat, 32, 0, 96);
    enc_gemm<<<(NTr + 63) / 64, 256, 0, stream>>>(d_in[1], d_in[12], d_in[13], flags, 1, 12,
                                                  13, xa, NTr, dTw, 128, NUr, 0);
    mfma_lin<<<(NNr + 127) / 128, 256, 0, stream>>>(xa, WinB, bIn, xb, NNr);
  }

  const int mt32 = (NNr + 31) / 32;
  mfma_conv_f<false><<<mt32, 256, 0, stream>>>(xb, off, cnt, elist, inv, ConvB, rbp, xa,
                                               nullptr, nullptr, nullptr, nullptr, nullptr,
                                               NNr, NNr, NEr);
  mfma_conv_f<true><<<mt32, 256, 0, stream>>>(xa, off, cnt, elist, inv, ConvB, rbp, nullptr,
                                              Wo1B, bO1, Wo2p, bo2p, out, NNr, NNr, NEr);
}

extern "C" void kernel_launch(void* const* d_in, const int* in_sizes, int n_in,
                              void* d_out, int out_size, void* d_ws, size_t ws_size,
                              hipStream_t stream) {
  float* out = (float*)d_out;
  char* ws = (char*)d_ws;

  auto signal = [&](int k) {
    sig_fill<<<(out_size + 255) / 256, 256, 0, stream>>>(out, out_size, (float)(200 + k));
  };

  if (n_in != 23) { signal(1); return; }
  const int* S = in_sizes;
  if (S[7] != 64 || S[9] != 32 || S[11] != 32 || S[13] != 128) { signal(2); return; }
  if (S[15] != 128) { signal(3); return; }
  if (S[6] % 64 || S[8] % 32 || S[10] % 32 || S[12] % 128) { signal(4); return; }
  int dDes = S[6] / 64, dNum = S[8] / 32, dCat = S[10] / 32, dTw = S[12] / 128;
  if (dDes <= 0 || dTw <= 0 || S[0] % dDes || S[1] % dTw) { signal(5); return; }
  if (dDes > 101 || dNum > 101 || dCat > 101 || dTw > 101) { signal(4); return; }
  int NUr = S[0] / dDes, NTr = S[1] / dTw, NNr = NUr + NTr, NEr = S[5];
  if (S[2] != NUr * dNum || S[3] != NUr * dCat) { signal(5); return; }
  if (S[4] != 2 * NEr || NEr < 1024) { signal(6); return; }
  if (NNr >= (1 << 24)) { signal(6); return; }  // elist src-packing limit
  if (S[14] != 16384 || S[16] != 32768 || S[17] != 16384 || S[18] != 128 ||
      S[19] != 16384 || S[20] != 128 || S[21] != 256 || S[22] != 2) { signal(7); return; }
  if (out_size != NNr * 2) { signal(8); return; }

  const size_t smallBytes = (size_t)4 * ((size_t)2 * NNr * 4) + 2 * 2048 * 4 +
                            (size_t)NEr * 4 + (size_t)PW_TOTAL * 4 + 512;
  const size_t need = 2 * (size_t)NNr * 128 * 2 + smallBytes;

  if (ws_size >= need) {
    run_pipeline(d_in, S, out, ws, NUr, NTr, NEr, dDes, dNum, dCat, dTw, stream);
  } else {
    signal(9);
  }
}